// Round 7
// baseline (438.589 us; speedup 1.0000x reference)
//
#include <hip/hip_runtime.h>
#include <math.h>

#define NEG_SLOPE 0.2f
#define EPS_F 1e-16f
typedef long long ll;

typedef __attribute__((ext_vector_type(4))) float f32x4;
typedef __attribute__((ext_vector_type(8))) short bf16x8;

// ---------------- bf16 helpers (bit-level, RTN-even) ----------------
__device__ __forceinline__ unsigned short bf16_of(float f) {
  unsigned u = __float_as_uint(f);
  u += 0x7fffu + ((u >> 16) & 1u);
  return (unsigned short)(u >> 16);
}
__device__ __forceinline__ float bf16_back(unsigned short s) {
  return __uint_as_float((unsigned)s << 16);
}

__device__ __forceinline__ void gload16(const void* g, void* l) {
  __builtin_amdgcn_global_load_lds((const __attribute__((address_space(1))) void*)g,
                                   (__attribute__((address_space(3))) void*)l, 16, 0, 0);
}

// ---------------- edge dtype detection (int64 vs int32) ----------------
__global__ void detect_int64_kernel(const unsigned int* __restrict__ w, int E,
                                    int* __restrict__ flag) {
  __shared__ int nz;
  if (threadIdx.x == 0) nz = 0;
  __syncthreads();
  int cnt = E < 2048 ? E : 2048;
  int local = 0;
  for (int i = threadIdx.x; i < cnt; i += blockDim.x)
    if (w[2 * i + 1] != 0u) local++;
  if (local) atomicAdd(&nz, local);
  __syncthreads();
  if (threadIdx.x == 0) *flag = (nz == 0) ? 1 : 0;  // 1 => int64 layout
}

__device__ __forceinline__ void edge_at(const int* __restrict__ ew, int E, int e,
                                        int is64, int& s, int& d) {
  if (is64) { s = ew[2 * e]; d = ew[2 * E + 2 * e]; }
  else      { s = ew[e];     d = ew[E + e]; }
}

// ---------------- CSR build ----------------
__global__ void init_deg_kernel(int* deg, int N) {
  int i = blockIdx.x * blockDim.x + threadIdx.x;
  if (i < N) deg[i] = 1;  // self loop
}

__global__ void count_deg_kernel(const int* __restrict__ ew, int E, int* deg,
                                 const int* __restrict__ flag) {
  int is64 = *flag;
  int e = blockIdx.x * blockDim.x + threadIdx.x;
  if (e < E) {
    int s, d;
    edge_at(ew, E, e, is64, s, d);
    atomicAdd(&deg[d], 1);
  }
}

__global__ void scan_kernel(const int* __restrict__ deg, int* rowptr, int* cursor, int N) {
  __shared__ int sums[1024];
  int tid = threadIdx.x;
  int chunk = (N + 1023) >> 10;
  int start = tid * chunk;
  int end = start + chunk; if (end > N) end = N;
  int s = 0;
  for (int i = start; i < end; ++i) s += deg[i];
  sums[tid] = s;
  __syncthreads();
  for (int off = 1; off < 1024; off <<= 1) {
    int v = (tid >= off) ? sums[tid - off] : 0;
    __syncthreads();
    sums[tid] += v;
    __syncthreads();
  }
  int run = (tid == 0) ? 0 : sums[tid - 1];
  for (int i = start; i < end; ++i) {
    rowptr[i] = run; cursor[i] = run;
    run += deg[i];
  }
  if (tid == 1023) rowptr[N] = sums[1023];
}

__global__ void fill_kernel(const int* __restrict__ ew, int E, int N, int* cursor,
                            int* csr, const int* __restrict__ flag) {
  int is64 = *flag;
  int i = blockIdx.x * blockDim.x + threadIdx.x;
  if (i < E) {
    int s, d;
    edge_at(ew, E, i, is64, s, d);
    int pos = atomicAdd(&cursor[d], 1);
    csr[pos] = s;
  } else if (i < E + N) {
    int n = i - E;
    int pos = atomicAdd(&cursor[n], 1);
    csr[pos] = n;
  }
}

// ---------------- input conversions to split-bf16 ----------------
__global__ void convert_x_kernel(const float* __restrict__ x, short* __restrict__ A, int N) {
  int i = blockIdx.x * blockDim.x + threadIdx.x;
  if (i >= N * 256) return;
  int r = i >> 8, c = i & 255;
  float v = x[i];
  unsigned short hi = bf16_of(v);
  unsigned short lo = bf16_of(v - bf16_back(hi));
  A[(ll)r * 512 + c] = (short)hi;
  A[(ll)r * 512 + 256 + c] = (short)lo;
}

// W [K, Nc] fp32 -> Bt [Nc, K] bf16 (W_hi^T only)
__global__ __launch_bounds__(256) void convert_w_kernel(const float* __restrict__ W,
                                                        short* __restrict__ Bt,
                                                        int K, int Nc) {
  __shared__ float t[32][33];
  int k0 = blockIdx.x * 32, n0 = blockIdx.y * 32;
  int r = threadIdx.x >> 3;          // 0..31
  int c4 = (threadIdx.x & 7) * 4;    // 0..28
  float4 v = *(const float4*)&W[(ll)(k0 + r) * Nc + n0 + c4];
  t[r][c4] = v.x; t[r][c4 + 1] = v.y; t[r][c4 + 2] = v.z; t[r][c4 + 3] = v.w;
  __syncthreads();
  float f0 = t[c4 + 0][r], f1 = t[c4 + 1][r], f2 = t[c4 + 2][r], f3 = t[c4 + 3][r];
  short4 hp = make_short4((short)bf16_of(f0), (short)bf16_of(f1),
                          (short)bf16_of(f2), (short)bf16_of(f3));
  *(short4*)&Bt[(ll)(n0 + r) * K + k0 + c4] = hp;
}

// ---------------- MFMA GEMM: C[M,Nc] = (A_hi + A_lo) x W_hi, fused scores ----
template <int HBF16>
__global__ __launch_bounds__(256) void gemm_mfma_kernel(
    const short* __restrict__ A, const short* __restrict__ Bt,
    void* __restrict__ Cv, const float* __restrict__ a_src,
    const float* __restrict__ a_dst, float* __restrict__ partS,
    float* __restrict__ partD, int M, int Nc, int K) {
  __shared__ char Ah[8192];
  __shared__ char Al[8192];
  __shared__ char Bs[8192];
  int tid = threadIdx.x;

  int nwg = gridDim.x * gridDim.y;
  int hb = blockIdx.y * gridDim.x + blockIdx.x;
  int xcd = hb & 7, q = nwg >> 3, r = nwg & 7;
  int lg = (xcd < r ? xcd * (q + 1) : r * (q + 1) + (xcd - r) * q) + (hb >> 3);
  int bx = lg % gridDim.x, by = lg / gridDim.x;
  int bm = by * 128, bn = bx * 128;

  int lane = tid & 63, wid = tid >> 6;
  int wr = wid >> 1, wc = wid & 1;
  int K2 = 2 * K;

  f32x4 acc[4][4];
#pragma unroll
  for (int m = 0; m < 4; ++m)
#pragma unroll
    for (int n = 0; n < 4; ++n) acc[m][n] = (f32x4){0.f, 0.f, 0.f, 0.f};

  int srow = tid >> 2;                 // 0..63
  int cphys = tid & 3;                 // LDS chunk slot this thread fills
  int swz = (srow >> 1) & 3;
  int clog = (cphys ^ swz) * 8;        // bf16 k-offset actually fetched
  int ra = bm + srow;       if (ra > M - 1) ra = M - 1;
  int rb = bm + srow + 64;  if (rb > M - 1) rb = M - 1;
  const short* aP0 = A + (ll)ra * K2 + clog;
  const short* aP1 = A + (ll)rb * K2 + clog;
  const short* bP0 = Bt + (ll)(bn + srow) * K + clog;
  const short* bP1 = Bt + (ll)(bn + srow + 64) * K + clog;
  int dstOff = tid * 16;

  int lrow = lane & 15;
  int lchunk = ((lane >> 4) ^ ((lrow >> 1) & 3)) * 16;
  int fOffA = (wr * 64 + lrow) * 64 + lchunk;
  int fOffB = (wc * 64 + lrow) * 64 + lchunk;

  for (int kt = 0; kt < K; kt += 32) {
    gload16(aP0 + kt, Ah + dstOff);
    gload16(aP1 + kt, Ah + 4096 + dstOff);
    gload16(aP0 + K + kt, Al + dstOff);
    gload16(aP1 + K + kt, Al + 4096 + dstOff);
    gload16(bP0 + kt, Bs + dstOff);
    gload16(bP1 + kt, Bs + 4096 + dstOff);
    __syncthreads();
    bf16x8 ah[4], al[4], bfr[4];
#pragma unroll
    for (int m = 0; m < 4; ++m) {
      ah[m] = *(const bf16x8*)(Ah + fOffA + m * 1024);
      al[m] = *(const bf16x8*)(Al + fOffA + m * 1024);
    }
#pragma unroll
    for (int n = 0; n < 4; ++n) bfr[n] = *(const bf16x8*)(Bs + fOffB + n * 1024);
#pragma unroll
    for (int m = 0; m < 4; ++m)
#pragma unroll
      for (int n = 0; n < 4; ++n) {
        acc[m][n] = __builtin_amdgcn_mfma_f32_16x16x32_bf16(ah[m], bfr[n], acc[m][n], 0, 0, 0);
        acc[m][n] = __builtin_amdgcn_mfma_f32_16x16x32_bf16(al[m], bfr[n], acc[m][n], 0, 0, 0);
      }
    __syncthreads();
  }

  int crow0 = bm + wr * 64 + (lane >> 4) * 4;
  int ccol0 = bn + wc * 64 + (lane & 15);
#pragma unroll
  for (int m = 0; m < 4; ++m) {
#pragma unroll
    for (int j = 0; j < 4; ++j) {
      int row = crow0 + m * 16 + j;
      if (row < M) {
#pragma unroll
        for (int n = 0; n < 4; ++n) {
          if (HBF16) ((unsigned short*)Cv)[(ll)row * Nc + ccol0 + n * 16] = bf16_of(acc[m][n][j]);
          else       ((float*)Cv)[(ll)row * Nc + ccol0 + n * 16] = acc[m][n][j];
        }
      }
    }
  }

  // fused partial attention scores
  float as4[4], ad4[4];
#pragma unroll
  for (int n = 0; n < 4; ++n) {
    as4[n] = a_src[ccol0 + n * 16];
    ad4[n] = a_dst[ccol0 + n * 16];
  }
  int p = bx * 2 + wc;
#pragma unroll
  for (int m = 0; m < 4; ++m) {
#pragma unroll
    for (int j = 0; j < 4; ++j) {
      float ps = acc[m][0][j] * as4[0] + acc[m][1][j] * as4[1] +
                 acc[m][2][j] * as4[2] + acc[m][3][j] * as4[3];
      float pd = acc[m][0][j] * ad4[0] + acc[m][1][j] * ad4[1] +
                 acc[m][2][j] * ad4[2] + acc[m][3][j] * ad4[3];
#pragma unroll
      for (int o = 1; o < 16; o <<= 1) {
        ps += __shfl_xor(ps, o, 64);
        pd += __shfl_xor(pd, o, 64);
      }
      int row = crow0 + m * 16 + j;
      if ((lane & 15) == 0 && row < M) {
        partS[(ll)p * M + row] = ps;
        partD[(ll)p * M + row] = pd;
      }
    }
  }
}

// sum the per-(col-block,wc) partials -> s_src/s_dst
__global__ void score_reduce_kernel(const float* __restrict__ partS,
                                    const float* __restrict__ partD,
                                    float* __restrict__ s_src, float* __restrict__ s_dst,
                                    int N, int NP) {
  int i = blockIdx.x * blockDim.x + threadIdx.x;
  if (i >= N) return;
  float a = 0.f, b = 0.f;
  for (int p = 0; p < NP; ++p) {
    a += partS[(ll)p * N + i];
    b += partD[(ll)p * N + i];
  }
  s_src[i] = a;
  s_dst[i] = b;
}

// ---------------- per-edge softmax weights (wave per node) ----------------
__global__ __launch_bounds__(256) void alpha_kernel(
    const float* __restrict__ ssrc, const float* __restrict__ sdst,
    const int* __restrict__ rowptr, const int* __restrict__ csr,
    float* __restrict__ alpha, int N) {
  int wid = threadIdx.x >> 6, lane = threadIdx.x & 63;
  int node = blockIdx.x * 4 + wid;
  if (node >= N) return;
  int rs = rowptr[node], re = rowptr[node + 1];
  int nd = re - rs;
  float sd = sdst[node];
  if (nd <= 64) {
    float e = -1e30f;
    if (lane < nd) {
      float t = ssrc[csr[rs + lane]] + sd;
      e = t > 0.f ? t : NEG_SLOPE * t;
    }
    float m = e;
#pragma unroll
    for (int o = 32; o > 0; o >>= 1) m = fmaxf(m, __shfl_xor(m, o, 64));
    float ex = (lane < nd) ? __expf(e - m) : 0.f;
    float den = ex;
#pragma unroll
    for (int o = 32; o > 0; o >>= 1) den += __shfl_xor(den, o, 64);
    if (lane < nd) alpha[rs + lane] = ex / (den + EPS_F);
  } else {
    float m = -1e30f;
    for (int i = lane; i < nd; i += 64) {
      float t = ssrc[csr[rs + i]] + sd;
      t = t > 0.f ? t : NEG_SLOPE * t;
      m = fmaxf(m, t);
    }
#pragma unroll
    for (int o = 32; o > 0; o >>= 1) m = fmaxf(m, __shfl_xor(m, o, 64));
    float den = 0.f;
    for (int i = lane; i < nd; i += 64) {
      float t = ssrc[csr[rs + i]] + sd;
      t = t > 0.f ? t : NEG_SLOPE * t;
      den += __expf(t - m);
    }
#pragma unroll
    for (int o = 32; o > 0; o >>= 1) den += __shfl_xor(den, o, 64);
    float inv = 1.f / (den + EPS_F);
    for (int i = lane; i < nd; i += 64) {
      float t = ssrc[csr[rs + i]] + sd;
      t = t > 0.f ? t : NEG_SLOPE * t;
      alpha[rs + i] = __expf(t - m) * inv;
    }
  }
}

// ---------------- XCD-sliced weighted aggregation ----------------
// Column-sliced gather: slice working set = N * (DOUT/SLICES) elems, sized to
// fit one XCD's 4MB L2. slice = bid % SLICES rides the HW's round-robin
// wg->XCD mapping so each XCD re-reads only its own slice. One wave per
// (node, slice); no LDS, no barriers.
template <int DOUT, int SLICES, int HIN_BF16, int OUTSPLIT>
__global__ __launch_bounds__(256) void agg_slice_kernel(
    const void* __restrict__ hv, const float* __restrict__ alpha,
    const int* __restrict__ rowptr, const int* __restrict__ csr,
    const float* __restrict__ bias, float* __restrict__ outF,
    short* __restrict__ outH, int N) {
  constexpr int SD = DOUT / SLICES;   // dims per slice
  constexpr int DPT = SD / 64;        // dims per lane (2 or 1)
  int wid = threadIdx.x >> 6, lane = threadIdx.x & 63;
  int slice = blockIdx.x & (SLICES - 1);
  int node = (blockIdx.x / SLICES) * 4 + wid;
  if (node >= N) return;
  int rs = rowptr[node];
  int nd = rowptr[node + 1] - rs;
  int d = slice * SD + lane * DPT;

  float a0 = 0.f, a1 = 0.f;
  if constexpr (HIN_BF16) {
    const unsigned short* hp = (const unsigned short*)hv;
    int i = 0;
    for (; i + 2 <= nd; i += 2) {
      int s0 = csr[rs + i], s1 = csr[rs + i + 1];
      float w0 = alpha[rs + i], w1 = alpha[rs + i + 1];
      if constexpr (DPT == 2) {
        short2 q0 = *(const short2*)(hp + (ll)s0 * DOUT + d);
        short2 q1 = *(const short2*)(hp + (ll)s1 * DOUT + d);
        a0 += w0 * bf16_back((unsigned short)q0.x) + w1 * bf16_back((unsigned short)q1.x);
        a1 += w0 * bf16_back((unsigned short)q0.y) + w1 * bf16_back((unsigned short)q1.y);
      } else {
        a0 += w0 * bf16_back(hp[(ll)s0 * DOUT + d]) + w1 * bf16_back(hp[(ll)s1 * DOUT + d]);
      }
    }
    if (i < nd) {
      int s0 = csr[rs + i];
      float w0 = alpha[rs + i];
      if constexpr (DPT == 2) {
        short2 q0 = *(const short2*)(hp + (ll)s0 * DOUT + d);
        a0 += w0 * bf16_back((unsigned short)q0.x);
        a1 += w0 * bf16_back((unsigned short)q0.y);
      } else {
        a0 += w0 * bf16_back(hp[(ll)s0 * DOUT + d]);
      }
    }
  } else {
    const float* hp = (const float*)hv;
    int i = 0;
    for (; i + 2 <= nd; i += 2) {
      int s0 = csr[rs + i], s1 = csr[rs + i + 1];
      float w0 = alpha[rs + i], w1 = alpha[rs + i + 1];
      if constexpr (DPT == 2) {
        float2 q0 = *(const float2*)(hp + (ll)s0 * DOUT + d);
        float2 q1 = *(const float2*)(hp + (ll)s1 * DOUT + d);
        a0 += w0 * q0.x + w1 * q1.x;
        a1 += w0 * q0.y + w1 * q1.y;
      } else {
        a0 += w0 * hp[(ll)s0 * DOUT + d] + w1 * hp[(ll)s1 * DOUT + d];
      }
    }
    if (i < nd) {
      int s0 = csr[rs + i];
      float w0 = alpha[rs + i];
      if constexpr (DPT == 2) {
        float2 q0 = *(const float2*)(hp + (ll)s0 * DOUT + d);
        a0 += w0 * q0.x;
        a1 += w0 * q0.y;
      } else {
        a0 += w0 * hp[(ll)s0 * DOUT + d];
      }
    }
  }

  if constexpr (DPT == 2) {
    float2 bv = *(const float2*)&bias[d];
    float v0 = a0 + bv.x, v1 = a1 + bv.y;
    if constexpr (OUTSPLIT) {
      v0 = fmaxf(v0, 0.f); v1 = fmaxf(v1, 0.f);
      unsigned short h0 = bf16_of(v0), h1 = bf16_of(v1);
      short2 hp2 = make_short2((short)h0, (short)h1);
      short2 lp2 = make_short2((short)bf16_of(v0 - bf16_back(h0)),
                               (short)bf16_of(v1 - bf16_back(h1)));
      ll base = (ll)node * (2 * DOUT) + d;
      *(short2*)&outH[base] = hp2;
      *(short2*)&outH[base + DOUT] = lp2;
    } else {
      *(float2*)&outF[(ll)node * DOUT + d] = make_float2(v0, v1);
    }
  } else {
    float v0 = a0 + bias[d];
    if constexpr (OUTSPLIT) {
      v0 = fmaxf(v0, 0.f);
      unsigned short h0 = bf16_of(v0);
      ll base = (ll)node * (2 * DOUT) + d;
      outH[base] = (short)h0;
      outH[base + DOUT] = (short)bf16_of(v0 - bf16_back(h0));
    } else {
      outF[(ll)node * DOUT + d] = v0;
    }
  }
}

// ---------------- row log_softmax (C == blockDim.x) ----------------
__global__ void log_softmax_kernel(const float* __restrict__ in, float* __restrict__ out,
                                   int C) {
  int row = blockIdx.x;
  int tid = threadIdx.x;
  int lane = tid & 63, wid = tid >> 6;
  __shared__ float red[2];
  float v = in[(ll)row * C + tid];
  float m = v;
#pragma unroll
  for (int o = 32; o > 0; o >>= 1) m = fmaxf(m, __shfl_xor(m, o, 64));
  if (lane == 0) red[wid] = m;
  __syncthreads();
  m = fmaxf(red[0], red[1]);
  __syncthreads();
  float ex = __expf(v - m);
  float s = ex;
#pragma unroll
  for (int o = 32; o > 0; o >>= 1) s += __shfl_xor(s, o, 64);
  if (lane == 0) red[wid] = s;
  __syncthreads();
  s = red[0] + red[1];
  out[(ll)row * C + tid] = v - m - logf(s);
}

// ---------------- launch ----------------
extern "C" void kernel_launch(void* const* d_in, const int* in_sizes, int n_in,
                              void* d_out, int out_size, void* d_ws, size_t ws_size,
                              hipStream_t stream) {
  const float* x = (const float*)d_in[0];
  const int* ew = (const int*)d_in[1];
  int N = in_sizes[0] / 256;
  int E = in_sizes[1] / 2;

  const float* W[4]   = {(const float*)d_in[2],  (const float*)d_in[6],
                         (const float*)d_in[10], (const float*)d_in[14]};
  const float* Asv[4] = {(const float*)d_in[3],  (const float*)d_in[7],
                         (const float*)d_in[11], (const float*)d_in[15]};
  const float* Adv[4] = {(const float*)d_in[4],  (const float*)d_in[8],
                         (const float*)d_in[12], (const float*)d_in[16]};
  const float* Bv[4]  = {(const float*)d_in[5],  (const float*)d_in[9],
                         (const float*)d_in[13], (const float*)d_in[17]};
  const int din[4]  = {256, 1024, 1024, 512};
  const int dout[4] = {1024, 1024, 512, 128};

  char* ws = (char*)d_ws;
  size_t off = 0;
  auto alloc = [&](size_t bytes) {
    void* p = ws + off;
    off += (bytes + 255) & ~(size_t)255;
    return p;
  };
  unsigned short* hB = (unsigned short*)alloc((size_t)N * 1024 * 2);  // bf16 h (layers 1-3)
  float* hF   = (float*)alloc((size_t)N * 128 * 4);                   // fp32 h (layer 4)
  short* bufP = (short*)alloc((size_t)N * 2048 * 2);
  short* bufQ = (short*)alloc((size_t)N * 2048 * 2);
  float* sF   = (float*)alloc((size_t)N * 128 * 4);
  float* s_src = (float*)alloc((size_t)N * 4);
  float* s_dst = (float*)alloc((size_t)N * 4);
  float* partS = (float*)alloc((size_t)16 * N * 4);
  float* partD = (float*)alloc((size_t)16 * N * 4);
  float* alphaB = (float*)alloc((size_t)(E + N) * 4);
  int* deg    = (int*)alloc((size_t)(N + 1) * 4);
  int* rowptr = (int*)alloc((size_t)(N + 1) * 4);
  int* cursor = (int*)alloc((size_t)(N + 1) * 4);
  int* csr    = (int*)alloc((size_t)(E + N) * 4);
  int* flag   = (int*)alloc(256);
  short* Bt[4];
  for (int l = 0; l < 4; ++l) Bt[l] = (short*)alloc((size_t)dout[l] * din[l] * 2);

  detect_int64_kernel<<<1, 256, 0, stream>>>((const unsigned int*)ew, E, flag);
  init_deg_kernel<<<(N + 255) / 256, 256, 0, stream>>>(deg, N);
  count_deg_kernel<<<(E + 255) / 256, 256, 0, stream>>>(ew, E, deg, flag);
  scan_kernel<<<1, 1024, 0, stream>>>(deg, rowptr, cursor, N);
  fill_kernel<<<(E + N + 255) / 256, 256, 0, stream>>>(ew, E, N, cursor, csr, flag);

  convert_x_kernel<<<(N * 256 + 255) / 256, 256, 0, stream>>>(x, bufP, N);
  for (int l = 0; l < 4; ++l) {
    dim3 cg(din[l] / 32, dout[l] / 32);
    convert_w_kernel<<<cg, 256, 0, stream>>>(W[l], Bt[l], din[l], dout[l]);
  }

  int ngrp = (N + 3) / 4;
  short* cur = bufP;
  short* nxt = bufQ;
  for (int l = 0; l < 4; ++l) {
    dim3 ggrid(dout[l] / 128, (N + 127) / 128);
    int NP = (dout[l] / 128) * 2;
    if (l < 3) {
      gemm_mfma_kernel<1><<<ggrid, 256, 0, stream>>>(cur, Bt[l], hB, Asv[l], Adv[l],
                                                     partS, partD, N, dout[l], din[l]);
    } else {
      gemm_mfma_kernel<0><<<ggrid, 256, 0, stream>>>(cur, Bt[l], hF, Asv[l], Adv[l],
                                                     partS, partD, N, dout[l], din[l]);
    }
    score_reduce_kernel<<<(N + 255) / 256, 256, 0, stream>>>(partS, partD, s_src, s_dst,
                                                             N, NP);
    alpha_kernel<<<ngrp, 256, 0, stream>>>(s_src, s_dst, rowptr, csr, alphaB, N);
    if (l < 2) {
      agg_slice_kernel<1024, 8, 1, 1><<<ngrp * 8, 256, 0, stream>>>(
          hB, alphaB, rowptr, csr, Bv[l], nullptr, nxt, N);
    } else if (l == 2) {
      agg_slice_kernel<512, 4, 1, 1><<<ngrp * 4, 256, 0, stream>>>(
          hB, alphaB, rowptr, csr, Bv[l], nullptr, nxt, N);
    } else {
      agg_slice_kernel<128, 2, 0, 0><<<ngrp * 2, 256, 0, stream>>>(
          hF, alphaB, rowptr, csr, Bv[l], sF, nullptr, N);
    }
    short* t = cur; cur = nxt; nxt = t;
  }
  log_softmax_kernel<<<N, 128, 0, stream>>>(sF, (float*)d_out, 128);
}

// Round 8
// 368.030 us; speedup vs baseline: 1.1917x; 1.1917x over previous
//
#include <hip/hip_runtime.h>
#include <math.h>

#define NEG_SLOPE 0.2f
#define EPS_F 1e-16f
typedef long long ll;

typedef __attribute__((ext_vector_type(4))) float f32x4;
typedef __attribute__((ext_vector_type(8))) short bf16x8;

// ---------------- bf16 helpers (bit-level, RTN-even) ----------------
__device__ __forceinline__ unsigned short bf16_of(float f) {
  unsigned u = __float_as_uint(f);
  u += 0x7fffu + ((u >> 16) & 1u);
  return (unsigned short)(u >> 16);
}
__device__ __forceinline__ float bf16_back(unsigned short s) {
  return __uint_as_float((unsigned)s << 16);
}

__device__ __forceinline__ void gload16(const void* g, void* l) {
  __builtin_amdgcn_global_load_lds((const __attribute__((address_space(1))) void*)g,
                                   (__attribute__((address_space(3))) void*)l, 16, 0, 0);
}

// ---------------- edge dtype detection (int64 vs int32) ----------------
__global__ void detect_int64_kernel(const unsigned int* __restrict__ w, int E,
                                    int* __restrict__ flag) {
  __shared__ int nz;
  if (threadIdx.x == 0) nz = 0;
  __syncthreads();
  int cnt = E < 2048 ? E : 2048;
  int local = 0;
  for (int i = threadIdx.x; i < cnt; i += blockDim.x)
    if (w[2 * i + 1] != 0u) local++;
  if (local) atomicAdd(&nz, local);
  __syncthreads();
  if (threadIdx.x == 0) *flag = (nz == 0) ? 1 : 0;  // 1 => int64 layout
}

__device__ __forceinline__ void edge_at(const int* __restrict__ ew, int E, int e,
                                        int is64, int& s, int& d) {
  if (is64) { s = ew[2 * e]; d = ew[2 * E + 2 * e]; }
  else      { s = ew[e];     d = ew[E + e]; }
}

// ---------------- CSR build ----------------
__global__ void init_deg_kernel(int* deg, int N) {
  int i = blockIdx.x * blockDim.x + threadIdx.x;
  if (i < N) deg[i] = 1;  // self loop
}

__global__ void count_deg_kernel(const int* __restrict__ ew, int E, int* deg,
                                 const int* __restrict__ flag) {
  int is64 = *flag;
  int e = blockIdx.x * blockDim.x + threadIdx.x;
  if (e < E) {
    int s, d;
    edge_at(ew, E, e, is64, s, d);
    atomicAdd(&deg[d], 1);
  }
}

__global__ void scan_kernel(const int* __restrict__ deg, int* rowptr, int* cursor, int N) {
  __shared__ int sums[1024];
  int tid = threadIdx.x;
  int chunk = (N + 1023) >> 10;
  int start = tid * chunk;
  int end = start + chunk; if (end > N) end = N;
  int s = 0;
  for (int i = start; i < end; ++i) s += deg[i];
  sums[tid] = s;
  __syncthreads();
  for (int off = 1; off < 1024; off <<= 1) {
    int v = (tid >= off) ? sums[tid - off] : 0;
    __syncthreads();
    sums[tid] += v;
    __syncthreads();
  }
  int run = (tid == 0) ? 0 : sums[tid - 1];
  for (int i = start; i < end; ++i) {
    rowptr[i] = run; cursor[i] = run;
    run += deg[i];
  }
  if (tid == 1023) rowptr[N] = sums[1023];
}

__global__ void fill_kernel(const int* __restrict__ ew, int E, int N, int* cursor,
                            int* csr, const int* __restrict__ flag) {
  int is64 = *flag;
  int i = blockIdx.x * blockDim.x + threadIdx.x;
  if (i < E) {
    int s, d;
    edge_at(ew, E, i, is64, s, d);
    int pos = atomicAdd(&cursor[d], 1);
    csr[pos] = s;
  } else if (i < E + N) {
    int n = i - E;
    int pos = atomicAdd(&cursor[n], 1);
    csr[pos] = n;
  }
}

// ---------------- input conversions to split-bf16 ----------------
__global__ void convert_x_kernel(const float* __restrict__ x, short* __restrict__ A, int N) {
  int i = blockIdx.x * blockDim.x + threadIdx.x;
  if (i >= N * 256) return;
  int r = i >> 8, c = i & 255;
  float v = x[i];
  unsigned short hi = bf16_of(v);
  unsigned short lo = bf16_of(v - bf16_back(hi));
  A[(ll)r * 512 + c] = (short)hi;
  A[(ll)r * 512 + 256 + c] = (short)lo;
}

// W [K, Nc] fp32 -> Bt [Nc, K] bf16 (W_hi^T only)
__global__ __launch_bounds__(256) void convert_w_kernel(const float* __restrict__ W,
                                                        short* __restrict__ Bt,
                                                        int K, int Nc) {
  __shared__ float t[32][33];
  int k0 = blockIdx.x * 32, n0 = blockIdx.y * 32;
  int r = threadIdx.x >> 3;          // 0..31
  int c4 = (threadIdx.x & 7) * 4;    // 0..28
  float4 v = *(const float4*)&W[(ll)(k0 + r) * Nc + n0 + c4];
  t[r][c4] = v.x; t[r][c4 + 1] = v.y; t[r][c4 + 2] = v.z; t[r][c4 + 3] = v.w;
  __syncthreads();
  float f0 = t[c4 + 0][r], f1 = t[c4 + 1][r], f2 = t[c4 + 2][r], f3 = t[c4 + 3][r];
  short4 hp = make_short4((short)bf16_of(f0), (short)bf16_of(f1),
                          (short)bf16_of(f2), (short)bf16_of(f3));
  *(short4*)&Bt[(ll)(n0 + r) * K + k0 + c4] = hp;
}

// ---------------- MFMA GEMM: C[M,Nc] = (A_hi + A_lo) x W_hi, fused scores ----
template <int HBF16>
__global__ __launch_bounds__(256) void gemm_mfma_kernel(
    const short* __restrict__ A, const short* __restrict__ Bt,
    void* __restrict__ Cv, const float* __restrict__ a_src,
    const float* __restrict__ a_dst, float* __restrict__ partS,
    float* __restrict__ partD, int M, int Nc, int K) {
  __shared__ char Ah[8192];
  __shared__ char Al[8192];
  __shared__ char Bs[8192];
  int tid = threadIdx.x;

  int nwg = gridDim.x * gridDim.y;
  int hb = blockIdx.y * gridDim.x + blockIdx.x;
  int xcd = hb & 7, q = nwg >> 3, r = nwg & 7;
  int lg = (xcd < r ? xcd * (q + 1) : r * (q + 1) + (xcd - r) * q) + (hb >> 3);
  int bx = lg % gridDim.x, by = lg / gridDim.x;
  int bm = by * 128, bn = bx * 128;

  int lane = tid & 63, wid = tid >> 6;
  int wr = wid >> 1, wc = wid & 1;
  int K2 = 2 * K;

  f32x4 acc[4][4];
#pragma unroll
  for (int m = 0; m < 4; ++m)
#pragma unroll
    for (int n = 0; n < 4; ++n) acc[m][n] = (f32x4){0.f, 0.f, 0.f, 0.f};

  int srow = tid >> 2;                 // 0..63
  int cphys = tid & 3;                 // LDS chunk slot this thread fills
  int swz = (srow >> 1) & 3;
  int clog = (cphys ^ swz) * 8;        // bf16 k-offset actually fetched
  int ra = bm + srow;       if (ra > M - 1) ra = M - 1;
  int rb = bm + srow + 64;  if (rb > M - 1) rb = M - 1;
  const short* aP0 = A + (ll)ra * K2 + clog;
  const short* aP1 = A + (ll)rb * K2 + clog;
  const short* bP0 = Bt + (ll)(bn + srow) * K + clog;
  const short* bP1 = Bt + (ll)(bn + srow + 64) * K + clog;
  int dstOff = tid * 16;

  int lrow = lane & 15;
  int lchunk = ((lane >> 4) ^ ((lrow >> 1) & 3)) * 16;
  int fOffA = (wr * 64 + lrow) * 64 + lchunk;
  int fOffB = (wc * 64 + lrow) * 64 + lchunk;

  for (int kt = 0; kt < K; kt += 32) {
    gload16(aP0 + kt, Ah + dstOff);
    gload16(aP1 + kt, Ah + 4096 + dstOff);
    gload16(aP0 + K + kt, Al + dstOff);
    gload16(aP1 + K + kt, Al + 4096 + dstOff);
    gload16(bP0 + kt, Bs + dstOff);
    gload16(bP1 + kt, Bs + 4096 + dstOff);
    __syncthreads();
    bf16x8 ah[4], al[4], bfr[4];
#pragma unroll
    for (int m = 0; m < 4; ++m) {
      ah[m] = *(const bf16x8*)(Ah + fOffA + m * 1024);
      al[m] = *(const bf16x8*)(Al + fOffA + m * 1024);
    }
#pragma unroll
    for (int n = 0; n < 4; ++n) bfr[n] = *(const bf16x8*)(Bs + fOffB + n * 1024);
#pragma unroll
    for (int m = 0; m < 4; ++m)
#pragma unroll
      for (int n = 0; n < 4; ++n) {
        acc[m][n] = __builtin_amdgcn_mfma_f32_16x16x32_bf16(ah[m], bfr[n], acc[m][n], 0, 0, 0);
        acc[m][n] = __builtin_amdgcn_mfma_f32_16x16x32_bf16(al[m], bfr[n], acc[m][n], 0, 0, 0);
      }
    __syncthreads();
  }

  int crow0 = bm + wr * 64 + (lane >> 4) * 4;
  int ccol0 = bn + wc * 64 + (lane & 15);
#pragma unroll
  for (int m = 0; m < 4; ++m) {
#pragma unroll
    for (int j = 0; j < 4; ++j) {
      int row = crow0 + m * 16 + j;
      if (row < M) {
#pragma unroll
        for (int n = 0; n < 4; ++n) {
          if (HBF16) ((unsigned short*)Cv)[(ll)row * Nc + ccol0 + n * 16] = bf16_of(acc[m][n][j]);
          else       ((float*)Cv)[(ll)row * Nc + ccol0 + n * 16] = acc[m][n][j];
        }
      }
    }
  }

  // fused partial attention scores
  float as4[4], ad4[4];
#pragma unroll
  for (int n = 0; n < 4; ++n) {
    as4[n] = a_src[ccol0 + n * 16];
    ad4[n] = a_dst[ccol0 + n * 16];
  }
  int p = bx * 2 + wc;
#pragma unroll
  for (int m = 0; m < 4; ++m) {
#pragma unroll
    for (int j = 0; j < 4; ++j) {
      float ps = acc[m][0][j] * as4[0] + acc[m][1][j] * as4[1] +
                 acc[m][2][j] * as4[2] + acc[m][3][j] * as4[3];
      float pd = acc[m][0][j] * ad4[0] + acc[m][1][j] * ad4[1] +
                 acc[m][2][j] * ad4[2] + acc[m][3][j] * ad4[3];
#pragma unroll
      for (int o = 1; o < 16; o <<= 1) {
        ps += __shfl_xor(ps, o, 64);
        pd += __shfl_xor(pd, o, 64);
      }
      int row = crow0 + m * 16 + j;
      if ((lane & 15) == 0 && row < M) {
        partS[(ll)p * M + row] = ps;
        partD[(ll)p * M + row] = pd;
      }
    }
  }
}

// sum the per-(col-block,wc) partials -> s_src/s_dst
__global__ void score_reduce_kernel(const float* __restrict__ partS,
                                    const float* __restrict__ partD,
                                    float* __restrict__ s_src, float* __restrict__ s_dst,
                                    int N, int NP) {
  int i = blockIdx.x * blockDim.x + threadIdx.x;
  if (i >= N) return;
  float a = 0.f, b = 0.f;
  for (int p = 0; p < NP; ++p) {
    a += partS[(ll)p * N + i];
    b += partD[(ll)p * N + i];
  }
  s_src[i] = a;
  s_dst[i] = b;
}

// ---------------- wave-per-node fused softmax + weighted aggregation --------
// One 64-lane wave per node. Fast path (deg <= 64, ~always for this graph):
// one edge per lane, softmax entirely in registers via shfl_xor; then per
// edge broadcast (src, alpha) via uniform-index shfl and gather 16B/lane
// contiguous row segments (full coalescing), unrolled x2. No LDS, no
// barriers, no separate alpha pass.
template <int DOUT, int HIN_BF16, int OUTSPLIT>
__global__ __launch_bounds__(256) void agg_wave_kernel(
    const void* __restrict__ hv, const float* __restrict__ ssrc,
    const float* __restrict__ sdst, const int* __restrict__ rowptr,
    const int* __restrict__ csr, const float* __restrict__ bias,
    float* __restrict__ outF, short* __restrict__ outH, int N) {
  constexpr int NH = (DOUT >= 512) ? DOUT / 512 : 1;   // row halves of 512 dims
  constexpr int DPL = (DOUT >= 512) ? 8 : DOUT / 64;   // dims/lane per half
  int wid = threadIdx.x >> 6, lane = threadIdx.x & 63;
  int node = blockIdx.x * 4 + wid;
  if (node >= N) return;
  int rs = rowptr[node];
  int nd = rowptr[node + 1] - rs;
  float sd = sdst[node];
  int d0 = lane * DPL;

  float acc[NH][DPL];
#pragma unroll
  for (int hh = 0; hh < NH; ++hh)
#pragma unroll
    for (int k = 0; k < DPL; ++k) acc[hh][k] = 0.f;

  auto accum = [&](int s, float w) {
    if constexpr (HIN_BF16) {
      const unsigned short* hp = (const unsigned short*)hv + (ll)s * DOUT + d0;
#pragma unroll
      for (int hh = 0; hh < NH; ++hh) {
        bf16x8 qv = *(const bf16x8*)(hp + hh * 512);
#pragma unroll
        for (int k = 0; k < 8; ++k)
          acc[hh][k] += w * bf16_back((unsigned short)qv[k]);
      }
    } else {
      const float* hp = (const float*)hv + (ll)s * DOUT + d0;
#pragma unroll
      for (int k = 0; k < DPL; ++k) acc[0][k] += w * hp[k];
    }
  };

  if (nd <= 64) {
    // in-register softmax: one edge per lane
    int srcl = 0;
    float e = -1e30f;
    if (lane < nd) {
      srcl = csr[rs + lane];
      float t = ssrc[srcl] + sd;
      e = t > 0.f ? t : NEG_SLOPE * t;
    }
    float m = e;
#pragma unroll
    for (int o = 32; o > 0; o >>= 1) m = fmaxf(m, __shfl_xor(m, o, 64));
    float ex = (lane < nd) ? __expf(e - m) : 0.f;
    float den = ex;
#pragma unroll
    for (int o = 32; o > 0; o >>= 1) den += __shfl_xor(den, o, 64);
    float al = ex / (den + EPS_F);

    int i = 0;
    for (; i + 2 <= nd; i += 2) {
      int s0 = __shfl(srcl, i, 64), s1 = __shfl(srcl, i + 1, 64);
      float w0 = __shfl(al, i, 64), w1 = __shfl(al, i + 1, 64);
      accum(s0, w0);
      accum(s1, w1);
    }
    if (i < nd) accum(__shfl(srcl, i, 64), __shfl(al, i, 64));
  } else {
    // rare fallback: strided 2-pass softmax + serial gather
    float m = -1e30f;
    for (int i = lane; i < nd; i += 64) {
      float t = ssrc[csr[rs + i]] + sd;
      t = t > 0.f ? t : NEG_SLOPE * t;
      m = fmaxf(m, t);
    }
#pragma unroll
    for (int o = 32; o > 0; o >>= 1) m = fmaxf(m, __shfl_xor(m, o, 64));
    float den = 0.f;
    for (int i = lane; i < nd; i += 64) {
      float t = ssrc[csr[rs + i]] + sd;
      t = t > 0.f ? t : NEG_SLOPE * t;
      den += __expf(t - m);
    }
#pragma unroll
    for (int o = 32; o > 0; o >>= 1) den += __shfl_xor(den, o, 64);
    float inv = 1.f / (den + EPS_F);
    for (int i = 0; i < nd; ++i) {
      int s = csr[rs + i];  // wave-uniform broadcast load
      float t = ssrc[s] + sd;
      t = t > 0.f ? t : NEG_SLOPE * t;
      accum(s, __expf(t - m) * inv);
    }
  }

  // epilogue: bias (+ReLU), store (split-bf16 for next GEMM, or fp32)
  if constexpr (OUTSPLIT) {
#pragma unroll
    for (int hh = 0; hh < NH; ++hh) {
      int d = hh * 512 + d0;
      bf16x8 hp8, lp8;
#pragma unroll
      for (int k = 0; k < 8; ++k) {
        float v = fmaxf(acc[hh][k] + bias[d + k], 0.f);
        unsigned short h0 = bf16_of(v);
        hp8[k] = (short)h0;
        lp8[k] = (short)bf16_of(v - bf16_back(h0));
      }
      *(bf16x8*)&outH[(ll)node * (2 * DOUT) + d] = hp8;
      *(bf16x8*)&outH[(ll)node * (2 * DOUT) + DOUT + d] = lp8;
    }
  } else {
#pragma unroll
    for (int k = 0; k < DPL; ++k) {
      float v = acc[0][k] + bias[d0 + k];
      outF[(ll)node * DOUT + d0 + k] = v;
    }
  }
}

// ---------------- row log_softmax (C == blockDim.x) ----------------
__global__ void log_softmax_kernel(const float* __restrict__ in, float* __restrict__ out,
                                   int C) {
  int row = blockIdx.x;
  int tid = threadIdx.x;
  int lane = tid & 63, wid = tid >> 6;
  __shared__ float red[2];
  float v = in[(ll)row * C + tid];
  float m = v;
#pragma unroll
  for (int o = 32; o > 0; o >>= 1) m = fmaxf(m, __shfl_xor(m, o, 64));
  if (lane == 0) red[wid] = m;
  __syncthreads();
  m = fmaxf(red[0], red[1]);
  __syncthreads();
  float ex = __expf(v - m);
  float s = ex;
#pragma unroll
  for (int o = 32; o > 0; o >>= 1) s += __shfl_xor(s, o, 64);
  if (lane == 0) red[wid] = s;
  __syncthreads();
  s = red[0] + red[1];
  out[(ll)row * C + tid] = v - m - logf(s);
}

// ---------------- launch ----------------
extern "C" void kernel_launch(void* const* d_in, const int* in_sizes, int n_in,
                              void* d_out, int out_size, void* d_ws, size_t ws_size,
                              hipStream_t stream) {
  const float* x = (const float*)d_in[0];
  const int* ew = (const int*)d_in[1];
  int N = in_sizes[0] / 256;
  int E = in_sizes[1] / 2;

  const float* W[4]   = {(const float*)d_in[2],  (const float*)d_in[6],
                         (const float*)d_in[10], (const float*)d_in[14]};
  const float* Asv[4] = {(const float*)d_in[3],  (const float*)d_in[7],
                         (const float*)d_in[11], (const float*)d_in[15]};
  const float* Adv[4] = {(const float*)d_in[4],  (const float*)d_in[8],
                         (const float*)d_in[12], (const float*)d_in[16]};
  const float* Bv[4]  = {(const float*)d_in[5],  (const float*)d_in[9],
                         (const float*)d_in[13], (const float*)d_in[17]};
  const int din[4]  = {256, 1024, 1024, 512};
  const int dout[4] = {1024, 1024, 512, 128};

  char* ws = (char*)d_ws;
  size_t off = 0;
  auto alloc = [&](size_t bytes) {
    void* p = ws + off;
    off += (bytes + 255) & ~(size_t)255;
    return p;
  };
  unsigned short* hB = (unsigned short*)alloc((size_t)N * 1024 * 2);  // bf16 h (layers 1-3)
  float* hF   = (float*)alloc((size_t)N * 128 * 4);                   // fp32 h (layer 4)
  short* bufP = (short*)alloc((size_t)N * 2048 * 2);
  short* bufQ = (short*)alloc((size_t)N * 2048 * 2);
  float* sF   = (float*)alloc((size_t)N * 128 * 4);
  float* s_src = (float*)alloc((size_t)N * 4);
  float* s_dst = (float*)alloc((size_t)N * 4);
  float* partS = (float*)alloc((size_t)16 * N * 4);
  float* partD = (float*)alloc((size_t)16 * N * 4);
  int* deg    = (int*)alloc((size_t)(N + 1) * 4);
  int* rowptr = (int*)alloc((size_t)(N + 1) * 4);
  int* cursor = (int*)alloc((size_t)(N + 1) * 4);
  int* csr    = (int*)alloc((size_t)(E + N) * 4);
  int* flag   = (int*)alloc(256);
  short* Bt[4];
  for (int l = 0; l < 4; ++l) Bt[l] = (short*)alloc((size_t)dout[l] * din[l] * 2);

  detect_int64_kernel<<<1, 256, 0, stream>>>((const unsigned int*)ew, E, flag);
  init_deg_kernel<<<(N + 255) / 256, 256, 0, stream>>>(deg, N);
  count_deg_kernel<<<(E + 255) / 256, 256, 0, stream>>>(ew, E, deg, flag);
  scan_kernel<<<1, 1024, 0, stream>>>(deg, rowptr, cursor, N);
  fill_kernel<<<(E + N + 255) / 256, 256, 0, stream>>>(ew, E, N, cursor, csr, flag);

  convert_x_kernel<<<(N * 256 + 255) / 256, 256, 0, stream>>>(x, bufP, N);
  for (int l = 0; l < 4; ++l) {
    dim3 cg(din[l] / 32, dout[l] / 32);
    convert_w_kernel<<<cg, 256, 0, stream>>>(W[l], Bt[l], din[l], dout[l]);
  }

  int ngrp = (N + 3) / 4;
  short* cur = bufP;
  short* nxt = bufQ;
  for (int l = 0; l < 4; ++l) {
    dim3 ggrid(dout[l] / 128, (N + 127) / 128);
    int NP = (dout[l] / 128) * 2;
    if (l < 3) {
      gemm_mfma_kernel<1><<<ggrid, 256, 0, stream>>>(cur, Bt[l], hB, Asv[l], Adv[l],
                                                     partS, partD, N, dout[l], din[l]);
    } else {
      gemm_mfma_kernel<0><<<ggrid, 256, 0, stream>>>(cur, Bt[l], hF, Asv[l], Adv[l],
                                                     partS, partD, N, dout[l], din[l]);
    }
    score_reduce_kernel<<<(N + 255) / 256, 256, 0, stream>>>(partS, partD, s_src, s_dst,
                                                             N, NP);
    if (l < 2) {
      agg_wave_kernel<1024, 1, 1><<<ngrp, 256, 0, stream>>>(
          hB, s_src, s_dst, rowptr, csr, Bv[l], nullptr, nxt, N);
    } else if (l == 2) {
      agg_wave_kernel<512, 1, 1><<<ngrp, 256, 0, stream>>>(
          hB, s_src, s_dst, rowptr, csr, Bv[l], nullptr, nxt, N);
    } else {
      agg_wave_kernel<128, 0, 0><<<ngrp, 256, 0, stream>>>(
          hF, s_src, s_dst, rowptr, csr, Bv[l], sF, nullptr, N);
    }
    short* t = cur; cur = nxt; nxt = t;
  }
  log_softmax_kernel<<<N, 128, 0, stream>>>(sF, (float*)d_out, 128);
}

// Round 9
// 352.756 us; speedup vs baseline: 1.2433x; 1.0433x over previous
//
#include <hip/hip_runtime.h>
#include <math.h>

#define NEG_SLOPE 0.2f
#define EPS_F 1e-16f
typedef long long ll;

typedef __attribute__((ext_vector_type(4))) float f32x4;
typedef __attribute__((ext_vector_type(8))) short bf16x8;

// ---------------- bf16 helpers (bit-level, RTN-even) ----------------
__device__ __forceinline__ unsigned short bf16_of(float f) {
  unsigned u = __float_as_uint(f);
  u += 0x7fffu + ((u >> 16) & 1u);
  return (unsigned short)(u >> 16);
}
__device__ __forceinline__ float bf16_back(unsigned short s) {
  return __uint_as_float((unsigned)s << 16);
}

__device__ __forceinline__ void gload16(const void* g, void* l) {
  __builtin_amdgcn_global_load_lds((const __attribute__((address_space(1))) void*)g,
                                   (__attribute__((address_space(3))) void*)l, 16, 0, 0);
}

// ---------------- edge dtype detection (int64 vs int32) ----------------
__global__ void detect_int64_kernel(const unsigned int* __restrict__ w, int E,
                                    int* __restrict__ flag) {
  __shared__ int nz;
  if (threadIdx.x == 0) nz = 0;
  __syncthreads();
  int cnt = E < 2048 ? E : 2048;
  int local = 0;
  for (int i = threadIdx.x; i < cnt; i += blockDim.x)
    if (w[2 * i + 1] != 0u) local++;
  if (local) atomicAdd(&nz, local);
  __syncthreads();
  if (threadIdx.x == 0) *flag = (nz == 0) ? 1 : 0;  // 1 => int64 layout
}

__device__ __forceinline__ void edge_at(const int* __restrict__ ew, int E, int e,
                                        int is64, int& s, int& d) {
  if (is64) { s = ew[2 * e]; d = ew[2 * E + 2 * e]; }
  else      { s = ew[e];     d = ew[E + e]; }
}

// ---------------- CSR build (deg holds edge-count only; +1 self-loop in scan) ----
__global__ void count_deg_kernel(const int* __restrict__ ew, int E, int* deg,
                                 const int* __restrict__ flag) {
  int is64 = *flag;
  int e = blockIdx.x * blockDim.x + threadIdx.x;
  if (e < E) {
    int s, d;
    edge_at(ew, E, e, is64, s, d);
    atomicAdd(&deg[d], 1);
  }
}

__global__ void scan_kernel(const int* __restrict__ deg, int* rowptr, int* cursor, int N) {
  __shared__ int sums[1024];
  int tid = threadIdx.x;
  int chunk = (N + 1023) >> 10;
  int start = tid * chunk;
  int end = start + chunk; if (end > N) end = N;
  int s = 0;
  for (int i = start; i < end; ++i) s += deg[i] + 1;  // +1 = self loop
  sums[tid] = s;
  __syncthreads();
  for (int off = 1; off < 1024; off <<= 1) {
    int v = (tid >= off) ? sums[tid - off] : 0;
    __syncthreads();
    sums[tid] += v;
    __syncthreads();
  }
  int run = (tid == 0) ? 0 : sums[tid - 1];
  for (int i = start; i < end; ++i) {
    rowptr[i] = run; cursor[i] = run;
    run += deg[i] + 1;
  }
  if (tid == 1023) rowptr[N] = sums[1023];
}

__global__ void fill_kernel(const int* __restrict__ ew, int E, int N, int* cursor,
                            int* csr, const int* __restrict__ flag) {
  int is64 = *flag;
  int i = blockIdx.x * blockDim.x + threadIdx.x;
  if (i < E) {
    int s, d;
    edge_at(ew, E, i, is64, s, d);
    int pos = atomicAdd(&cursor[d], 1);
    csr[pos] = s;
  } else if (i < E + N) {
    int n = i - E;
    int pos = atomicAdd(&cursor[n], 1);
    csr[pos] = n;
  }
}

// ---------------- input conversions to split-bf16 ----------------
__global__ void convert_x_kernel(const float* __restrict__ x, short* __restrict__ A, int N) {
  int i = blockIdx.x * blockDim.x + threadIdx.x;
  if (i >= N * 256) return;
  int r = i >> 8, c = i & 255;
  float v = x[i];
  unsigned short hi = bf16_of(v);
  unsigned short lo = bf16_of(v - bf16_back(hi));
  A[(ll)r * 512 + c] = (short)hi;
  A[(ll)r * 512 + 256 + c] = (short)lo;
}

// all 4 W [K, Nc] fp32 -> Bt [Nc, K] bf16 (W_hi^T), one dispatch (z = layer)
__global__ __launch_bounds__(256) void convert_w_all_kernel(
    const float* __restrict__ W0, const float* __restrict__ W1,
    const float* __restrict__ W2, const float* __restrict__ W3,
    short* __restrict__ B0, short* __restrict__ B1,
    short* __restrict__ B2, short* __restrict__ B3) {
  const int Ks[4]  = {256, 1024, 1024, 512};
  const int Ncs[4] = {1024, 1024, 512, 128};
  int z = blockIdx.z;
  int K = Ks[z], Nc = Ncs[z];
  int k0 = blockIdx.x * 32, n0 = blockIdx.y * 32;
  if (k0 >= K || n0 >= Nc) return;
  const float* W = z == 0 ? W0 : (z == 1 ? W1 : (z == 2 ? W2 : W3));
  short* Bt = z == 0 ? B0 : (z == 1 ? B1 : (z == 2 ? B2 : B3));
  __shared__ float t[32][33];
  int r = threadIdx.x >> 3;          // 0..31
  int c4 = (threadIdx.x & 7) * 4;    // 0..28
  float4 v = *(const float4*)&W[(ll)(k0 + r) * Nc + n0 + c4];
  t[r][c4] = v.x; t[r][c4 + 1] = v.y; t[r][c4 + 2] = v.z; t[r][c4 + 3] = v.w;
  __syncthreads();
  float f0 = t[c4 + 0][r], f1 = t[c4 + 1][r], f2 = t[c4 + 2][r], f3 = t[c4 + 3][r];
  short4 hp = make_short4((short)bf16_of(f0), (short)bf16_of(f1),
                          (short)bf16_of(f2), (short)bf16_of(f3));
  *(short4*)&Bt[(ll)(n0 + r) * K + k0 + c4] = hp;
}

// ---------------- MFMA GEMM: C[M,Nc] = (A_hi + A_lo) x W_hi, fused scores ----
template <int HBF16>
__global__ __launch_bounds__(256) void gemm_mfma_kernel(
    const short* __restrict__ A, const short* __restrict__ Bt,
    void* __restrict__ Cv, const float* __restrict__ a_src,
    const float* __restrict__ a_dst, float* __restrict__ partS,
    float* __restrict__ partD, int M, int Nc, int K) {
  __shared__ char Ah[8192];
  __shared__ char Al[8192];
  __shared__ char Bs[8192];
  int tid = threadIdx.x;

  int nwg = gridDim.x * gridDim.y;
  int hb = blockIdx.y * gridDim.x + blockIdx.x;
  int xcd = hb & 7, q = nwg >> 3, r = nwg & 7;
  int lg = (xcd < r ? xcd * (q + 1) : r * (q + 1) + (xcd - r) * q) + (hb >> 3);
  int bx = lg % gridDim.x, by = lg / gridDim.x;
  int bm = by * 128, bn = bx * 128;

  int lane = tid & 63, wid = tid >> 6;
  int wr = wid >> 1, wc = wid & 1;
  int K2 = 2 * K;

  f32x4 acc[4][4];
#pragma unroll
  for (int m = 0; m < 4; ++m)
#pragma unroll
    for (int n = 0; n < 4; ++n) acc[m][n] = (f32x4){0.f, 0.f, 0.f, 0.f};

  int srow = tid >> 2;                 // 0..63
  int cphys = tid & 3;                 // LDS chunk slot this thread fills
  int swz = (srow >> 1) & 3;
  int clog = (cphys ^ swz) * 8;        // bf16 k-offset actually fetched
  int ra = bm + srow;       if (ra > M - 1) ra = M - 1;
  int rb = bm + srow + 64;  if (rb > M - 1) rb = M - 1;
  const short* aP0 = A + (ll)ra * K2 + clog;
  const short* aP1 = A + (ll)rb * K2 + clog;
  const short* bP0 = Bt + (ll)(bn + srow) * K + clog;
  const short* bP1 = Bt + (ll)(bn + srow + 64) * K + clog;
  int dstOff = tid * 16;

  int lrow = lane & 15;
  int lchunk = ((lane >> 4) ^ ((lrow >> 1) & 3)) * 16;
  int fOffA = (wr * 64 + lrow) * 64 + lchunk;
  int fOffB = (wc * 64 + lrow) * 64 + lchunk;

  for (int kt = 0; kt < K; kt += 32) {
    gload16(aP0 + kt, Ah + dstOff);
    gload16(aP1 + kt, Ah + 4096 + dstOff);
    gload16(aP0 + K + kt, Al + dstOff);
    gload16(aP1 + K + kt, Al + 4096 + dstOff);
    gload16(bP0 + kt, Bs + dstOff);
    gload16(bP1 + kt, Bs + 4096 + dstOff);
    __syncthreads();
    bf16x8 ah[4], al[4], bfr[4];
#pragma unroll
    for (int m = 0; m < 4; ++m) {
      ah[m] = *(const bf16x8*)(Ah + fOffA + m * 1024);
      al[m] = *(const bf16x8*)(Al + fOffA + m * 1024);
    }
#pragma unroll
    for (int n = 0; n < 4; ++n) bfr[n] = *(const bf16x8*)(Bs + fOffB + n * 1024);
#pragma unroll
    for (int m = 0; m < 4; ++m)
#pragma unroll
      for (int n = 0; n < 4; ++n) {
        acc[m][n] = __builtin_amdgcn_mfma_f32_16x16x32_bf16(ah[m], bfr[n], acc[m][n], 0, 0, 0);
        acc[m][n] = __builtin_amdgcn_mfma_f32_16x16x32_bf16(al[m], bfr[n], acc[m][n], 0, 0, 0);
      }
    __syncthreads();
  }

  int crow0 = bm + wr * 64 + (lane >> 4) * 4;
  int ccol0 = bn + wc * 64 + (lane & 15);
#pragma unroll
  for (int m = 0; m < 4; ++m) {
#pragma unroll
    for (int j = 0; j < 4; ++j) {
      int row = crow0 + m * 16 + j;
      if (row < M) {
#pragma unroll
        for (int n = 0; n < 4; ++n) {
          if (HBF16) ((unsigned short*)Cv)[(ll)row * Nc + ccol0 + n * 16] = bf16_of(acc[m][n][j]);
          else       ((float*)Cv)[(ll)row * Nc + ccol0 + n * 16] = acc[m][n][j];
        }
      }
    }
  }

  // fused partial attention scores
  float as4[4], ad4[4];
#pragma unroll
  for (int n = 0; n < 4; ++n) {
    as4[n] = a_src[ccol0 + n * 16];
    ad4[n] = a_dst[ccol0 + n * 16];
  }
  int p = bx * 2 + wc;
#pragma unroll
  for (int m = 0; m < 4; ++m) {
#pragma unroll
    for (int j = 0; j < 4; ++j) {
      float ps = acc[m][0][j] * as4[0] + acc[m][1][j] * as4[1] +
                 acc[m][2][j] * as4[2] + acc[m][3][j] * as4[3];
      float pd = acc[m][0][j] * ad4[0] + acc[m][1][j] * ad4[1] +
                 acc[m][2][j] * ad4[2] + acc[m][3][j] * ad4[3];
#pragma unroll
      for (int o = 1; o < 16; o <<= 1) {
        ps += __shfl_xor(ps, o, 64);
        pd += __shfl_xor(pd, o, 64);
      }
      int row = crow0 + m * 16 + j;
      if ((lane & 15) == 0 && row < M) {
        partS[(ll)p * M + row] = ps;
        partD[(ll)p * M + row] = pd;
      }
    }
  }
}

// sum the per-(col-block,wc) partials -> s_src/s_dst
__global__ void score_reduce_kernel(const float* __restrict__ partS,
                                    const float* __restrict__ partD,
                                    float* __restrict__ s_src, float* __restrict__ s_dst,
                                    int N, int NP) {
  int i = blockIdx.x * blockDim.x + threadIdx.x;
  if (i >= N) return;
  float a = 0.f, b = 0.f;
  for (int p = 0; p < NP; ++p) {
    a += partS[(ll)p * N + i];
    b += partD[(ll)p * N + i];
  }
  s_src[i] = a;
  s_dst[i] = b;
}

// ---------------- wave-per-node fused softmax + weighted aggregation --------
// One 64-lane wave per node; softmax in registers (shfl_xor); per-edge
// broadcast (src, alpha) via uniform shfl; 16B/lane coalesced gathers,
// unrolled x4. LOGSM: fuse row log_softmax (DOUT=128 only) and write d_out.
template <int DOUT, int HIN_BF16, int OUTSPLIT, int LOGSM>
__global__ __launch_bounds__(256) void agg_wave_kernel(
    const void* __restrict__ hv, const float* __restrict__ ssrc,
    const float* __restrict__ sdst, const int* __restrict__ rowptr,
    const int* __restrict__ csr, const float* __restrict__ bias,
    float* __restrict__ outF, short* __restrict__ outH, int N) {
  constexpr int NH = (DOUT >= 512) ? DOUT / 512 : 1;   // row halves of 512 dims
  constexpr int DPL = (DOUT >= 512) ? 8 : DOUT / 64;   // dims/lane per half
  int wid = threadIdx.x >> 6, lane = threadIdx.x & 63;
  int node = blockIdx.x * 4 + wid;
  if (node >= N) return;
  int rs = rowptr[node];
  int nd = rowptr[node + 1] - rs;
  float sd = sdst[node];
  int d0 = lane * DPL;

  float acc[NH][DPL];
#pragma unroll
  for (int hh = 0; hh < NH; ++hh)
#pragma unroll
    for (int k = 0; k < DPL; ++k) acc[hh][k] = 0.f;

  auto accum = [&](int s, float w) {
    if constexpr (HIN_BF16) {
      const unsigned short* hp = (const unsigned short*)hv + (ll)s * DOUT + d0;
#pragma unroll
      for (int hh = 0; hh < NH; ++hh) {
        bf16x8 qv = *(const bf16x8*)(hp + hh * 512);
#pragma unroll
        for (int k = 0; k < 8; ++k)
          acc[hh][k] += w * bf16_back((unsigned short)qv[k]);
      }
    } else {
      const float* hp = (const float*)hv + (ll)s * DOUT + d0;
#pragma unroll
      for (int k = 0; k < DPL; ++k) acc[0][k] += w * hp[k];
    }
  };

  if (nd <= 64) {
    // in-register softmax: one edge per lane
    int srcl = 0;
    float e = -1e30f;
    if (lane < nd) {
      srcl = csr[rs + lane];
      float t = ssrc[srcl] + sd;
      e = t > 0.f ? t : NEG_SLOPE * t;
    }
    float m = e;
#pragma unroll
    for (int o = 32; o > 0; o >>= 1) m = fmaxf(m, __shfl_xor(m, o, 64));
    float ex = (lane < nd) ? __expf(e - m) : 0.f;
    float den = ex;
#pragma unroll
    for (int o = 32; o > 0; o >>= 1) den += __shfl_xor(den, o, 64);
    float al = ex / (den + EPS_F);

    int i = 0;
    for (; i + 4 <= nd; i += 4) {
      int s0 = __shfl(srcl, i, 64), s1 = __shfl(srcl, i + 1, 64);
      int s2 = __shfl(srcl, i + 2, 64), s3 = __shfl(srcl, i + 3, 64);
      float w0 = __shfl(al, i, 64), w1 = __shfl(al, i + 1, 64);
      float w2 = __shfl(al, i + 2, 64), w3 = __shfl(al, i + 3, 64);
      accum(s0, w0);
      accum(s1, w1);
      accum(s2, w2);
      accum(s3, w3);
    }
    for (; i < nd; ++i) accum(__shfl(srcl, i, 64), __shfl(al, i, 64));
  } else {
    // rare fallback: strided 2-pass softmax + serial gather
    float m = -1e30f;
    for (int i = lane; i < nd; i += 64) {
      float t = ssrc[csr[rs + i]] + sd;
      t = t > 0.f ? t : NEG_SLOPE * t;
      m = fmaxf(m, t);
    }
#pragma unroll
    for (int o = 32; o > 0; o >>= 1) m = fmaxf(m, __shfl_xor(m, o, 64));
    float den = 0.f;
    for (int i = lane; i < nd; i += 64) {
      float t = ssrc[csr[rs + i]] + sd;
      t = t > 0.f ? t : NEG_SLOPE * t;
      den += __expf(t - m);
    }
#pragma unroll
    for (int o = 32; o > 0; o >>= 1) den += __shfl_xor(den, o, 64);
    float inv = 1.f / (den + EPS_F);
    for (int i = 0; i < nd; ++i) {
      int s = csr[rs + i];  // wave-uniform broadcast load
      float t = ssrc[s] + sd;
      t = t > 0.f ? t : NEG_SLOPE * t;
      accum(s, __expf(t - m) * inv);
    }
  }

  // epilogue
  if constexpr (OUTSPLIT) {
#pragma unroll
    for (int hh = 0; hh < NH; ++hh) {
      int d = hh * 512 + d0;
      bf16x8 hp8, lp8;
#pragma unroll
      for (int k = 0; k < 8; ++k) {
        float v = fmaxf(acc[hh][k] + bias[d + k], 0.f);
        unsigned short h0 = bf16_of(v);
        hp8[k] = (short)h0;
        lp8[k] = (short)bf16_of(v - bf16_back(h0));
      }
      *(bf16x8*)&outH[(ll)node * (2 * DOUT) + d] = hp8;
      *(bf16x8*)&outH[(ll)node * (2 * DOUT) + DOUT + d] = lp8;
    }
  } else if constexpr (LOGSM) {
    // fused row log_softmax over DOUT=128 (2 dims/lane, one wave = one row)
    float v0 = acc[0][0] + bias[d0 + 0];
    float v1 = acc[0][1] + bias[d0 + 1];
    float mx = fmaxf(v0, v1);
#pragma unroll
    for (int o = 32; o > 0; o >>= 1) mx = fmaxf(mx, __shfl_xor(mx, o, 64));
    float s = __expf(v0 - mx) + __expf(v1 - mx);
#pragma unroll
    for (int o = 32; o > 0; o >>= 1) s += __shfl_xor(s, o, 64);
    float ls = logf(s);
    outF[(ll)node * DOUT + d0 + 0] = v0 - mx - ls;
    outF[(ll)node * DOUT + d0 + 1] = v1 - mx - ls;
  } else {
#pragma unroll
    for (int k = 0; k < DPL; ++k)
      outF[(ll)node * DOUT + d0 + k] = acc[0][k] + bias[d0 + k];
  }
}

// ---------------- launch ----------------
extern "C" void kernel_launch(void* const* d_in, const int* in_sizes, int n_in,
                              void* d_out, int out_size, void* d_ws, size_t ws_size,
                              hipStream_t stream) {
  const float* x = (const float*)d_in[0];
  const int* ew = (const int*)d_in[1];
  int N = in_sizes[0] / 256;
  int E = in_sizes[1] / 2;

  const float* W[4]   = {(const float*)d_in[2],  (const float*)d_in[6],
                         (const float*)d_in[10], (const float*)d_in[14]};
  const float* Asv[4] = {(const float*)d_in[3],  (const float*)d_in[7],
                         (const float*)d_in[11], (const float*)d_in[15]};
  const float* Adv[4] = {(const float*)d_in[4],  (const float*)d_in[8],
                         (const float*)d_in[12], (const float*)d_in[16]};
  const float* Bv[4]  = {(const float*)d_in[5],  (const float*)d_in[9],
                         (const float*)d_in[13], (const float*)d_in[17]};
  const int din[4]  = {256, 1024, 1024, 512};
  const int dout[4] = {1024, 1024, 512, 128};

  char* ws = (char*)d_ws;
  size_t off = 0;
  auto alloc = [&](size_t bytes) {
    void* p = ws + off;
    off += (bytes + 255) & ~(size_t)255;
    return p;
  };
  unsigned short* hB = (unsigned short*)alloc((size_t)N * 1024 * 2);  // bf16 h (layers 1-3)
  float* hF   = (float*)alloc((size_t)N * 128 * 4);                   // fp32 h (layer 4)
  short* bufP = (short*)alloc((size_t)N * 2048 * 2);
  short* bufQ = (short*)alloc((size_t)N * 2048 * 2);
  float* s_src = (float*)alloc((size_t)N * 4);
  float* s_dst = (float*)alloc((size_t)N * 4);
  float* partS = (float*)alloc((size_t)16 * N * 4);
  float* partD = (float*)alloc((size_t)16 * N * 4);
  int* deg    = (int*)alloc((size_t)(N + 1) * 4);
  int* rowptr = (int*)alloc((size_t)(N + 1) * 4);
  int* cursor = (int*)alloc((size_t)(N + 1) * 4);
  int* csr    = (int*)alloc((size_t)(E + N) * 4);
  int* flag   = (int*)alloc(256);
  short* Bt[4];
  for (int l = 0; l < 4; ++l) Bt[l] = (short*)alloc((size_t)dout[l] * din[l] * 2);

  detect_int64_kernel<<<1, 256, 0, stream>>>((const unsigned int*)ew, E, flag);
  hipMemsetAsync(deg, 0, (size_t)(N + 1) * 4, stream);
  count_deg_kernel<<<(E + 255) / 256, 256, 0, stream>>>(ew, E, deg, flag);
  scan_kernel<<<1, 1024, 0, stream>>>(deg, rowptr, cursor, N);
  fill_kernel<<<(E + N + 255) / 256, 256, 0, stream>>>(ew, E, N, cursor, csr, flag);

  convert_x_kernel<<<(N * 256 + 255) / 256, 256, 0, stream>>>(x, bufP, N);
  {
    dim3 cg(32, 32, 4);
    convert_w_all_kernel<<<cg, 256, 0, stream>>>(W[0], W[1], W[2], W[3],
                                                 Bt[0], Bt[1], Bt[2], Bt[3]);
  }

  int ngrp = (N + 3) / 4;
  short* cur = bufP;
  short* nxt = bufQ;
  for (int l = 0; l < 4; ++l) {
    dim3 ggrid(dout[l] / 128, (N + 127) / 128);
    int NP = (dout[l] / 128) * 2;
    if (l < 3) {
      gemm_mfma_kernel<1><<<ggrid, 256, 0, stream>>>(cur, Bt[l], hB, Asv[l], Adv[l],
                                                     partS, partD, N, dout[l], din[l]);
    } else {
      gemm_mfma_kernel<0><<<ggrid, 256, 0, stream>>>(cur, Bt[l], hF, Asv[l], Adv[l],
                                                     partS, partD, N, dout[l], din[l]);
    }
    score_reduce_kernel<<<(N + 255) / 256, 256, 0, stream>>>(partS, partD, s_src, s_dst,
                                                             N, NP);
    if (l < 2) {
      agg_wave_kernel<1024, 1, 1, 0><<<ngrp, 256, 0, stream>>>(
          hB, s_src, s_dst, rowptr, csr, Bv[l], nullptr, nxt, N);
    } else if (l == 2) {
      agg_wave_kernel<512, 1, 1, 0><<<ngrp, 256, 0, stream>>>(
          hB, s_src, s_dst, rowptr, csr, Bv[l], nullptr, nxt, N);
    } else {
      agg_wave_kernel<128, 0, 0, 1><<<ngrp, 256, 0, stream>>>(
          hF, s_src, s_dst, rowptr, csr, Bv[l], (float*)d_out, nullptr, N);
    }
    short* t = cur; cur = nxt; nxt = t;
  }
}

// Round 10
// 315.288 us; speedup vs baseline: 1.3911x; 1.1188x over previous
//
#include <hip/hip_runtime.h>
#include <math.h>

#define NEG_SLOPE 0.2f
#define EPS_F 1e-16f
typedef long long ll;

typedef __attribute__((ext_vector_type(4))) float f32x4;
typedef __attribute__((ext_vector_type(8))) short bf16x8;

// ---------------- bf16 helpers (bit-level, RTN-even) ----------------
__device__ __forceinline__ unsigned short bf16_of(float f) {
  unsigned u = __float_as_uint(f);
  u += 0x7fffu + ((u >> 16) & 1u);
  return (unsigned short)(u >> 16);
}
__device__ __forceinline__ float bf16_back(unsigned short s) {
  return __uint_as_float((unsigned)s << 16);
}

__device__ __forceinline__ void gload16(const void* g, void* l) {
  __builtin_amdgcn_global_load_lds((const __attribute__((address_space(1))) void*)g,
                                   (__attribute__((address_space(3))) void*)l, 16, 0, 0);
}

// ---------------- edge dtype detection (int64 vs int32) ----------------
__global__ void detect_int64_kernel(const unsigned int* __restrict__ w, int E,
                                    int* __restrict__ flag) {
  __shared__ int nz;
  if (threadIdx.x == 0) nz = 0;
  __syncthreads();
  int cnt = E < 2048 ? E : 2048;
  int local = 0;
  for (int i = threadIdx.x; i < cnt; i += blockDim.x)
    if (w[2 * i + 1] != 0u) local++;
  if (local) atomicAdd(&nz, local);
  __syncthreads();
  if (threadIdx.x == 0) *flag = (nz == 0) ? 1 : 0;  // 1 => int64 layout
}

__device__ __forceinline__ void edge_at(const int* __restrict__ ew, int E, int e,
                                        int is64, int& s, int& d) {
  if (is64) { s = ew[2 * e]; d = ew[2 * E + 2 * e]; }
  else      { s = ew[e];     d = ew[E + e]; }
}

// ---------------- CSR build (deg holds edge-count only; +1 self-loop in scan) ----
__global__ void count_deg_kernel(const int* __restrict__ ew, int E, int* deg,
                                 const int* __restrict__ flag) {
  int is64 = *flag;
  int e = blockIdx.x * blockDim.x + threadIdx.x;
  if (e < E) {
    int s, d;
    edge_at(ew, E, e, is64, s, d);
    atomicAdd(&deg[d], 1);
  }
}

__global__ void scan_kernel(const int* __restrict__ deg, int* rowptr, int* cursor, int N) {
  __shared__ int sums[1024];
  int tid = threadIdx.x;
  int chunk = (N + 1023) >> 10;
  int start = tid * chunk;
  int end = start + chunk; if (end > N) end = N;
  int s = 0;
  for (int i = start; i < end; ++i) s += deg[i] + 1;  // +1 = self loop
  sums[tid] = s;
  __syncthreads();
  for (int off = 1; off < 1024; off <<= 1) {
    int v = (tid >= off) ? sums[tid - off] : 0;
    __syncthreads();
    sums[tid] += v;
    __syncthreads();
  }
  int run = (tid == 0) ? 0 : sums[tid - 1];
  for (int i = start; i < end; ++i) {
    rowptr[i] = run; cursor[i] = run;
    run += deg[i] + 1;
  }
  if (tid == 1023) rowptr[N] = sums[1023];
}

__global__ void fill_kernel(const int* __restrict__ ew, int E, int N, int* cursor,
                            int* csr, const int* __restrict__ flag) {
  int is64 = *flag;
  int i = blockIdx.x * blockDim.x + threadIdx.x;
  if (i < E) {
    int s, d;
    edge_at(ew, E, i, is64, s, d);
    int pos = atomicAdd(&cursor[d], 1);
    csr[pos] = s;
  } else if (i < E + N) {
    int n = i - E;
    int pos = atomicAdd(&cursor[n], 1);
    csr[pos] = n;
  }
}

// ---------------- input conversions ----------------
// x [N,256] fp32 -> split bf16 [N, 512] ([hi|lo]) for the layer-1 GEMM
__global__ void convert_x_kernel(const float* __restrict__ x, short* __restrict__ A, int N) {
  int i = blockIdx.x * blockDim.x + threadIdx.x;
  if (i >= N * 256) return;
  int r = i >> 8, c = i & 255;
  float v = x[i];
  unsigned short hi = bf16_of(v);
  unsigned short lo = bf16_of(v - bf16_back(hi));
  A[(ll)r * 512 + c] = (short)hi;
  A[(ll)r * 512 + 256 + c] = (short)lo;
}

// all 4 W [K, Nc] fp32 -> Bt [Nc, K] bf16 (W_hi^T), one dispatch (z = layer)
__global__ __launch_bounds__(256) void convert_w_all_kernel(
    const float* __restrict__ W0, const float* __restrict__ W1,
    const float* __restrict__ W2, const float* __restrict__ W3,
    short* __restrict__ B0, short* __restrict__ B1,
    short* __restrict__ B2, short* __restrict__ B3) {
  const int Ks[4]  = {256, 1024, 1024, 512};
  const int Ncs[4] = {1024, 1024, 512, 128};
  int z = blockIdx.z;
  int K = Ks[z], Nc = Ncs[z];
  int k0 = blockIdx.x * 32, n0 = blockIdx.y * 32;
  if (k0 >= K || n0 >= Nc) return;
  const float* W = z == 0 ? W0 : (z == 1 ? W1 : (z == 2 ? W2 : W3));
  short* Bt = z == 0 ? B0 : (z == 1 ? B1 : (z == 2 ? B2 : B3));
  __shared__ float t[32][33];
  int r = threadIdx.x >> 3;          // 0..31
  int c4 = (threadIdx.x & 7) * 4;    // 0..28
  float4 v = *(const float4*)&W[(ll)(k0 + r) * Nc + n0 + c4];
  t[r][c4] = v.x; t[r][c4 + 1] = v.y; t[r][c4 + 2] = v.z; t[r][c4 + 3] = v.w;
  __syncthreads();
  float f0 = t[c4 + 0][r], f1 = t[c4 + 1][r], f2 = t[c4 + 2][r], f3 = t[c4 + 3][r];
  short4 hp = make_short4((short)bf16_of(f0), (short)bf16_of(f1),
                          (short)bf16_of(f2), (short)bf16_of(f3));
  *(short4*)&Bt[(ll)(n0 + r) * K + k0 + c4] = hp;
}

// ---------------- MFMA GEMM + fused scores ----------------
// SPLIT=1: A is [M,2K] bf16 ([hi|lo]), C = (A_hi+A_lo) x W_hi (layer 1).
// SPLIT=0: A is [M,K] plain bf16, C = A x W_hi (layers 2-4).
// LDS: row-major [128][4 x 16B], chunk XOR-rotated per row pair; XCD-chunked
// bijective block swizzle; epilogue computes per-row partial attention dots.
template <int HBF16, int SPLIT>
__global__ __launch_bounds__(256) void gemm_mfma_kernel(
    const short* __restrict__ A, const short* __restrict__ Bt,
    void* __restrict__ Cv, const float* __restrict__ a_src,
    const float* __restrict__ a_dst, float* __restrict__ partS,
    float* __restrict__ partD, int M, int Nc, int K) {
  __shared__ char Ah[SPLIT ? 16384 : 8192];
  __shared__ char Bs[8192];
  char* Al = Ah + 8192;  // valid only when SPLIT
  int tid = threadIdx.x;

  int nwg = gridDim.x * gridDim.y;
  int hb = blockIdx.y * gridDim.x + blockIdx.x;
  int xcd = hb & 7, q = nwg >> 3, r = nwg & 7;
  int lg = (xcd < r ? xcd * (q + 1) : r * (q + 1) + (xcd - r) * q) + (hb >> 3);
  int bx = lg % gridDim.x, by = lg / gridDim.x;
  int bm = by * 128, bn = bx * 128;

  int lane = tid & 63, wid = tid >> 6;
  int wr = wid >> 1, wc = wid & 1;
  int AS = SPLIT ? 2 * K : K;  // A row stride

  f32x4 acc[4][4];
#pragma unroll
  for (int m = 0; m < 4; ++m)
#pragma unroll
    for (int n = 0; n < 4; ++n) acc[m][n] = (f32x4){0.f, 0.f, 0.f, 0.f};

  int srow = tid >> 2;                 // 0..63
  int cphys = tid & 3;                 // LDS chunk slot this thread fills
  int swz = (srow >> 1) & 3;
  int clog = (cphys ^ swz) * 8;        // bf16 k-offset actually fetched
  int ra = bm + srow;       if (ra > M - 1) ra = M - 1;
  int rb = bm + srow + 64;  if (rb > M - 1) rb = M - 1;
  const short* aP0 = A + (ll)ra * AS + clog;
  const short* aP1 = A + (ll)rb * AS + clog;
  const short* bP0 = Bt + (ll)(bn + srow) * K + clog;
  const short* bP1 = Bt + (ll)(bn + srow + 64) * K + clog;
  int dstOff = tid * 16;

  int lrow = lane & 15;
  int lchunk = ((lane >> 4) ^ ((lrow >> 1) & 3)) * 16;
  int fOffA = (wr * 64 + lrow) * 64 + lchunk;
  int fOffB = (wc * 64 + lrow) * 64 + lchunk;

  for (int kt = 0; kt < K; kt += 32) {
    gload16(aP0 + kt, Ah + dstOff);
    gload16(aP1 + kt, Ah + 4096 + dstOff);
    if constexpr (SPLIT) {
      gload16(aP0 + K + kt, Al + dstOff);
      gload16(aP1 + K + kt, Al + 4096 + dstOff);
    }
    gload16(bP0 + kt, Bs + dstOff);
    gload16(bP1 + kt, Bs + 4096 + dstOff);
    __syncthreads();
    bf16x8 ah[4], al[4], bfr[4];
#pragma unroll
    for (int m = 0; m < 4; ++m) {
      ah[m] = *(const bf16x8*)(Ah + fOffA + m * 1024);
      if constexpr (SPLIT) al[m] = *(const bf16x8*)(Al + fOffA + m * 1024);
    }
#pragma unroll
    for (int n = 0; n < 4; ++n) bfr[n] = *(const bf16x8*)(Bs + fOffB + n * 1024);
#pragma unroll
    for (int m = 0; m < 4; ++m)
#pragma unroll
      for (int n = 0; n < 4; ++n) {
        acc[m][n] = __builtin_amdgcn_mfma_f32_16x16x32_bf16(ah[m], bfr[n], acc[m][n], 0, 0, 0);
        if constexpr (SPLIT)
          acc[m][n] = __builtin_amdgcn_mfma_f32_16x16x32_bf16(al[m], bfr[n], acc[m][n], 0, 0, 0);
      }
    __syncthreads();
  }

  int crow0 = bm + wr * 64 + (lane >> 4) * 4;
  int ccol0 = bn + wc * 64 + (lane & 15);
#pragma unroll
  for (int m = 0; m < 4; ++m) {
#pragma unroll
    for (int j = 0; j < 4; ++j) {
      int row = crow0 + m * 16 + j;
      if (row < M) {
#pragma unroll
        for (int n = 0; n < 4; ++n) {
          if (HBF16) ((unsigned short*)Cv)[(ll)row * Nc + ccol0 + n * 16] = bf16_of(acc[m][n][j]);
          else       ((float*)Cv)[(ll)row * Nc + ccol0 + n * 16] = acc[m][n][j];
        }
      }
    }
  }

  // fused partial attention scores
  float as4[4], ad4[4];
#pragma unroll
  for (int n = 0; n < 4; ++n) {
    as4[n] = a_src[ccol0 + n * 16];
    ad4[n] = a_dst[ccol0 + n * 16];
  }
  int p = bx * 2 + wc;
#pragma unroll
  for (int m = 0; m < 4; ++m) {
#pragma unroll
    for (int j = 0; j < 4; ++j) {
      float ps = acc[m][0][j] * as4[0] + acc[m][1][j] * as4[1] +
                 acc[m][2][j] * as4[2] + acc[m][3][j] * as4[3];
      float pd = acc[m][0][j] * ad4[0] + acc[m][1][j] * ad4[1] +
                 acc[m][2][j] * ad4[2] + acc[m][3][j] * ad4[3];
#pragma unroll
      for (int o = 1; o < 16; o <<= 1) {
        ps += __shfl_xor(ps, o, 64);
        pd += __shfl_xor(pd, o, 64);
      }
      int row = crow0 + m * 16 + j;
      if ((lane & 15) == 0 && row < M) {
        partS[(ll)p * M + row] = ps;
        partD[(ll)p * M + row] = pd;
      }
    }
  }
}

// sum the per-(col-block,wc) partials -> s_src/s_dst
__global__ void score_reduce_kernel(const float* __restrict__ partS,
                                    const float* __restrict__ partD,
                                    float* __restrict__ s_src, float* __restrict__ s_dst,
                                    int N, int NP) {
  int i = blockIdx.x * blockDim.x + threadIdx.x;
  if (i >= N) return;
  float a = 0.f, b = 0.f;
  for (int p = 0; p < NP; ++p) {
    a += partS[(ll)p * N + i];
    b += partD[(ll)p * N + i];
  }
  s_src[i] = a;
  s_dst[i] = b;
}

// ---------------- wave-per-node fused softmax + weighted aggregation --------
// One 64-lane wave per node; softmax in registers (shfl_xor); per-edge
// broadcast (src, alpha) via uniform shfl; 16B/lane coalesced gathers,
// unrolled x4. OUTB16: store plain bf16 (next-layer GEMM input + agg h).
// LOGSM: fuse row log_softmax (DOUT=128) and write d_out.
template <int DOUT, int HIN_BF16, int OUTB16, int LOGSM>
__global__ __launch_bounds__(256) void agg_wave_kernel(
    const void* __restrict__ hv, const float* __restrict__ ssrc,
    const float* __restrict__ sdst, const int* __restrict__ rowptr,
    const int* __restrict__ csr, const float* __restrict__ bias,
    float* __restrict__ outF, short* __restrict__ outH, int N) {
  constexpr int NH = (DOUT >= 512) ? DOUT / 512 : 1;   // row halves of 512 dims
  constexpr int DPL = (DOUT >= 512) ? 8 : DOUT / 64;   // dims/lane per half
  int wid = threadIdx.x >> 6, lane = threadIdx.x & 63;
  int node = blockIdx.x * 4 + wid;
  if (node >= N) return;
  int rs = rowptr[node];
  int nd = rowptr[node + 1] - rs;
  float sd = sdst[node];
  int d0 = lane * DPL;

  float acc[NH][DPL];
#pragma unroll
  for (int hh = 0; hh < NH; ++hh)
#pragma unroll
    for (int k = 0; k < DPL; ++k) acc[hh][k] = 0.f;

  auto accum = [&](int s, float w) {
    if constexpr (HIN_BF16) {
      const unsigned short* hp = (const unsigned short*)hv + (ll)s * DOUT + d0;
#pragma unroll
      for (int hh = 0; hh < NH; ++hh) {
        bf16x8 qv = *(const bf16x8*)(hp + hh * 512);
#pragma unroll
        for (int k = 0; k < 8; ++k)
          acc[hh][k] += w * bf16_back((unsigned short)qv[k]);
      }
    } else {
      const float* hp = (const float*)hv + (ll)s * DOUT + d0;
#pragma unroll
      for (int k = 0; k < DPL; ++k) acc[0][k] += w * hp[k];
    }
  };

  if (nd <= 64) {
    // in-register softmax: one edge per lane
    int srcl = 0;
    float e = -1e30f;
    if (lane < nd) {
      srcl = csr[rs + lane];
      float t = ssrc[srcl] + sd;
      e = t > 0.f ? t : NEG_SLOPE * t;
    }
    float m = e;
#pragma unroll
    for (int o = 32; o > 0; o >>= 1) m = fmaxf(m, __shfl_xor(m, o, 64));
    float ex = (lane < nd) ? __expf(e - m) : 0.f;
    float den = ex;
#pragma unroll
    for (int o = 32; o > 0; o >>= 1) den += __shfl_xor(den, o, 64);
    float al = ex / (den + EPS_F);

    int i = 0;
    for (; i + 4 <= nd; i += 4) {
      int s0 = __shfl(srcl, i, 64), s1 = __shfl(srcl, i + 1, 64);
      int s2 = __shfl(srcl, i + 2, 64), s3 = __shfl(srcl, i + 3, 64);
      float w0 = __shfl(al, i, 64), w1 = __shfl(al, i + 1, 64);
      float w2 = __shfl(al, i + 2, 64), w3 = __shfl(al, i + 3, 64);
      accum(s0, w0);
      accum(s1, w1);
      accum(s2, w2);
      accum(s3, w3);
    }
    for (; i < nd; ++i) accum(__shfl(srcl, i, 64), __shfl(al, i, 64));
  } else {
    // rare fallback: strided 2-pass softmax + serial gather
    float m = -1e30f;
    for (int i = lane; i < nd; i += 64) {
      float t = ssrc[csr[rs + i]] + sd;
      t = t > 0.f ? t : NEG_SLOPE * t;
      m = fmaxf(m, t);
    }
#pragma unroll
    for (int o = 32; o > 0; o >>= 1) m = fmaxf(m, __shfl_xor(m, o, 64));
    float den = 0.f;
    for (int i = lane; i < nd; i += 64) {
      float t = ssrc[csr[rs + i]] + sd;
      t = t > 0.f ? t : NEG_SLOPE * t;
      den += __expf(t - m);
    }
#pragma unroll
    for (int o = 32; o > 0; o >>= 1) den += __shfl_xor(den, o, 64);
    float inv = 1.f / (den + EPS_F);
    for (int i = 0; i < nd; ++i) {
      int s = csr[rs + i];  // wave-uniform broadcast load
      float t = ssrc[s] + sd;
      t = t > 0.f ? t : NEG_SLOPE * t;
      accum(s, __expf(t - m) * inv);
    }
  }

  // epilogue
  if constexpr (OUTB16) {
#pragma unroll
    for (int hh = 0; hh < NH; ++hh) {
      int d = hh * 512 + d0;
      bf16x8 hp8;
#pragma unroll
      for (int k = 0; k < 8; ++k) {
        float v = fmaxf(acc[hh][k] + bias[d + k], 0.f);
        hp8[k] = (short)bf16_of(v);
      }
      *(bf16x8*)&outH[(ll)node * DOUT + d] = hp8;
    }
  } else if constexpr (LOGSM) {
    // fused row log_softmax over DOUT=128 (2 dims/lane, one wave = one row)
    float v0 = acc[0][0] + bias[d0 + 0];
    float v1 = acc[0][1] + bias[d0 + 1];
    float mx = fmaxf(v0, v1);
#pragma unroll
    for (int o = 32; o > 0; o >>= 1) mx = fmaxf(mx, __shfl_xor(mx, o, 64));
    float s = __expf(v0 - mx) + __expf(v1 - mx);
#pragma unroll
    for (int o = 32; o > 0; o >>= 1) s += __shfl_xor(s, o, 64);
    float ls = logf(s);
    outF[(ll)node * DOUT + d0 + 0] = v0 - mx - ls;
    outF[(ll)node * DOUT + d0 + 1] = v1 - mx - ls;
  } else {
#pragma unroll
    for (int k = 0; k < DPL; ++k)
      outF[(ll)node * DOUT + d0 + k] = acc[0][k] + bias[d0 + k];
  }
}

// ---------------- launch ----------------
extern "C" void kernel_launch(void* const* d_in, const int* in_sizes, int n_in,
                              void* d_out, int out_size, void* d_ws, size_t ws_size,
                              hipStream_t stream) {
  const float* x = (const float*)d_in[0];
  const int* ew = (const int*)d_in[1];
  int N = in_sizes[0] / 256;
  int E = in_sizes[1] / 2;

  const float* W[4]   = {(const float*)d_in[2],  (const float*)d_in[6],
                         (const float*)d_in[10], (const float*)d_in[14]};
  const float* Asv[4] = {(const float*)d_in[3],  (const float*)d_in[7],
                         (const float*)d_in[11], (const float*)d_in[15]};
  const float* Adv[4] = {(const float*)d_in[4],  (const float*)d_in[8],
                         (const float*)d_in[12], (const float*)d_in[16]};
  const float* Bv[4]  = {(const float*)d_in[5],  (const float*)d_in[9],
                         (const float*)d_in[13], (const float*)d_in[17]};
  const int din[4]  = {256, 1024, 1024, 512};
  const int dout[4] = {1024, 1024, 512, 128};

  char* ws = (char*)d_ws;
  size_t off = 0;
  auto alloc = [&](size_t bytes) {
    void* p = ws + off;
    off += (bytes + 255) & ~(size_t)255;
    return p;
  };
  unsigned short* hB = (unsigned short*)alloc((size_t)N * 1024 * 2);  // bf16 h (layers 1-3)
  float* hF   = (float*)alloc((size_t)N * 128 * 4);                   // fp32 h (layer 4)
  short* bufP = (short*)alloc((size_t)N * 512 * 2);   // x split [hi|lo]
  short* bufQ = (short*)alloc((size_t)N * 1024 * 2);  // inter-layer bf16 act
  short* bufR = (short*)alloc((size_t)N * 1024 * 2);
  float* s_src = (float*)alloc((size_t)N * 4);
  float* s_dst = (float*)alloc((size_t)N * 4);
  float* partS = (float*)alloc((size_t)16 * N * 4);
  float* partD = (float*)alloc((size_t)16 * N * 4);
  int* deg    = (int*)alloc((size_t)(N + 1) * 4);
  int* rowptr = (int*)alloc((size_t)(N + 1) * 4);
  int* cursor = (int*)alloc((size_t)(N + 1) * 4);
  int* csr    = (int*)alloc((size_t)(E + N) * 4);
  int* flag   = (int*)alloc(256);
  short* Bt[4];
  for (int l = 0; l < 4; ++l) Bt[l] = (short*)alloc((size_t)dout[l] * din[l] * 2);

  detect_int64_kernel<<<1, 256, 0, stream>>>((const unsigned int*)ew, E, flag);
  hipMemsetAsync(deg, 0, (size_t)(N + 1) * 4, stream);
  count_deg_kernel<<<(E + 255) / 256, 256, 0, stream>>>(ew, E, deg, flag);
  scan_kernel<<<1, 1024, 0, stream>>>(deg, rowptr, cursor, N);
  fill_kernel<<<(E + N + 255) / 256, 256, 0, stream>>>(ew, E, N, cursor, csr, flag);

  convert_x_kernel<<<(N * 256 + 255) / 256, 256, 0, stream>>>(x, bufP, N);
  {
    dim3 cg(32, 32, 4);
    convert_w_all_kernel<<<cg, 256, 0, stream>>>(W[0], W[1], W[2], W[3],
                                                 Bt[0], Bt[1], Bt[2], Bt[3]);
  }

  int ngrp = (N + 3) / 4;
  // layer 1: split-A GEMM (input precision matters most here)
  {
    dim3 gg(dout[0] / 128, (N + 127) / 128);
    gemm_mfma_kernel<1, 1><<<gg, 256, 0, stream>>>(bufP, Bt[0], hB, Asv[0], Adv[0],
                                                   partS, partD, N, dout[0], din[0]);
    score_reduce_kernel<<<(N + 255) / 256, 256, 0, stream>>>(partS, partD, s_src, s_dst,
                                                             N, (dout[0] / 128) * 2);
    agg_wave_kernel<1024, 1, 1, 0><<<ngrp, 256, 0, stream>>>(
        hB, s_src, s_dst, rowptr, csr, Bv[0], nullptr, bufQ, N);
  }
  // layer 2: plain bf16 A
  {
    dim3 gg(dout[1] / 128, (N + 127) / 128);
    gemm_mfma_kernel<1, 0><<<gg, 256, 0, stream>>>(bufQ, Bt[1], hB, Asv[1], Adv[1],
                                                   partS, partD, N, dout[1], din[1]);
    score_reduce_kernel<<<(N + 255) / 256, 256, 0, stream>>>(partS, partD, s_src, s_dst,
                                                             N, (dout[1] / 128) * 2);
    agg_wave_kernel<1024, 1, 1, 0><<<ngrp, 256, 0, stream>>>(
        hB, s_src, s_dst, rowptr, csr, Bv[1], nullptr, bufR, N);
  }
  // layer 3
  {
    dim3 gg(dout[2] / 128, (N + 127) / 128);
    gemm_mfma_kernel<1, 0><<<gg, 256, 0, stream>>>(bufR, Bt[2], hB, Asv[2], Adv[2],
                                                   partS, partD, N, dout[2], din[2]);
    score_reduce_kernel<<<(N + 255) / 256, 256, 0, stream>>>(partS, partD, s_src, s_dst,
                                                             N, (dout[2] / 128) * 2);
    agg_wave_kernel<512, 1, 1, 0><<<ngrp, 256, 0, stream>>>(
        hB, s_src, s_dst, rowptr, csr, Bv[2], nullptr, bufQ, N);
  }
  // layer 4: fp32 h, fused log_softmax
  {
    dim3 gg(dout[3] / 128, (N + 127) / 128);
    gemm_mfma_kernel<0, 0><<<gg, 256, 0, stream>>>(bufQ, Bt[3], hF, Asv[3], Adv[3],
                                                   partS, partD, N, dout[3], din[3]);
    score_reduce_kernel<<<(N + 255) / 256, 256, 0, stream>>>(partS, partD, s_src, s_dst,
                                                             N, (dout[3] / 128) * 2);
    agg_wave_kernel<128, 0, 0, 1><<<ngrp, 256, 0, stream>>>(
        hF, s_src, s_dst, rowptr, csr, Bv[3], (float*)d_out, nullptr, N);
  }
}

// Round 11
// 285.290 us; speedup vs baseline: 1.5373x; 1.1051x over previous
//
#include <hip/hip_runtime.h>
#include <math.h>

#define NEG_SLOPE 0.2f
#define EPS_F 1e-16f
typedef long long ll;

typedef __attribute__((ext_vector_type(4))) float f32x4;
typedef __attribute__((ext_vector_type(8))) short bf16x8;

// ---------------- bf16 helpers (bit-level, RTN-even) ----------------
__device__ __forceinline__ unsigned short bf16_of(float f) {
  unsigned u = __float_as_uint(f);
  u += 0x7fffu + ((u >> 16) & 1u);
  return (unsigned short)(u >> 16);
}
__device__ __forceinline__ float bf16_back(unsigned short s) {
  return __uint_as_float((unsigned)s << 16);
}

__device__ __forceinline__ void gload16(const void* g, void* l) {
  __builtin_amdgcn_global_load_lds((const __attribute__((address_space(1))) void*)g,
                                   (__attribute__((address_space(3))) void*)l, 16, 0, 0);
}

// ---------------- edge dtype detection (int64 vs int32) ----------------
__global__ void detect_int64_kernel(const unsigned int* __restrict__ w, int E,
                                    int* __restrict__ flag) {
  __shared__ int nz;
  if (threadIdx.x == 0) nz = 0;
  __syncthreads();
  int cnt = E < 2048 ? E : 2048;
  int local = 0;
  for (int i = threadIdx.x; i < cnt; i += blockDim.x)
    if (w[2 * i + 1] != 0u) local++;
  if (local) atomicAdd(&nz, local);
  __syncthreads();
  if (threadIdx.x == 0) *flag = (nz == 0) ? 1 : 0;  // 1 => int64 layout
}

__device__ __forceinline__ void edge_at(const int* __restrict__ ew, int E, int e,
                                        int is64, int& s, int& d) {
  if (is64) { s = ew[2 * e]; d = ew[2 * E + 2 * e]; }
  else      { s = ew[e];     d = ew[E + e]; }
}

// ---------------- CSR build (deg = edge-count; +1 self-loop folded in scan) ----
__global__ void count_deg_kernel(const int* __restrict__ ew, int E, int* deg,
                                 const int* __restrict__ flag) {
  int is64 = *flag;
  int e = blockIdx.x * blockDim.x + threadIdx.x;
  if (e < E) {
    int s, d;
    edge_at(ew, E, e, is64, s, d);
    atomicAdd(&deg[d], 1);
  }
}

__global__ void scan_kernel(const int* __restrict__ deg, int* rowptr, int* cursor, int N) {
  __shared__ int sums[1024];
  int tid = threadIdx.x;
  int chunk = (N + 1023) >> 10;
  int start = tid * chunk;
  int end = start + chunk; if (end > N) end = N;
  int s = 0;
  for (int i = start; i < end; ++i) s += deg[i] + 1;  // +1 = self loop
  sums[tid] = s;
  __syncthreads();
  for (int off = 1; off < 1024; off <<= 1) {
    int v = (tid >= off) ? sums[tid - off] : 0;
    __syncthreads();
    sums[tid] += v;
    __syncthreads();
  }
  int run = (tid == 0) ? 0 : sums[tid - 1];
  for (int i = start; i < end; ++i) {
    rowptr[i] = run; cursor[i] = run;
    run += deg[i] + 1;
  }
  if (tid == 1023) rowptr[N] = sums[1023];
}

__global__ void fill_kernel(const int* __restrict__ ew, int E, int N, int* cursor,
                            int* csr, const int* __restrict__ flag) {
  int is64 = *flag;
  int i = blockIdx.x * blockDim.x + threadIdx.x;
  if (i < E) {
    int s, d;
    edge_at(ew, E, i, is64, s, d);
    int pos = atomicAdd(&cursor[d], 1);
    csr[pos] = s;
  } else if (i < E + N) {
    int n = i - E;
    int pos = atomicAdd(&cursor[n], 1);
    csr[pos] = n;
  }
}

// ---------------- weight conversions ----------------
// all 4 W [K, Nc] fp32 -> Bt [Nc, K] bf16 (W_hi^T), one dispatch (z = layer)
__global__ __launch_bounds__(256) void convert_w_all_kernel(
    const float* __restrict__ W0, const float* __restrict__ W1,
    const float* __restrict__ W2, const float* __restrict__ W3,
    short* __restrict__ B0, short* __restrict__ B1,
    short* __restrict__ B2, short* __restrict__ B3) {
  const int Ks[4]  = {256, 1024, 1024, 512};
  const int Ncs[4] = {1024, 1024, 512, 128};
  int z = blockIdx.z;
  int K = Ks[z], Nc = Ncs[z];
  int k0 = blockIdx.x * 32, n0 = blockIdx.y * 32;
  if (k0 >= K || n0 >= Nc) return;
  const float* W = z == 0 ? W0 : (z == 1 ? W1 : (z == 2 ? W2 : W3));
  short* Bt = z == 0 ? B0 : (z == 1 ? B1 : (z == 2 ? B2 : B3));
  __shared__ float t[32][33];
  int r = threadIdx.x >> 3;          // 0..31
  int c4 = (threadIdx.x & 7) * 4;    // 0..28
  float4 v = *(const float4*)&W[(ll)(k0 + r) * Nc + n0 + c4];
  t[r][c4] = v.x; t[r][c4 + 1] = v.y; t[r][c4 + 2] = v.z; t[r][c4 + 3] = v.w;
  __syncthreads();
  float f0 = t[c4 + 0][r], f1 = t[c4 + 1][r], f2 = t[c4 + 2][r], f3 = t[c4 + 3][r];
  short4 hp = make_short4((short)bf16_of(f0), (short)bf16_of(f1),
                          (short)bf16_of(f2), (short)bf16_of(f3));
  *(short4*)&Bt[(ll)(n0 + r) * K + k0 + c4] = hp;
}

// wvec1 = W1 @ a1 (per output-dim contraction): ws[k] = sum_j W[k][j]*as[j]
__global__ void wvec_kernel(const float* __restrict__ W, const float* __restrict__ as,
                            const float* __restrict__ ad, float* __restrict__ ws,
                            float* __restrict__ wd, int K, int Nc) {
  int wid = threadIdx.x >> 6, lane = threadIdx.x & 63;
  int k = blockIdx.x * 4 + wid;
  if (k >= K) return;
  const float* row = W + (ll)k * Nc;
  float a = 0.f, b = 0.f;
  for (int j = lane; j < Nc; j += 64) {
    float w = row[j];
    a += w * as[j];
    b += w * ad[j];
  }
#pragma unroll
  for (int o = 32; o > 0; o >>= 1) {
    a += __shfl_xor(a, o, 64);
    b += __shfl_xor(b, o, 64);
  }
  if (lane == 0) { ws[k] = a; wd[k] = b; }
}

// layer-1 scores by GEMV: s_src[n] = x[n]·ws, s_dst[n] = x[n]·wd  (din=256)
__global__ void score_gemv_kernel(const float* __restrict__ x, const float* __restrict__ ws,
                                  const float* __restrict__ wd, float* __restrict__ s_src,
                                  float* __restrict__ s_dst, int N) {
  int wid = threadIdx.x >> 6, lane = threadIdx.x & 63;
  int n = blockIdx.x * 4 + wid;
  if (n >= N) return;
  float4 xv = *(const float4*)&x[(ll)n * 256 + lane * 4];
  float4 wsv = *(const float4*)&ws[lane * 4];
  float4 wdv = *(const float4*)&wd[lane * 4];
  float a = xv.x * wsv.x + xv.y * wsv.y + xv.z * wsv.z + xv.w * wsv.w;
  float b = xv.x * wdv.x + xv.y * wdv.y + xv.z * wdv.z + xv.w * wdv.w;
#pragma unroll
  for (int o = 32; o > 0; o >>= 1) {
    a += __shfl_xor(a, o, 64);
    b += __shfl_xor(b, o, 64);
  }
  if (lane == 0) { s_src[n] = a; s_dst[n] = b; }
}

// ---------------- layer-1 input-side aggregation -----------------
// xagg[dst] = sum alpha * x[src] over fp32 x (256-dim, float4/lane), then
// split to bf16 [hi|lo] for the split GEMM. Wave per node, softmax in regs.
__global__ __launch_bounds__(256) void agg_x_kernel(
    const float* __restrict__ x, const float* __restrict__ ssrc,
    const float* __restrict__ sdst, const int* __restrict__ rowptr,
    const int* __restrict__ csr, short* __restrict__ outH, int N) {
  int wid = threadIdx.x >> 6, lane = threadIdx.x & 63;
  int node = blockIdx.x * 4 + wid;
  if (node >= N) return;
  int rs = rowptr[node];
  int nd = rowptr[node + 1] - rs;
  float sd = sdst[node];
  int d0 = lane * 4;

  float a0 = 0.f, a1 = 0.f, a2 = 0.f, a3 = 0.f;
  auto accum = [&](int s, float w) {
    float4 xv = *(const float4*)&x[(ll)s * 256 + d0];
    a0 += w * xv.x; a1 += w * xv.y; a2 += w * xv.z; a3 += w * xv.w;
  };

  if (nd <= 64) {
    int srcl = 0;
    float e = -1e30f;
    if (lane < nd) {
      srcl = csr[rs + lane];
      float t = ssrc[srcl] + sd;
      e = t > 0.f ? t : NEG_SLOPE * t;
    }
    float m = e;
#pragma unroll
    for (int o = 32; o > 0; o >>= 1) m = fmaxf(m, __shfl_xor(m, o, 64));
    float ex = (lane < nd) ? __expf(e - m) : 0.f;
    float den = ex;
#pragma unroll
    for (int o = 32; o > 0; o >>= 1) den += __shfl_xor(den, o, 64);
    float al = ex / (den + EPS_F);
    int i = 0;
    for (; i + 4 <= nd; i += 4) {
      int s0 = __shfl(srcl, i, 64), s1 = __shfl(srcl, i + 1, 64);
      int s2 = __shfl(srcl, i + 2, 64), s3 = __shfl(srcl, i + 3, 64);
      float w0 = __shfl(al, i, 64), w1 = __shfl(al, i + 1, 64);
      float w2 = __shfl(al, i + 2, 64), w3 = __shfl(al, i + 3, 64);
      accum(s0, w0); accum(s1, w1); accum(s2, w2); accum(s3, w3);
    }
    for (; i < nd; ++i) accum(__shfl(srcl, i, 64), __shfl(al, i, 64));
  } else {
    float m = -1e30f;
    for (int i = lane; i < nd; i += 64) {
      float t = ssrc[csr[rs + i]] + sd;
      t = t > 0.f ? t : NEG_SLOPE * t;
      m = fmaxf(m, t);
    }
#pragma unroll
    for (int o = 32; o > 0; o >>= 1) m = fmaxf(m, __shfl_xor(m, o, 64));
    float den = 0.f;
    for (int i = lane; i < nd; i += 64) {
      float t = ssrc[csr[rs + i]] + sd;
      t = t > 0.f ? t : NEG_SLOPE * t;
      den += __expf(t - m);
    }
#pragma unroll
    for (int o = 32; o > 0; o >>= 1) den += __shfl_xor(den, o, 64);
    float inv = 1.f / (den + EPS_F);
    for (int i = 0; i < nd; ++i) {
      int s = csr[rs + i];
      float t = ssrc[s] + sd;
      t = t > 0.f ? t : NEG_SLOPE * t;
      accum(s, __expf(t - m) * inv);
    }
  }

  unsigned short h0 = bf16_of(a0), h1 = bf16_of(a1), h2 = bf16_of(a2), h3 = bf16_of(a3);
  short4 hp = make_short4((short)h0, (short)h1, (short)h2, (short)h3);
  short4 lp = make_short4((short)bf16_of(a0 - bf16_back(h0)),
                          (short)bf16_of(a1 - bf16_back(h1)),
                          (short)bf16_of(a2 - bf16_back(h2)),
                          (short)bf16_of(a3 - bf16_back(h3)));
  ll base = (ll)node * 512 + d0;
  *(short4*)&outH[base] = hp;
  *(short4*)&outH[base + 256] = lp;
}

// ---------------- MFMA GEMM + optional fused scores / bias-relu ----------
// SPLIT: A is [M,2K] bf16 ([hi|lo]); else [M,K] plain bf16. B = W_hi^T.
// BIASRELU: epilogue adds bias + ReLU (layer-1 out). SCORES: partial att dots.
template <int HBF16, int SPLIT, int BIASRELU, int SCORES>
__global__ __launch_bounds__(256) void gemm_mfma_kernel(
    const short* __restrict__ A, const short* __restrict__ Bt,
    void* __restrict__ Cv, const float* __restrict__ a_src,
    const float* __restrict__ a_dst, const float* __restrict__ bias,
    float* __restrict__ partS, float* __restrict__ partD, int M, int Nc, int K) {
  __shared__ char Ah[SPLIT ? 16384 : 8192];
  __shared__ char Bs[8192];
  char* Al = Ah + 8192;  // valid only when SPLIT
  int tid = threadIdx.x;

  int nwg = gridDim.x * gridDim.y;
  int hb = blockIdx.y * gridDim.x + blockIdx.x;
  int xcd = hb & 7, q = nwg >> 3, r = nwg & 7;
  int lg = (xcd < r ? xcd * (q + 1) : r * (q + 1) + (xcd - r) * q) + (hb >> 3);
  int bx = lg % gridDim.x, by = lg / gridDim.x;
  int bm = by * 128, bn = bx * 128;

  int lane = tid & 63, wid = tid >> 6;
  int wr = wid >> 1, wc = wid & 1;
  int AS = SPLIT ? 2 * K : K;  // A row stride

  f32x4 acc[4][4];
#pragma unroll
  for (int m = 0; m < 4; ++m)
#pragma unroll
    for (int n = 0; n < 4; ++n) acc[m][n] = (f32x4){0.f, 0.f, 0.f, 0.f};

  int srow = tid >> 2;                 // 0..63
  int cphys = tid & 3;                 // LDS chunk slot this thread fills
  int swz = (srow >> 1) & 3;
  int clog = (cphys ^ swz) * 8;        // bf16 k-offset actually fetched
  int ra = bm + srow;       if (ra > M - 1) ra = M - 1;
  int rb = bm + srow + 64;  if (rb > M - 1) rb = M - 1;
  const short* aP0 = A + (ll)ra * AS + clog;
  const short* aP1 = A + (ll)rb * AS + clog;
  const short* bP0 = Bt + (ll)(bn + srow) * K + clog;
  const short* bP1 = Bt + (ll)(bn + srow + 64) * K + clog;
  int dstOff = tid * 16;

  int lrow = lane & 15;
  int lchunk = ((lane >> 4) ^ ((lrow >> 1) & 3)) * 16;
  int fOffA = (wr * 64 + lrow) * 64 + lchunk;
  int fOffB = (wc * 64 + lrow) * 64 + lchunk;

  for (int kt = 0; kt < K; kt += 32) {
    gload16(aP0 + kt, Ah + dstOff);
    gload16(aP1 + kt, Ah + 4096 + dstOff);
    if constexpr (SPLIT) {
      gload16(aP0 + K + kt, Al + dstOff);
      gload16(aP1 + K + kt, Al + 4096 + dstOff);
    }
    gload16(bP0 + kt, Bs + dstOff);
    gload16(bP1 + kt, Bs + 4096 + dstOff);
    __syncthreads();
    bf16x8 ah[4], al[4], bfr[4];
#pragma unroll
    for (int m = 0; m < 4; ++m) {
      ah[m] = *(const bf16x8*)(Ah + fOffA + m * 1024);
      if constexpr (SPLIT) al[m] = *(const bf16x8*)(Al + fOffA + m * 1024);
    }
#pragma unroll
    for (int n = 0; n < 4; ++n) bfr[n] = *(const bf16x8*)(Bs + fOffB + n * 1024);
#pragma unroll
    for (int m = 0; m < 4; ++m)
#pragma unroll
      for (int n = 0; n < 4; ++n) {
        acc[m][n] = __builtin_amdgcn_mfma_f32_16x16x32_bf16(ah[m], bfr[n], acc[m][n], 0, 0, 0);
        if constexpr (SPLIT)
          acc[m][n] = __builtin_amdgcn_mfma_f32_16x16x32_bf16(al[m], bfr[n], acc[m][n], 0, 0, 0);
      }
    __syncthreads();
  }

  int crow0 = bm + wr * 64 + (lane >> 4) * 4;
  int ccol0 = bn + wc * 64 + (lane & 15);
  float bv4[4];
  if constexpr (BIASRELU) {
#pragma unroll
    for (int n = 0; n < 4; ++n) bv4[n] = bias[ccol0 + n * 16];
  }
#pragma unroll
  for (int m = 0; m < 4; ++m) {
#pragma unroll
    for (int j = 0; j < 4; ++j) {
      int row = crow0 + m * 16 + j;
      if (row < M) {
#pragma unroll
        for (int n = 0; n < 4; ++n) {
          float v = acc[m][n][j];
          if constexpr (BIASRELU) v = fmaxf(v + bv4[n], 0.f);
          if (HBF16) ((unsigned short*)Cv)[(ll)row * Nc + ccol0 + n * 16] = bf16_of(v);
          else       ((float*)Cv)[(ll)row * Nc + ccol0 + n * 16] = v;
        }
      }
    }
  }

  if constexpr (SCORES) {
    float as4[4], ad4[4];
#pragma unroll
    for (int n = 0; n < 4; ++n) {
      as4[n] = a_src[ccol0 + n * 16];
      ad4[n] = a_dst[ccol0 + n * 16];
    }
    int p = bx * 2 + wc;
#pragma unroll
    for (int m = 0; m < 4; ++m) {
#pragma unroll
      for (int j = 0; j < 4; ++j) {
        float ps = acc[m][0][j] * as4[0] + acc[m][1][j] * as4[1] +
                   acc[m][2][j] * as4[2] + acc[m][3][j] * as4[3];
        float pd = acc[m][0][j] * ad4[0] + acc[m][1][j] * ad4[1] +
                   acc[m][2][j] * ad4[2] + acc[m][3][j] * ad4[3];
#pragma unroll
        for (int o = 1; o < 16; o <<= 1) {
          ps += __shfl_xor(ps, o, 64);
          pd += __shfl_xor(pd, o, 64);
        }
        int row = crow0 + m * 16 + j;
        if ((lane & 15) == 0 && row < M) {
          partS[(ll)p * M + row] = ps;
          partD[(ll)p * M + row] = pd;
        }
      }
    }
  }
}

// sum the per-(col-block,wc) partials -> s_src/s_dst
__global__ void score_reduce_kernel(const float* __restrict__ partS,
                                    const float* __restrict__ partD,
                                    float* __restrict__ s_src, float* __restrict__ s_dst,
                                    int N, int NP) {
  int i = blockIdx.x * blockDim.x + threadIdx.x;
  if (i >= N) return;
  float a = 0.f, b = 0.f;
  for (int p = 0; p < NP; ++p) {
    a += partS[(ll)p * N + i];
    b += partD[(ll)p * N + i];
  }
  s_src[i] = a;
  s_dst[i] = b;
}

// ---------------- wave-per-node fused softmax + weighted aggregation --------
template <int DOUT, int HIN_BF16, int OUTB16, int LOGSM>
__global__ __launch_bounds__(256) void agg_wave_kernel(
    const void* __restrict__ hv, const float* __restrict__ ssrc,
    const float* __restrict__ sdst, const int* __restrict__ rowptr,
    const int* __restrict__ csr, const float* __restrict__ bias,
    float* __restrict__ outF, short* __restrict__ outH, int N) {
  constexpr int NH = (DOUT >= 512) ? DOUT / 512 : 1;   // row halves of 512 dims
  constexpr int DPL = (DOUT >= 512) ? 8 : DOUT / 64;   // dims/lane per half
  int wid = threadIdx.x >> 6, lane = threadIdx.x & 63;
  int node = blockIdx.x * 4 + wid;
  if (node >= N) return;
  int rs = rowptr[node];
  int nd = rowptr[node + 1] - rs;
  float sd = sdst[node];
  int d0 = lane * DPL;

  float acc[NH][DPL];
#pragma unroll
  for (int hh = 0; hh < NH; ++hh)
#pragma unroll
    for (int k = 0; k < DPL; ++k) acc[hh][k] = 0.f;

  auto accum = [&](int s, float w) {
    if constexpr (HIN_BF16) {
      const unsigned short* hp = (const unsigned short*)hv + (ll)s * DOUT + d0;
#pragma unroll
      for (int hh = 0; hh < NH; ++hh) {
        bf16x8 qv = *(const bf16x8*)(hp + hh * 512);
#pragma unroll
        for (int k = 0; k < 8; ++k)
          acc[hh][k] += w * bf16_back((unsigned short)qv[k]);
      }
    } else {
      const float* hp = (const float*)hv + (ll)s * DOUT + d0;
#pragma unroll
      for (int k = 0; k < DPL; ++k) acc[0][k] += w * hp[k];
    }
  };

  if (nd <= 64) {
    int srcl = 0;
    float e = -1e30f;
    if (lane < nd) {
      srcl = csr[rs + lane];
      float t = ssrc[srcl] + sd;
      e = t > 0.f ? t : NEG_SLOPE * t;
    }
    float m = e;
#pragma unroll
    for (int o = 32; o > 0; o >>= 1) m = fmaxf(m, __shfl_xor(m, o, 64));
    float ex = (lane < nd) ? __expf(e - m) : 0.f;
    float den = ex;
#pragma unroll
    for (int o = 32; o > 0; o >>= 1) den += __shfl_xor(den, o, 64);
    float al = ex / (den + EPS_F);

    int i = 0;
    for (; i + 4 <= nd; i += 4) {
      int s0 = __shfl(srcl, i, 64), s1 = __shfl(srcl, i + 1, 64);
      int s2 = __shfl(srcl, i + 2, 64), s3 = __shfl(srcl, i + 3, 64);
      float w0 = __shfl(al, i, 64), w1 = __shfl(al, i + 1, 64);
      float w2 = __shfl(al, i + 2, 64), w3 = __shfl(al, i + 3, 64);
      accum(s0, w0); accum(s1, w1); accum(s2, w2); accum(s3, w3);
    }
    for (; i < nd; ++i) accum(__shfl(srcl, i, 64), __shfl(al, i, 64));
  } else {
    float m = -1e30f;
    for (int i = lane; i < nd; i += 64) {
      float t = ssrc[csr[rs + i]] + sd;
      t = t > 0.f ? t : NEG_SLOPE * t;
      m = fmaxf(m, t);
    }
#pragma unroll
    for (int o = 32; o > 0; o >>= 1) m = fmaxf(m, __shfl_xor(m, o, 64));
    float den = 0.f;
    for (int i = lane; i < nd; i += 64) {
      float t = ssrc[csr[rs + i]] + sd;
      t = t > 0.f ? t : NEG_SLOPE * t;
      den += __expf(t - m);
    }
#pragma unroll
    for (int o = 32; o > 0; o >>= 1) den += __shfl_xor(den, o, 64);
    float inv = 1.f / (den + EPS_F);
    for (int i = 0; i < nd; ++i) {
      int s = csr[rs + i];  // wave-uniform broadcast load
      float t = ssrc[s] + sd;
      t = t > 0.f ? t : NEG_SLOPE * t;
      accum(s, __expf(t - m) * inv);
    }
  }

  if constexpr (OUTB16) {
#pragma unroll
    for (int hh = 0; hh < NH; ++hh) {
      int d = hh * 512 + d0;
      bf16x8 hp8;
#pragma unroll
      for (int k = 0; k < 8; ++k) {
        float v = fmaxf(acc[hh][k] + bias[d + k], 0.f);
        hp8[k] = (short)bf16_of(v);
      }
      *(bf16x8*)&outH[(ll)node * DOUT + d] = hp8;
    }
  } else if constexpr (LOGSM) {
    float v0 = acc[0][0] + bias[d0 + 0];
    float v1 = acc[0][1] + bias[d0 + 1];
    float mx = fmaxf(v0, v1);
#pragma unroll
    for (int o = 32; o > 0; o >>= 1) mx = fmaxf(mx, __shfl_xor(mx, o, 64));
    float s = __expf(v0 - mx) + __expf(v1 - mx);
#pragma unroll
    for (int o = 32; o > 0; o >>= 1) s += __shfl_xor(s, o, 64);
    float ls = logf(s);
    outF[(ll)node * DOUT + d0 + 0] = v0 - mx - ls;
    outF[(ll)node * DOUT + d0 + 1] = v1 - mx - ls;
  } else {
#pragma unroll
    for (int k = 0; k < DPL; ++k)
      outF[(ll)node * DOUT + d0 + k] = acc[0][k] + bias[d0 + k];
  }
}

// ---------------- launch ----------------
extern "C" void kernel_launch(void* const* d_in, const int* in_sizes, int n_in,
                              void* d_out, int out_size, void* d_ws, size_t ws_size,
                              hipStream_t stream) {
  const float* x = (const float*)d_in[0];
  const int* ew = (const int*)d_in[1];
  int N = in_sizes[0] / 256;
  int E = in_sizes[1] / 2;

  const float* W[4]   = {(const float*)d_in[2],  (const float*)d_in[6],
                         (const float*)d_in[10], (const float*)d_in[14]};
  const float* Asv[4] = {(const float*)d_in[3],  (const float*)d_in[7],
                         (const float*)d_in[11], (const float*)d_in[15]};
  const float* Adv[4] = {(const float*)d_in[4],  (const float*)d_in[8],
                         (const float*)d_in[12], (const float*)d_in[16]};
  const float* Bv[4]  = {(const float*)d_in[5],  (const float*)d_in[9],
                         (const float*)d_in[13], (const float*)d_in[17]};
  const int din[4]  = {256, 1024, 1024, 512};
  const int dout[4] = {1024, 1024, 512, 128};

  char* ws = (char*)d_ws;
  size_t off = 0;
  auto alloc = [&](size_t bytes) {
    void* p = ws + off;
    off += (bytes + 255) & ~(size_t)255;
    return p;
  };
  unsigned short* hB = (unsigned short*)alloc((size_t)N * 1024 * 2);  // bf16 h (layers 2-3)
  float* hF   = (float*)alloc((size_t)N * 128 * 4);                   // fp32 h (layer 4)
  short* bufP = (short*)alloc((size_t)N * 512 * 2);   // xagg split [hi|lo]
  short* bufQ = (short*)alloc((size_t)N * 1024 * 2);  // inter-layer bf16 act
  short* bufR = (short*)alloc((size_t)N * 1024 * 2);
  float* s_src = (float*)alloc((size_t)N * 4);
  float* s_dst = (float*)alloc((size_t)N * 4);
  float* partS = (float*)alloc((size_t)16 * N * 4);
  float* partD = (float*)alloc((size_t)16 * N * 4);
  float* wvS  = (float*)alloc((size_t)256 * 4);
  float* wvD  = (float*)alloc((size_t)256 * 4);
  int* deg    = (int*)alloc((size_t)(N + 1) * 4);
  int* rowptr = (int*)alloc((size_t)(N + 1) * 4);
  int* cursor = (int*)alloc((size_t)(N + 1) * 4);
  int* csr    = (int*)alloc((size_t)(E + N) * 4);
  int* flag   = (int*)alloc(256);
  short* Bt[4];
  for (int l = 0; l < 4; ++l) Bt[l] = (short*)alloc((size_t)dout[l] * din[l] * 2);

  detect_int64_kernel<<<1, 256, 0, stream>>>((const unsigned int*)ew, E, flag);
  hipMemsetAsync(deg, 0, (size_t)(N + 1) * 4, stream);
  count_deg_kernel<<<(E + 255) / 256, 256, 0, stream>>>(ew, E, deg, flag);
  scan_kernel<<<1, 1024, 0, stream>>>(deg, rowptr, cursor, N);
  fill_kernel<<<(E + N + 255) / 256, 256, 0, stream>>>(ew, E, N, cursor, csr, flag);

  {
    dim3 cg(32, 32, 4);
    convert_w_all_kernel<<<cg, 256, 0, stream>>>(W[0], W[1], W[2], W[3],
                                                 Bt[0], Bt[1], Bt[2], Bt[3]);
  }
  wvec_kernel<<<64, 256, 0, stream>>>(W[0], Asv[0], Adv[0], wvS, wvD, 256, 1024);

  int ngrp = (N + 3) / 4;
  // layer 1: GEMV scores -> input-side aggregation -> split GEMM (bias+relu fused)
  {
    score_gemv_kernel<<<ngrp, 256, 0, stream>>>(x, wvS, wvD, s_src, s_dst, N);
    agg_x_kernel<<<ngrp, 256, 0, stream>>>(x, s_src, s_dst, rowptr, csr, bufP, N);
    dim3 gg(dout[0] / 128, (N + 127) / 128);
    gemm_mfma_kernel<1, 1, 1, 0><<<gg, 256, 0, stream>>>(
        bufP, Bt[0], bufQ, nullptr, nullptr, Bv[0], partS, partD, N, dout[0], din[0]);
  }
  // layer 2: GEMM (h2 + fused scores) -> reduce -> output-side agg
  {
    dim3 gg(dout[1] / 128, (N + 127) / 128);
    gemm_mfma_kernel<1, 0, 0, 1><<<gg, 256, 0, stream>>>(
        bufQ, Bt[1], hB, Asv[1], Adv[1], nullptr, partS, partD, N, dout[1], din[1]);
    score_reduce_kernel<<<(N + 255) / 256, 256, 0, stream>>>(partS, partD, s_src, s_dst,
                                                             N, (dout[1] / 128) * 2);
    agg_wave_kernel<1024, 1, 1, 0><<<ngrp, 256, 0, stream>>>(
        hB, s_src, s_dst, rowptr, csr, Bv[1], nullptr, bufR, N);
  }
  // layer 3
  {
    dim3 gg(dout[2] / 128, (N + 127) / 128);
    gemm_mfma_kernel<1, 0, 0, 1><<<gg, 256, 0, stream>>>(
        bufR, Bt[2], hB, Asv[2], Adv[2], nullptr, partS, partD, N, dout[2], din[2]);
    score_reduce_kernel<<<(N + 255) / 256, 256, 0, stream>>>(partS, partD, s_src, s_dst,
                                                             N, (dout[2] / 128) * 2);
    agg_wave_kernel<512, 1, 1, 0><<<ngrp, 256, 0, stream>>>(
        hB, s_src, s_dst, rowptr, csr, Bv[2], nullptr, bufQ, N);
  }
  // layer 4: fp32 h, fused log_softmax
  {
    dim3 gg(dout[3] / 128, (N + 127) / 128);
    gemm_mfma_kernel<0, 0, 0, 1><<<gg, 256, 0, stream>>>(
        bufQ, Bt[3], hF, Asv[3], Adv[3], nullptr, partS, partD, N, dout[3], din[3]);
    score_reduce_kernel<<<(N + 255) / 256, 256, 0, stream>>>(partS, partD, s_src, s_dst,
                                                             N, (dout[3] / 128) * 2);
    agg_wave_kernel<128, 0, 0, 1><<<ngrp, 256, 0, stream>>>(
        hF, s_src, s_dst, rowptr, csr, Bv[3], (float*)d_out, nullptr, N);
  }
}

// Round 12
// 273.498 us; speedup vs baseline: 1.6036x; 1.0431x over previous
//
#include <hip/hip_runtime.h>
#include <math.h>

#define NEG_SLOPE 0.2f
#define EPS_F 1e-16f
typedef long long ll;

typedef __attribute__((ext_vector_type(4))) float f32x4;
typedef __attribute__((ext_vector_type(8))) short bf16x8;

// ---------------- bf16 helpers (bit-level, RTN-even) ----------------
__device__ __forceinline__ unsigned short bf16_of(float f) {
  unsigned u = __float_as_uint(f);
  u += 0x7fffu + ((u >> 16) & 1u);
  return (unsigned short)(u >> 16);
}
__device__ __forceinline__ float bf16_back(unsigned short s) {
  return __uint_as_float((unsigned)s << 16);
}

__device__ __forceinline__ void gload16(const void* g, void* l) {
  __builtin_amdgcn_global_load_lds((const __attribute__((address_space(1))) void*)g,
                                   (__attribute__((address_space(3))) void*)l, 16, 0, 0);
}

// ---------------- edge dtype detection (int64 vs int32) ----------------
__global__ void detect_int64_kernel(const unsigned int* __restrict__ w, int E,
                                    int* __restrict__ flag) {
  __shared__ int nz;
  if (threadIdx.x == 0) nz = 0;
  __syncthreads();
  int cnt = E < 2048 ? E : 2048;
  int local = 0;
  for (int i = threadIdx.x; i < cnt; i += blockDim.x)
    if (w[2 * i + 1] != 0u) local++;
  if (local) atomicAdd(&nz, local);
  __syncthreads();
  if (threadIdx.x == 0) *flag = (nz == 0) ? 1 : 0;  // 1 => int64 layout
}

__device__ __forceinline__ void edge_at(const int* __restrict__ ew, int E, int e,
                                        int is64, int& s, int& d) {
  if (is64) { s = ew[2 * e]; d = ew[2 * E + 2 * e]; }
  else      { s = ew[e];     d = ew[E + e]; }
}

// ---------------- CSR build (deg = edge-count; +1 self-loop folded in scan) ----
__global__ void count_deg_kernel(const int* __restrict__ ew, int E, int* deg,
                                 const int* __restrict__ flag) {
  int is64 = *flag;
  int e = blockIdx.x * blockDim.x + threadIdx.x;
  if (e < E) {
    int s, d;
    edge_at(ew, E, e, is64, s, d);
    atomicAdd(&deg[d], 1);
  }
}

__global__ void scan_kernel(const int* __restrict__ deg, int* rowptr, int* cursor, int N) {
  __shared__ int sums[1024];
  int tid = threadIdx.x;
  int chunk = (N + 1023) >> 10;
  int start = tid * chunk;
  int end = start + chunk; if (end > N) end = N;
  int s = 0;
  for (int i = start; i < end; ++i) s += deg[i] + 1;  // +1 = self loop
  sums[tid] = s;
  __syncthreads();
  for (int off = 1; off < 1024; off <<= 1) {
    int v = (tid >= off) ? sums[tid - off] : 0;
    __syncthreads();
    sums[tid] += v;
    __syncthreads();
  }
  int run = (tid == 0) ? 0 : sums[tid - 1];
  for (int i = start; i < end; ++i) {
    rowptr[i] = run; cursor[i] = run;
    run += deg[i] + 1;
  }
  if (tid == 1023) rowptr[N] = sums[1023];
}

__global__ void fill_kernel(const int* __restrict__ ew, int E, int N, int* cursor,
                            int* csr, const int* __restrict__ flag) {
  int is64 = *flag;
  int i = blockIdx.x * blockDim.x + threadIdx.x;
  if (i < E) {
    int s, d;
    edge_at(ew, E, i, is64, s, d);
    int pos = atomicAdd(&cursor[d], 1);
    csr[pos] = s;
  } else if (i < E + N) {
    int n = i - E;
    int pos = atomicAdd(&cursor[n], 1);
    csr[pos] = n;
  }
}

// ---------------- weight conversions ----------------
__global__ __launch_bounds__(256) void convert_w_all_kernel(
    const float* __restrict__ W0, const float* __restrict__ W1,
    const float* __restrict__ W2, const float* __restrict__ W3,
    short* __restrict__ B0, short* __restrict__ B1,
    short* __restrict__ B2, short* __restrict__ B3) {
  const int Ks[4]  = {256, 1024, 1024, 512};
  const int Ncs[4] = {1024, 1024, 512, 128};
  int z = blockIdx.z;
  int K = Ks[z], Nc = Ncs[z];
  int k0 = blockIdx.x * 32, n0 = blockIdx.y * 32;
  if (k0 >= K || n0 >= Nc) return;
  const float* W = z == 0 ? W0 : (z == 1 ? W1 : (z == 2 ? W2 : W3));
  short* Bt = z == 0 ? B0 : (z == 1 ? B1 : (z == 2 ? B2 : B3));
  __shared__ float t[32][33];
  int r = threadIdx.x >> 3;          // 0..31
  int c4 = (threadIdx.x & 7) * 4;    // 0..28
  float4 v = *(const float4*)&W[(ll)(k0 + r) * Nc + n0 + c4];
  t[r][c4] = v.x; t[r][c4 + 1] = v.y; t[r][c4 + 2] = v.z; t[r][c4 + 3] = v.w;
  __syncthreads();
  float f0 = t[c4 + 0][r], f1 = t[c4 + 1][r], f2 = t[c4 + 2][r], f3 = t[c4 + 3][r];
  short4 hp = make_short4((short)bf16_of(f0), (short)bf16_of(f1),
                          (short)bf16_of(f2), (short)bf16_of(f3));
  *(short4*)&Bt[(ll)(n0 + r) * K + k0 + c4] = hp;
}

// wvec1 = W1 @ a1
__global__ void wvec_kernel(const float* __restrict__ W, const float* __restrict__ as,
                            const float* __restrict__ ad, float* __restrict__ ws,
                            float* __restrict__ wd, int K, int Nc) {
  int wid = threadIdx.x >> 6, lane = threadIdx.x & 63;
  int k = blockIdx.x * 4 + wid;
  if (k >= K) return;
  const float* row = W + (ll)k * Nc;
  float a = 0.f, b = 0.f;
  for (int j = lane; j < Nc; j += 64) {
    float w = row[j];
    a += w * as[j];
    b += w * ad[j];
  }
#pragma unroll
  for (int o = 32; o > 0; o >>= 1) {
    a += __shfl_xor(a, o, 64);
    b += __shfl_xor(b, o, 64);
  }
  if (lane == 0) { ws[k] = a; wd[k] = b; }
}

// layer-1 scores by GEMV (din=256)
__global__ void score_gemv_kernel(const float* __restrict__ x, const float* __restrict__ ws,
                                  const float* __restrict__ wd, float* __restrict__ s_src,
                                  float* __restrict__ s_dst, int N) {
  int wid = threadIdx.x >> 6, lane = threadIdx.x & 63;
  int n = blockIdx.x * 4 + wid;
  if (n >= N) return;
  float4 xv = *(const float4*)&x[(ll)n * 256 + lane * 4];
  float4 wsv = *(const float4*)&ws[lane * 4];
  float4 wdv = *(const float4*)&wd[lane * 4];
  float a = xv.x * wsv.x + xv.y * wsv.y + xv.z * wsv.z + xv.w * wsv.w;
  float b = xv.x * wdv.x + xv.y * wdv.y + xv.z * wdv.z + xv.w * wdv.w;
#pragma unroll
  for (int o = 32; o > 0; o >>= 1) {
    a += __shfl_xor(a, o, 64);
    b += __shfl_xor(b, o, 64);
  }
  if (lane == 0) { s_src[n] = a; s_dst[n] = b; }
}

// ---------------- layer-1 input-side aggregation -----------------
__global__ __launch_bounds__(256) void agg_x_kernel(
    const float* __restrict__ x, const float* __restrict__ ssrc,
    const float* __restrict__ sdst, const int* __restrict__ rowptr,
    const int* __restrict__ csr, short* __restrict__ outH, int N) {
  int wid = threadIdx.x >> 6, lane = threadIdx.x & 63;
  int node = blockIdx.x * 4 + wid;
  if (node >= N) return;
  int rs = rowptr[node];
  int nd = rowptr[node + 1] - rs;
  float sd = sdst[node];
  int d0 = lane * 4;

  float a0 = 0.f, a1 = 0.f, a2 = 0.f, a3 = 0.f;
  auto accum = [&](int s, float w) {
    float4 xv = *(const float4*)&x[(ll)s * 256 + d0];
    a0 += w * xv.x; a1 += w * xv.y; a2 += w * xv.z; a3 += w * xv.w;
  };

  if (nd <= 64) {
    int srcl = 0;
    float e = -1e30f;
    if (lane < nd) {
      srcl = csr[rs + lane];
      float t = ssrc[srcl] + sd;
      e = t > 0.f ? t : NEG_SLOPE * t;
    }
    float m = e;
#pragma unroll
    for (int o = 32; o > 0; o >>= 1) m = fmaxf(m, __shfl_xor(m, o, 64));
    float ex = (lane < nd) ? __expf(e - m) : 0.f;
    float den = ex;
#pragma unroll
    for (int o = 32; o > 0; o >>= 1) den += __shfl_xor(den, o, 64);
    float al = ex / (den + EPS_F);
    int i = 0;
    for (; i + 4 <= nd; i += 4) {
      int s0 = __shfl(srcl, i, 64), s1 = __shfl(srcl, i + 1, 64);
      int s2 = __shfl(srcl, i + 2, 64), s3 = __shfl(srcl, i + 3, 64);
      float w0 = __shfl(al, i, 64), w1 = __shfl(al, i + 1, 64);
      float w2 = __shfl(al, i + 2, 64), w3 = __shfl(al, i + 3, 64);
      accum(s0, w0); accum(s1, w1); accum(s2, w2); accum(s3, w3);
    }
    for (; i < nd; ++i) accum(__shfl(srcl, i, 64), __shfl(al, i, 64));
  } else {
    float m = -1e30f;
    for (int i = lane; i < nd; i += 64) {
      float t = ssrc[csr[rs + i]] + sd;
      t = t > 0.f ? t : NEG_SLOPE * t;
      m = fmaxf(m, t);
    }
#pragma unroll
    for (int o = 32; o > 0; o >>= 1) m = fmaxf(m, __shfl_xor(m, o, 64));
    float den = 0.f;
    for (int i = lane; i < nd; i += 64) {
      float t = ssrc[csr[rs + i]] + sd;
      t = t > 0.f ? t : NEG_SLOPE * t;
      den += __expf(t - m);
    }
#pragma unroll
    for (int o = 32; o > 0; o >>= 1) den += __shfl_xor(den, o, 64);
    float inv = 1.f / (den + EPS_F);
    for (int i = 0; i < nd; ++i) {
      int s = csr[rs + i];
      float t = ssrc[s] + sd;
      t = t > 0.f ? t : NEG_SLOPE * t;
      accum(s, __expf(t - m) * inv);
    }
  }

  unsigned short h0 = bf16_of(a0), h1 = bf16_of(a1), h2 = bf16_of(a2), h3 = bf16_of(a3);
  short4 hp = make_short4((short)h0, (short)h1, (short)h2, (short)h3);
  short4 lp = make_short4((short)bf16_of(a0 - bf16_back(h0)),
                          (short)bf16_of(a1 - bf16_back(h1)),
                          (short)bf16_of(a2 - bf16_back(h2)),
                          (short)bf16_of(a3 - bf16_back(h3)));
  ll base = (ll)node * 512 + d0;
  *(short4*)&outH[base] = hp;
  *(short4*)&outH[base + 256] = lp;
}

// ---------------- MFMA GEMM (64x128 tile) + optional fused epilogues --------
// BM=64, BN=128, BK=32; 4 waves as 2(row)x2(col); each wave 32x64 out (2x4
// frags). Doubled grid vs 128^2 tile -> ~5 blocks/CU (occupancy was the
// limit at 2.5). LDS: A 4KB (+4KB lo if SPLIT), B 8KB; chunk XOR-rotated per
// row pair, staged linear, source-permuted (both-sides rule). XCD-chunked
// bijective block swizzle keeps A-panel L2 locality.
template <int HBF16, int SPLIT, int BIASRELU, int SCORES>
__global__ __launch_bounds__(256) void gemm_mfma_kernel(
    const short* __restrict__ A, const short* __restrict__ Bt,
    void* __restrict__ Cv, const float* __restrict__ a_src,
    const float* __restrict__ a_dst, const float* __restrict__ bias,
    float* __restrict__ partS, float* __restrict__ partD, int M, int Nc, int K) {
  __shared__ char Ah[SPLIT ? 8192 : 4096];
  __shared__ char Bs[8192];
  char* Al = Ah + 4096;  // valid only when SPLIT
  int tid = threadIdx.x;

  int nwg = gridDim.x * gridDim.y;
  int hb = blockIdx.y * gridDim.x + blockIdx.x;
  int xcd = hb & 7, q = nwg >> 3, r = nwg & 7;
  int lg = (xcd < r ? xcd * (q + 1) : r * (q + 1) + (xcd - r) * q) + (hb >> 3);
  int bx = lg % gridDim.x, by = lg / gridDim.x;
  int bm = by * 64, bn = bx * 128;

  int lane = tid & 63, wid = tid >> 6;
  int wr = wid >> 1, wc = wid & 1;
  int AS = SPLIT ? 2 * K : K;  // A row stride

  f32x4 acc[2][4];
#pragma unroll
  for (int m = 0; m < 2; ++m)
#pragma unroll
    for (int n = 0; n < 4; ++n) acc[m][n] = (f32x4){0.f, 0.f, 0.f, 0.f};

  int srow = tid >> 2;                 // 0..63
  int cphys = tid & 3;                 // LDS chunk slot this thread fills
  int swz = (srow >> 1) & 3;
  int clog = (cphys ^ swz) * 8;        // bf16 k-offset actually fetched
  int ra = bm + srow; if (ra > M - 1) ra = M - 1;
  const short* aP0 = A + (ll)ra * AS + clog;
  const short* bP0 = Bt + (ll)(bn + srow) * K + clog;
  const short* bP1 = Bt + (ll)(bn + srow + 64) * K + clog;
  int dstOff = tid * 16;

  int lrow = lane & 15;
  int lchunk = ((lane >> 4) ^ ((lrow >> 1) & 3)) * 16;
  int fOffA = (wr * 32 + lrow) * 64 + lchunk;
  int fOffB = (wc * 64 + lrow) * 64 + lchunk;

  for (int kt = 0; kt < K; kt += 32) {
    gload16(aP0 + kt, Ah + dstOff);
    if constexpr (SPLIT) gload16(aP0 + K + kt, Al + dstOff);
    gload16(bP0 + kt, Bs + dstOff);
    gload16(bP1 + kt, Bs + 4096 + dstOff);
    __syncthreads();
    bf16x8 ah[2], al[2], bfr[4];
#pragma unroll
    for (int m = 0; m < 2; ++m) {
      ah[m] = *(const bf16x8*)(Ah + fOffA + m * 1024);
      if constexpr (SPLIT) al[m] = *(const bf16x8*)(Al + fOffA + m * 1024);
    }
#pragma unroll
    for (int n = 0; n < 4; ++n) bfr[n] = *(const bf16x8*)(Bs + fOffB + n * 1024);
#pragma unroll
    for (int m = 0; m < 2; ++m)
#pragma unroll
      for (int n = 0; n < 4; ++n) {
        acc[m][n] = __builtin_amdgcn_mfma_f32_16x16x32_bf16(ah[m], bfr[n], acc[m][n], 0, 0, 0);
        if constexpr (SPLIT)
          acc[m][n] = __builtin_amdgcn_mfma_f32_16x16x32_bf16(al[m], bfr[n], acc[m][n], 0, 0, 0);
      }
    __syncthreads();
  }

  int crow0 = bm + wr * 32 + (lane >> 4) * 4;
  int ccol0 = bn + wc * 64 + (lane & 15);
  float bv4[4];
  if constexpr (BIASRELU) {
#pragma unroll
    for (int n = 0; n < 4; ++n) bv4[n] = bias[ccol0 + n * 16];
  }
#pragma unroll
  for (int m = 0; m < 2; ++m) {
#pragma unroll
    for (int j = 0; j < 4; ++j) {
      int row = crow0 + m * 16 + j;
      if (row < M) {
#pragma unroll
        for (int n = 0; n < 4; ++n) {
          float v = acc[m][n][j];
          if constexpr (BIASRELU) v = fmaxf(v + bv4[n], 0.f);
          if (HBF16) ((unsigned short*)Cv)[(ll)row * Nc + ccol0 + n * 16] = bf16_of(v);
          else       ((float*)Cv)[(ll)row * Nc + ccol0 + n * 16] = v;
        }
      }
    }
  }

  if constexpr (SCORES) {
    float as4[4], ad4[4];
#pragma unroll
    for (int n = 0; n < 4; ++n) {
      as4[n] = a_src[ccol0 + n * 16];
      ad4[n] = a_dst[ccol0 + n * 16];
    }
    int p = bx * 2 + wc;
#pragma unroll
    for (int m = 0; m < 2; ++m) {
#pragma unroll
      for (int j = 0; j < 4; ++j) {
        float ps = acc[m][0][j] * as4[0] + acc[m][1][j] * as4[1] +
                   acc[m][2][j] * as4[2] + acc[m][3][j] * as4[3];
        float pd = acc[m][0][j] * ad4[0] + acc[m][1][j] * ad4[1] +
                   acc[m][2][j] * ad4[2] + acc[m][3][j] * ad4[3];
#pragma unroll
        for (int o = 1; o < 16; o <<= 1) {
          ps += __shfl_xor(ps, o, 64);
          pd += __shfl_xor(pd, o, 64);
        }
        int row = crow0 + m * 16 + j;
        if ((lane & 15) == 0 && row < M) {
          partS[(ll)p * M + row] = ps;
          partD[(ll)p * M + row] = pd;
        }
      }
    }
  }
}

// sum the per-(col-block,wc) partials -> s_src/s_dst
__global__ void score_reduce_kernel(const float* __restrict__ partS,
                                    const float* __restrict__ partD,
                                    float* __restrict__ s_src, float* __restrict__ s_dst,
                                    int N, int NP) {
  int i = blockIdx.x * blockDim.x + threadIdx.x;
  if (i >= N) return;
  float a = 0.f, b = 0.f;
  for (int p = 0; p < NP; ++p) {
    a += partS[(ll)p * N + i];
    b += partD[(ll)p * N + i];
  }
  s_src[i] = a;
  s_dst[i] = b;
}

// ---------------- wave-per-node fused softmax + weighted aggregation --------
template <int DOUT, int HIN_BF16, int OUTB16, int LOGSM>
__global__ __launch_bounds__(256) void agg_wave_kernel(
    const void* __restrict__ hv, const float* __restrict__ ssrc,
    const float* __restrict__ sdst, const int* __restrict__ rowptr,
    const int* __restrict__ csr, const float* __restrict__ bias,
    float* __restrict__ outF, short* __restrict__ outH, int N) {
  constexpr int NH = (DOUT >= 512) ? DOUT / 512 : 1;   // row halves of 512 dims
  constexpr int DPL = (DOUT >= 512) ? 8 : DOUT / 64;   // dims/lane per half
  int wid = threadIdx.x >> 6, lane = threadIdx.x & 63;
  int node = blockIdx.x * 4 + wid;
  if (node >= N) return;
  int rs = rowptr[node];
  int nd = rowptr[node + 1] - rs;
  float sd = sdst[node];
  int d0 = lane * DPL;

  float acc[NH][DPL];
#pragma unroll
  for (int hh = 0; hh < NH; ++hh)
#pragma unroll
    for (int k = 0; k < DPL; ++k) acc[hh][k] = 0.f;

  auto accum = [&](int s, float w) {
    if constexpr (HIN_BF16) {
      const unsigned short* hp = (const unsigned short*)hv + (ll)s * DOUT + d0;
#pragma unroll
      for (int hh = 0; hh < NH; ++hh) {
        bf16x8 qv = *(const bf16x8*)(hp + hh * 512);
#pragma unroll
        for (int k = 0; k < 8; ++k)
          acc[hh][k] += w * bf16_back((unsigned short)qv[k]);
      }
    } else {
      const float* hp = (const float*)hv + (ll)s * DOUT + d0;
#pragma unroll
      for (int k = 0; k < DPL; ++k) acc[0][k] += w * hp[k];
    }
  };

  if (nd <= 64) {
    int srcl = 0;
    float e = -1e30f;
    if (lane < nd) {
      srcl = csr[rs + lane];
      float t = ssrc[srcl] + sd;
      e = t > 0.f ? t : NEG_SLOPE * t;
    }
    float m = e;
#pragma unroll
    for (int o = 32; o > 0; o >>= 1) m = fmaxf(m, __shfl_xor(m, o, 64));
    float ex = (lane < nd) ? __expf(e - m) : 0.f;
    float den = ex;
#pragma unroll
    for (int o = 32; o > 0; o >>= 1) den += __shfl_xor(den, o, 64);
    float al = ex / (den + EPS_F);

    int i = 0;
    for (; i + 4 <= nd; i += 4) {
      int s0 = __shfl(srcl, i, 64), s1 = __shfl(srcl, i + 1, 64);
      int s2 = __shfl(srcl, i + 2, 64), s3 = __shfl(srcl, i + 3, 64);
      float w0 = __shfl(al, i, 64), w1 = __shfl(al, i + 1, 64);
      float w2 = __shfl(al, i + 2, 64), w3 = __shfl(al, i + 3, 64);
      accum(s0, w0); accum(s1, w1); accum(s2, w2); accum(s3, w3);
    }
    for (; i < nd; ++i) accum(__shfl(srcl, i, 64), __shfl(al, i, 64));
  } else {
    float m = -1e30f;
    for (int i = lane; i < nd; i += 64) {
      float t = ssrc[csr[rs + i]] + sd;
      t = t > 0.f ? t : NEG_SLOPE * t;
      m = fmaxf(m, t);
    }
#pragma unroll
    for (int o = 32; o > 0; o >>= 1) m = fmaxf(m, __shfl_xor(m, o, 64));
    float den = 0.f;
    for (int i = lane; i < nd; i += 64) {
      float t = ssrc[csr[rs + i]] + sd;
      t = t > 0.f ? t : NEG_SLOPE * t;
      den += __expf(t - m);
    }
#pragma unroll
    for (int o = 32; o > 0; o >>= 1) den += __shfl_xor(den, o, 64);
    float inv = 1.f / (den + EPS_F);
    for (int i = 0; i < nd; ++i) {
      int s = csr[rs + i];  // wave-uniform broadcast load
      float t = ssrc[s] + sd;
      t = t > 0.f ? t : NEG_SLOPE * t;
      accum(s, __expf(t - m) * inv);
    }
  }

  if constexpr (OUTB16) {
#pragma unroll
    for (int hh = 0; hh < NH; ++hh) {
      int d = hh * 512 + d0;
      bf16x8 hp8;
#pragma unroll
      for (int k = 0; k < 8; ++k) {
        float v = fmaxf(acc[hh][k] + bias[d + k], 0.f);
        hp8[k] = (short)bf16_of(v);
      }
      *(bf16x8*)&outH[(ll)node * DOUT + d] = hp8;
    }
  } else if constexpr (LOGSM) {
    float v0 = acc[0][0] + bias[d0 + 0];
    float v1 = acc[0][1] + bias[d0 + 1];
    float mx = fmaxf(v0, v1);
#pragma unroll
    for (int o = 32; o > 0; o >>= 1) mx = fmaxf(mx, __shfl_xor(mx, o, 64));
    float s = __expf(v0 - mx) + __expf(v1 - mx);
#pragma unroll
    for (int o = 32; o > 0; o >>= 1) s += __shfl_xor(s, o, 64);
    float ls = logf(s);
    outF[(ll)node * DOUT + d0 + 0] = v0 - mx - ls;
    outF[(ll)node * DOUT + d0 + 1] = v1 - mx - ls;
  } else {
#pragma unroll
    for (int k = 0; k < DPL; ++k)
      outF[(ll)node * DOUT + d0 + k] = acc[0][k] + bias[d0 + k];
  }
}

// ---------------- launch ----------------
extern "C" void kernel_launch(void* const* d_in, const int* in_sizes, int n_in,
                              void* d_out, int out_size, void* d_ws, size_t ws_size,
                              hipStream_t stream) {
  const float* x = (const float*)d_in[0];
  const int* ew = (const int*)d_in[1];
  int N = in_sizes[0] / 256;
  int E = in_sizes[1] / 2;

  const float* W[4]   = {(const float*)d_in[2],  (const float*)d_in[6],
                         (const float*)d_in[10], (const float*)d_in[14]};
  const float* Asv[4] = {(const float*)d_in[3],  (const float*)d_in[7],
                         (const float*)d_in[11], (const float*)d_in[15]};
  const float* Adv[4] = {(const float*)d_in[4],  (const float*)d_in[8],
                         (const float*)d_in[12], (const float*)d_in[16]};
  const float* Bv[4]  = {(const float*)d_in[5],  (const float*)d_in[9],
                         (const float*)d_in[13], (const float*)d_in[17]};
  const int din[4]  = {256, 1024, 1024, 512};
  const int dout[4] = {1024, 1024, 512, 128};

  char* ws = (char*)d_ws;
  size_t off = 0;
  auto alloc = [&](size_t bytes) {
    void* p = ws + off;
    off += (bytes + 255) & ~(size_t)255;
    return p;
  };
  unsigned short* hB = (unsigned short*)alloc((size_t)N * 1024 * 2);  // bf16 h (layers 2-3)
  float* hF   = (float*)alloc((size_t)N * 128 * 4);                   // fp32 h (layer 4)
  short* bufP = (short*)alloc((size_t)N * 512 * 2);   // xagg split [hi|lo]
  short* bufQ = (short*)alloc((size_t)N * 1024 * 2);  // inter-layer bf16 act
  short* bufR = (short*)alloc((size_t)N * 1024 * 2);
  float* s_src = (float*)alloc((size_t)N * 4);
  float* s_dst = (float*)alloc((size_t)N * 4);
  float* partS = (float*)alloc((size_t)16 * N * 4);
  float* partD = (float*)alloc((size_t)16 * N * 4);
  float* wvS  = (float*)alloc((size_t)256 * 4);
  float* wvD  = (float*)alloc((size_t)256 * 4);
  int* deg    = (int*)alloc((size_t)(N + 1) * 4);
  int* rowptr = (int*)alloc((size_t)(N + 1) * 4);
  int* cursor = (int*)alloc((size_t)(N + 1) * 4);
  int* csr    = (int*)alloc((size_t)(E + N) * 4);
  int* flag   = (int*)alloc(256);
  short* Bt[4];
  for (int l = 0; l < 4; ++l) Bt[l] = (short*)alloc((size_t)dout[l] * din[l] * 2);

  detect_int64_kernel<<<1, 256, 0, stream>>>((const unsigned int*)ew, E, flag);
  hipMemsetAsync(deg, 0, (size_t)(N + 1) * 4, stream);
  count_deg_kernel<<<(E + 255) / 256, 256, 0, stream>>>(ew, E, deg, flag);
  scan_kernel<<<1, 1024, 0, stream>>>(deg, rowptr, cursor, N);
  fill_kernel<<<(E + N + 255) / 256, 256, 0, stream>>>(ew, E, N, cursor, csr, flag);

  {
    dim3 cg(32, 32, 4);
    convert_w_all_kernel<<<cg, 256, 0, stream>>>(W[0], W[1], W[2], W[3],
                                                 Bt[0], Bt[1], Bt[2], Bt[3]);
  }
  wvec_kernel<<<64, 256, 0, stream>>>(W[0], Asv[0], Adv[0], wvS, wvD, 256, 1024);

  int ngrp = (N + 3) / 4;
  int mgrp = (N + 63) / 64;
  // layer 1: GEMV scores -> input-side aggregation -> split GEMM (bias+relu fused)
  {
    score_gemv_kernel<<<ngrp, 256, 0, stream>>>(x, wvS, wvD, s_src, s_dst, N);
    agg_x_kernel<<<ngrp, 256, 0, stream>>>(x, s_src, s_dst, rowptr, csr, bufP, N);
    dim3 gg(dout[0] / 128, mgrp);
    gemm_mfma_kernel<1, 1, 1, 0><<<gg, 256, 0, stream>>>(
        bufP, Bt[0], bufQ, nullptr, nullptr, Bv[0], partS, partD, N, dout[0], din[0]);
  }
  // layer 2: GEMM (h2 + fused scores) -> reduce -> output-side agg
  {
    dim3 gg(dout[1] / 128, mgrp);
    gemm_mfma_kernel<1, 0, 0, 1><<<gg, 256, 0, stream>>>(
        bufQ, Bt[1], hB, Asv[1], Adv[1], nullptr, partS, partD, N, dout[1], din[1]);
    score_reduce_kernel<<<(N + 255) / 256, 256, 0, stream>>>(partS, partD, s_src, s_dst,
                                                             N, (dout[1] / 128) * 2);
    agg_wave_kernel<1024, 1, 1, 0><<<ngrp, 256, 0, stream>>>(
        hB, s_src, s_dst, rowptr, csr, Bv[1], nullptr, bufR, N);
  }
  // layer 3
  {
    dim3 gg(dout[2] / 128, mgrp);
    gemm_mfma_kernel<1, 0, 0, 1><<<gg, 256, 0, stream>>>(
        bufR, Bt[2], hB, Asv[2], Adv[2], nullptr, partS, partD, N, dout[2], din[2]);
    score_reduce_kernel<<<(N + 255) / 256, 256, 0, stream>>>(partS, partD, s_src, s_dst,
                                                             N, (dout[2] / 128) * 2);
    agg_wave_kernel<512, 1, 1, 0><<<ngrp, 256, 0, stream>>>(
        hB, s_src, s_dst, rowptr, csr, Bv[2], nullptr, bufQ, N);
  }
  // layer 4: fp32 h, fused log_softmax
  {
    dim3 gg(dout[3] / 128, mgrp);
    gemm_mfma_kernel<0, 0, 0, 1><<<gg, 256, 0, stream>>>(
        bufQ, Bt[3], hF, Asv[3], Adv[3], nullptr, partS, partD, N, dout[3], din[3]);
    score_reduce_kernel<<<(N + 255) / 256, 256, 0, stream>>>(partS, partD, s_src, s_dst,
                                                             N, (dout[3] / 128) * 2);
    agg_wave_kernel<128, 0, 0, 1><<<ngrp, 256, 0, stream>>>(
        hF, s_src, s_dst, rowptr, csr, Bv[3], (float*)d_out, nullptr, N);
  }
}

// Round 13
// 271.331 us; speedup vs baseline: 1.6164x; 1.0080x over previous
//
#include <hip/hip_runtime.h>
#include <math.h>

#define NEG_SLOPE 0.2f
#define EPS_F 1e-16f
typedef long long ll;

typedef __attribute__((ext_vector_type(4))) float f32x4;
typedef __attribute__((ext_vector_type(8))) short bf16x8;

// ---------------- bf16 helpers (bit-level, RTN-even) ----------------
__device__ __forceinline__ unsigned short bf16_of(float f) {
  unsigned u = __float_as_uint(f);
  u += 0x7fffu + ((u >> 16) & 1u);
  return (unsigned short)(u >> 16);
}
__device__ __forceinline__ float bf16_back(unsigned short s) {
  return __uint_as_float((unsigned)s << 16);
}

__device__ __forceinline__ void gload16(const void* g, void* l) {
  __builtin_amdgcn_global_load_lds((const __attribute__((address_space(1))) void*)g,
                                   (__attribute__((address_space(3))) void*)l, 16, 0, 0);
}

// ---------------- edge dtype detection (int64 vs int32) ----------------
__global__ void detect_int64_kernel(const unsigned int* __restrict__ w, int E,
                                    int* __restrict__ flag) {
  __shared__ int nz;
  if (threadIdx.x == 0) nz = 0;
  __syncthreads();
  int cnt = E < 2048 ? E : 2048;
  int local = 0;
  for (int i = threadIdx.x; i < cnt; i += blockDim.x)
    if (w[2 * i + 1] != 0u) local++;
  if (local) atomicAdd(&nz, local);
  __syncthreads();
  if (threadIdx.x == 0) *flag = (nz == 0) ? 1 : 0;  // 1 => int64 layout
}

__device__ __forceinline__ void edge_at(const int* __restrict__ ew, int E, int e,
                                        int is64, int& s, int& d) {
  if (is64) { s = ew[2 * e]; d = ew[2 * E + 2 * e]; }
  else      { s = ew[e];     d = ew[E + e]; }
}

// ---------------- CSR build (deg = edge-count; +1 self-loop folded in scan) ----
__global__ void count_deg_kernel(const int* __restrict__ ew, int E, int* deg,
                                 const int* __restrict__ flag) {
  int is64 = *flag;
  int e = blockIdx.x * blockDim.x + threadIdx.x;
  if (e < E) {
    int s, d;
    edge_at(ew, E, e, is64, s, d);
    atomicAdd(&deg[d], 1);
  }
}

__global__ void scan_kernel(const int* __restrict__ deg, int* rowptr, int* cursor, int N) {
  __shared__ int sums[1024];
  int tid = threadIdx.x;
  int chunk = (N + 1023) >> 10;
  int start = tid * chunk;
  int end = start + chunk; if (end > N) end = N;
  int s = 0;
  for (int i = start; i < end; ++i) s += deg[i] + 1;  // +1 = self loop
  sums[tid] = s;
  __syncthreads();
  for (int off = 1; off < 1024; off <<= 1) {
    int v = (tid >= off) ? sums[tid - off] : 0;
    __syncthreads();
    sums[tid] += v;
    __syncthreads();
  }
  int run = (tid == 0) ? 0 : sums[tid - 1];
  for (int i = start; i < end; ++i) {
    rowptr[i] = run; cursor[i] = run;
    run += deg[i] + 1;
  }
  if (tid == 1023) rowptr[N] = sums[1023];
}

__global__ void fill_kernel(const int* __restrict__ ew, int E, int N, int* cursor,
                            int* csr, const int* __restrict__ flag) {
  int is64 = *flag;
  int i = blockIdx.x * blockDim.x + threadIdx.x;
  if (i < E) {
    int s, d;
    edge_at(ew, E, i, is64, s, d);
    int pos = atomicAdd(&cursor[d], 1);
    csr[pos] = s;
  } else if (i < E + N) {
    int n = i - E;
    int pos = atomicAdd(&cursor[n], 1);
    csr[pos] = n;
  }
}

// ---------------- weight conversions ----------------
__global__ __launch_bounds__(256) void convert_w_all_kernel(
    const float* __restrict__ W0, const float* __restrict__ W1,
    const float* __restrict__ W2, const float* __restrict__ W3,
    short* __restrict__ B0, short* __restrict__ B1,
    short* __restrict__ B2, short* __restrict__ B3) {
  const int Ks[4]  = {256, 1024, 1024, 512};
  const int Ncs[4] = {1024, 1024, 512, 128};
  int z = blockIdx.z;
  int K = Ks[z], Nc = Ncs[z];
  int k0 = blockIdx.x * 32, n0 = blockIdx.y * 32;
  if (k0 >= K || n0 >= Nc) return;
  const float* W = z == 0 ? W0 : (z == 1 ? W1 : (z == 2 ? W2 : W3));
  short* Bt = z == 0 ? B0 : (z == 1 ? B1 : (z == 2 ? B2 : B3));
  __shared__ float t[32][33];
  int r = threadIdx.x >> 3;          // 0..31
  int c4 = (threadIdx.x & 7) * 4;    // 0..28
  float4 v = *(const float4*)&W[(ll)(k0 + r) * Nc + n0 + c4];
  t[r][c4] = v.x; t[r][c4 + 1] = v.y; t[r][c4 + 2] = v.z; t[r][c4 + 3] = v.w;
  __syncthreads();
  float f0 = t[c4 + 0][r], f1 = t[c4 + 1][r], f2 = t[c4 + 2][r], f3 = t[c4 + 3][r];
  short4 hp = make_short4((short)bf16_of(f0), (short)bf16_of(f1),
                          (short)bf16_of(f2), (short)bf16_of(f3));
  *(short4*)&Bt[(ll)(n0 + r) * K + k0 + c4] = hp;
}

// wvec for layers 0,2,3: wv[k] = sum_j W[k][j]*a[j]; offsets {0,256,1280}
__global__ void wvec_all_kernel(
    const float* __restrict__ W0, const float* __restrict__ as0, const float* __restrict__ ad0,
    const float* __restrict__ W2, const float* __restrict__ as2, const float* __restrict__ ad2,
    const float* __restrict__ W3, const float* __restrict__ as3, const float* __restrict__ ad3,
    float* __restrict__ wvS, float* __restrict__ wvD) {
  const int Ks[3]   = {256, 1024, 512};
  const int Ncs[3]  = {1024, 512, 128};
  const int offs[3] = {0, 256, 1280};
  int zi = blockIdx.y;
  int K = Ks[zi], Nc = Ncs[zi];
  int wid = threadIdx.x >> 6, lane = threadIdx.x & 63;
  int k = blockIdx.x * 4 + wid;
  if (k >= K) return;
  const float* W  = zi == 0 ? W0 : (zi == 1 ? W2 : W3);
  const float* as = zi == 0 ? as0 : (zi == 1 ? as2 : as3);
  const float* ad = zi == 0 ? ad0 : (zi == 1 ? ad2 : ad3);
  const float* row = W + (ll)k * Nc;
  float a = 0.f, b = 0.f;
  for (int j = lane; j < Nc; j += 64) {
    float w = row[j];
    a += w * as[j];
    b += w * ad[j];
  }
#pragma unroll
  for (int o = 32; o > 0; o >>= 1) {
    a += __shfl_xor(a, o, 64);
    b += __shfl_xor(b, o, 64);
  }
  if (lane == 0) { wvS[offs[zi] + k] = a; wvD[offs[zi] + k] = b; }
}

// layer-1 scores by GEMV (din=256)
__global__ void score_gemv_kernel(const float* __restrict__ x, const float* __restrict__ ws,
                                  const float* __restrict__ wd, float* __restrict__ s_src,
                                  float* __restrict__ s_dst, int N) {
  int wid = threadIdx.x >> 6, lane = threadIdx.x & 63;
  int n = blockIdx.x * 4 + wid;
  if (n >= N) return;
  float4 xv = *(const float4*)&x[(ll)n * 256 + lane * 4];
  float4 wsv = *(const float4*)&ws[lane * 4];
  float4 wdv = *(const float4*)&wd[lane * 4];
  float a = xv.x * wsv.x + xv.y * wsv.y + xv.z * wsv.z + xv.w * wsv.w;
  float b = xv.x * wdv.x + xv.y * wdv.y + xv.z * wdv.z + xv.w * wdv.w;
#pragma unroll
  for (int o = 32; o > 0; o >>= 1) {
    a += __shfl_xor(a, o, 64);
    b += __shfl_xor(b, o, 64);
  }
  if (lane == 0) { s_src[n] = a; s_dst[n] = b; }
}

// ---------------- layer-1 input-side aggregation -----------------
__global__ __launch_bounds__(256) void agg_x_kernel(
    const float* __restrict__ x, const float* __restrict__ ssrc,
    const float* __restrict__ sdst, const int* __restrict__ rowptr,
    const int* __restrict__ csr, short* __restrict__ outH, int N) {
  int wid = threadIdx.x >> 6, lane = threadIdx.x & 63;
  int node = blockIdx.x * 4 + wid;
  if (node >= N) return;
  int rs = rowptr[node];
  int nd = rowptr[node + 1] - rs;
  float sd = sdst[node];
  int d0 = lane * 4;

  float a0 = 0.f, a1 = 0.f, a2 = 0.f, a3 = 0.f;
  auto accum = [&](int s, float w) {
    float4 xv = *(const float4*)&x[(ll)s * 256 + d0];
    a0 += w * xv.x; a1 += w * xv.y; a2 += w * xv.z; a3 += w * xv.w;
  };

  if (nd <= 64) {
    int srcl = 0;
    float e = -1e30f;
    if (lane < nd) {
      srcl = csr[rs + lane];
      float t = ssrc[srcl] + sd;
      e = t > 0.f ? t : NEG_SLOPE * t;
    }
    float m = e;
#pragma unroll
    for (int o = 32; o > 0; o >>= 1) m = fmaxf(m, __shfl_xor(m, o, 64));
    float ex = (lane < nd) ? __expf(e - m) : 0.f;
    float den = ex;
#pragma unroll
    for (int o = 32; o > 0; o >>= 1) den += __shfl_xor(den, o, 64);
    float al = ex / (den + EPS_F);
    int i = 0;
    for (; i + 8 <= nd; i += 8) {
      int ssx[8]; float ww[8];
#pragma unroll
      for (int u = 0; u < 8; ++u) {
        ssx[u] = __shfl(srcl, i + u, 64);
        ww[u] = __shfl(al, i + u, 64);
      }
#pragma unroll
      for (int u = 0; u < 8; ++u) accum(ssx[u], ww[u]);
    }
    for (; i < nd; ++i) accum(__shfl(srcl, i, 64), __shfl(al, i, 64));
  } else {
    float m = -1e30f;
    for (int i = lane; i < nd; i += 64) {
      float t = ssrc[csr[rs + i]] + sd;
      t = t > 0.f ? t : NEG_SLOPE * t;
      m = fmaxf(m, t);
    }
#pragma unroll
    for (int o = 32; o > 0; o >>= 1) m = fmaxf(m, __shfl_xor(m, o, 64));
    float den = 0.f;
    for (int i = lane; i < nd; i += 64) {
      float t = ssrc[csr[rs + i]] + sd;
      t = t > 0.f ? t : NEG_SLOPE * t;
      den += __expf(t - m);
    }
#pragma unroll
    for (int o = 32; o > 0; o >>= 1) den += __shfl_xor(den, o, 64);
    float inv = 1.f / (den + EPS_F);
    for (int i = 0; i < nd; ++i) {
      int s = csr[rs + i];
      float t = ssrc[s] + sd;
      t = t > 0.f ? t : NEG_SLOPE * t;
      accum(s, __expf(t - m) * inv);
    }
  }

  unsigned short h0 = bf16_of(a0), h1 = bf16_of(a1), h2 = bf16_of(a2), h3 = bf16_of(a3);
  short4 hp = make_short4((short)h0, (short)h1, (short)h2, (short)h3);
  short4 lp = make_short4((short)bf16_of(a0 - bf16_back(h0)),
                          (short)bf16_of(a1 - bf16_back(h1)),
                          (short)bf16_of(a2 - bf16_back(h2)),
                          (short)bf16_of(a3 - bf16_back(h3)));
  ll base = (ll)node * 512 + d0;
  *(short4*)&outH[base] = hp;
  *(short4*)&outH[base + 256] = lp;
}

// ---------------- MFMA GEMM (64x128 tile) + optional fused epilogues --------
template <int HBF16, int SPLIT, int BIASRELU, int SCORES>
__global__ __launch_bounds__(256) void gemm_mfma_kernel(
    const short* __restrict__ A, const short* __restrict__ Bt,
    void* __restrict__ Cv, const float* __restrict__ a_src,
    const float* __restrict__ a_dst, const float* __restrict__ bias,
    float* __restrict__ partS, float* __restrict__ partD, int M, int Nc, int K) {
  __shared__ char Ah[SPLIT ? 8192 : 4096];
  __shared__ char Bs[8192];
  char* Al = Ah + 4096;  // valid only when SPLIT
  int tid = threadIdx.x;

  int nwg = gridDim.x * gridDim.y;
  int hb = blockIdx.y * gridDim.x + blockIdx.x;
  int xcd = hb & 7, q = nwg >> 3, r = nwg & 7;
  int lg = (xcd < r ? xcd * (q + 1) : r * (q + 1) + (xcd - r) * q) + (hb >> 3);
  int bx = lg % gridDim.x, by = lg / gridDim.x;
  int bm = by * 64, bn = bx * 128;

  int lane = tid & 63, wid = tid >> 6;
  int wr = wid >> 1, wc = wid & 1;
  int AS = SPLIT ? 2 * K : K;  // A row stride

  f32x4 acc[2][4];
#pragma unroll
  for (int m = 0; m < 2; ++m)
#pragma unroll
    for (int n = 0; n < 4; ++n) acc[m][n] = (f32x4){0.f, 0.f, 0.f, 0.f};

  int srow = tid >> 2;                 // 0..63
  int cphys = tid & 3;                 // LDS chunk slot this thread fills
  int swz = (srow >> 1) & 3;
  int clog = (cphys ^ swz) * 8;        // bf16 k-offset actually fetched
  int ra = bm + srow; if (ra > M - 1) ra = M - 1;
  const short* aP0 = A + (ll)ra * AS + clog;
  const short* bP0 = Bt + (ll)(bn + srow) * K + clog;
  const short* bP1 = Bt + (ll)(bn + srow + 64) * K + clog;
  int dstOff = tid * 16;

  int lrow = lane & 15;
  int lchunk = ((lane >> 4) ^ ((lrow >> 1) & 3)) * 16;
  int fOffA = (wr * 32 + lrow) * 64 + lchunk;
  int fOffB = (wc * 64 + lrow) * 64 + lchunk;

  for (int kt = 0; kt < K; kt += 32) {
    gload16(aP0 + kt, Ah + dstOff);
    if constexpr (SPLIT) gload16(aP0 + K + kt, Al + dstOff);
    gload16(bP0 + kt, Bs + dstOff);
    gload16(bP1 + kt, Bs + 4096 + dstOff);
    __syncthreads();
    bf16x8 ah[2], al[2], bfr[4];
#pragma unroll
    for (int m = 0; m < 2; ++m) {
      ah[m] = *(const bf16x8*)(Ah + fOffA + m * 1024);
      if constexpr (SPLIT) al[m] = *(const bf16x8*)(Al + fOffA + m * 1024);
    }
#pragma unroll
    for (int n = 0; n < 4; ++n) bfr[n] = *(const bf16x8*)(Bs + fOffB + n * 1024);
#pragma unroll
    for (int m = 0; m < 2; ++m)
#pragma unroll
      for (int n = 0; n < 4; ++n) {
        acc[m][n] = __builtin_amdgcn_mfma_f32_16x16x32_bf16(ah[m], bfr[n], acc[m][n], 0, 0, 0);
        if constexpr (SPLIT)
          acc[m][n] = __builtin_amdgcn_mfma_f32_16x16x32_bf16(al[m], bfr[n], acc[m][n], 0, 0, 0);
      }
    __syncthreads();
  }

  int crow0 = bm + wr * 32 + (lane >> 4) * 4;
  int ccol0 = bn + wc * 64 + (lane & 15);
  float bv4[4];
  if constexpr (BIASRELU) {
#pragma unroll
    for (int n = 0; n < 4; ++n) bv4[n] = bias[ccol0 + n * 16];
  }
#pragma unroll
  for (int m = 0; m < 2; ++m) {
#pragma unroll
    for (int j = 0; j < 4; ++j) {
      int row = crow0 + m * 16 + j;
      if (row < M) {
#pragma unroll
        for (int n = 0; n < 4; ++n) {
          float v = acc[m][n][j];
          if constexpr (BIASRELU) v = fmaxf(v + bv4[n], 0.f);
          if (HBF16) ((unsigned short*)Cv)[(ll)row * Nc + ccol0 + n * 16] = bf16_of(v);
          else       ((float*)Cv)[(ll)row * Nc + ccol0 + n * 16] = v;
        }
      }
    }
  }

  if constexpr (SCORES) {
    float as4[4], ad4[4];
#pragma unroll
    for (int n = 0; n < 4; ++n) {
      as4[n] = a_src[ccol0 + n * 16];
      ad4[n] = a_dst[ccol0 + n * 16];
    }
    int p = bx * 2 + wc;
#pragma unroll
    for (int m = 0; m < 2; ++m) {
#pragma unroll
      for (int j = 0; j < 4; ++j) {
        float ps = acc[m][0][j] * as4[0] + acc[m][1][j] * as4[1] +
                   acc[m][2][j] * as4[2] + acc[m][3][j] * as4[3];
        float pd = acc[m][0][j] * ad4[0] + acc[m][1][j] * ad4[1] +
                   acc[m][2][j] * ad4[2] + acc[m][3][j] * ad4[3];
#pragma unroll
        for (int o = 1; o < 16; o <<= 1) {
          ps += __shfl_xor(ps, o, 64);
          pd += __shfl_xor(pd, o, 64);
        }
        int row = crow0 + m * 16 + j;
        if ((lane & 15) == 0 && row < M) {
          partS[(ll)p * M + row] = ps;
          partD[(ll)p * M + row] = pd;
        }
      }
    }
  }
}

// sum the per-(col-block,wc) partials -> s_src/s_dst
__global__ void score_reduce_kernel(const float* __restrict__ partS,
                                    const float* __restrict__ partD,
                                    float* __restrict__ s_src, float* __restrict__ s_dst,
                                    int N, int NP) {
  int i = blockIdx.x * blockDim.x + threadIdx.x;
  if (i >= N) return;
  float a = 0.f, b = 0.f;
  for (int p = 0; p < NP; ++p) {
    a += partS[(ll)p * N + i];
    b += partD[(ll)p * N + i];
  }
  s_src[i] = a;
  s_dst[i] = b;
}

// ---------------- wave-per-node fused softmax + weighted aggregation --------
// SCORENEXT: compute next layer's scores from the fp32 output row in regs
// (s = out . wvec_next), write to oSs/oSd (ping-pong buffers vs ssrc/sdst).
template <int DOUT, int HIN_BF16, int OUTB16, int LOGSM, int SCORENEXT>
__global__ __launch_bounds__(256) void agg_wave_kernel(
    const void* __restrict__ hv, const float* __restrict__ ssrc,
    const float* __restrict__ sdst, const int* __restrict__ rowptr,
    const int* __restrict__ csr, const float* __restrict__ bias,
    float* __restrict__ outF, short* __restrict__ outH,
    const float* __restrict__ wvnS, const float* __restrict__ wvnD,
    float* __restrict__ oSs, float* __restrict__ oSd, int N) {
  constexpr int NH = (DOUT >= 512) ? DOUT / 512 : 1;   // row halves of 512 dims
  constexpr int DPL = (DOUT >= 512) ? 8 : DOUT / 64;   // dims/lane per half
  int wid = threadIdx.x >> 6, lane = threadIdx.x & 63;
  int node = blockIdx.x * 4 + wid;
  if (node >= N) return;
  int rs = rowptr[node];
  int nd = rowptr[node + 1] - rs;
  float sd = sdst[node];
  int d0 = lane * DPL;

  float acc[NH][DPL];
#pragma unroll
  for (int hh = 0; hh < NH; ++hh)
#pragma unroll
    for (int k = 0; k < DPL; ++k) acc[hh][k] = 0.f;

  auto accum = [&](int s, float w) {
    if constexpr (HIN_BF16) {
      const unsigned short* hp = (const unsigned short*)hv + (ll)s * DOUT + d0;
#pragma unroll
      for (int hh = 0; hh < NH; ++hh) {
        bf16x8 qv = *(const bf16x8*)(hp + hh * 512);
#pragma unroll
        for (int k = 0; k < 8; ++k)
          acc[hh][k] += w * bf16_back((unsigned short)qv[k]);
      }
    } else {
      const float* hp = (const float*)hv + (ll)s * DOUT + d0;
#pragma unroll
      for (int k = 0; k < DPL; ++k) acc[0][k] += w * hp[k];
    }
  };

  if (nd <= 64) {
    int srcl = 0;
    float e = -1e30f;
    if (lane < nd) {
      srcl = csr[rs + lane];
      float t = ssrc[srcl] + sd;
      e = t > 0.f ? t : NEG_SLOPE * t;
    }
    float m = e;
#pragma unroll
    for (int o = 32; o > 0; o >>= 1) m = fmaxf(m, __shfl_xor(m, o, 64));
    float ex = (lane < nd) ? __expf(e - m) : 0.f;
    float den = ex;
#pragma unroll
    for (int o = 32; o > 0; o >>= 1) den += __shfl_xor(den, o, 64);
    float al = ex / (den + EPS_F);

    int i = 0;
    for (; i + 8 <= nd; i += 8) {
      int ssx[8]; float ww[8];
#pragma unroll
      for (int u = 0; u < 8; ++u) {
        ssx[u] = __shfl(srcl, i + u, 64);
        ww[u] = __shfl(al, i + u, 64);
      }
#pragma unroll
      for (int u = 0; u < 8; ++u) accum(ssx[u], ww[u]);
    }
    for (; i < nd; ++i) accum(__shfl(srcl, i, 64), __shfl(al, i, 64));
  } else {
    float m = -1e30f;
    for (int i = lane; i < nd; i += 64) {
      float t = ssrc[csr[rs + i]] + sd;
      t = t > 0.f ? t : NEG_SLOPE * t;
      m = fmaxf(m, t);
    }
#pragma unroll
    for (int o = 32; o > 0; o >>= 1) m = fmaxf(m, __shfl_xor(m, o, 64));
    float den = 0.f;
    for (int i = lane; i < nd; i += 64) {
      float t = ssrc[csr[rs + i]] + sd;
      t = t > 0.f ? t : NEG_SLOPE * t;
      den += __expf(t - m);
    }
#pragma unroll
    for (int o = 32; o > 0; o >>= 1) den += __shfl_xor(den, o, 64);
    float inv = 1.f / (den + EPS_F);
    for (int i = 0; i < nd; ++i) {
      int s = csr[rs + i];  // wave-uniform broadcast load
      float t = ssrc[s] + sd;
      t = t > 0.f ? t : NEG_SLOPE * t;
      accum(s, __expf(t - m) * inv);
    }
  }

  if constexpr (OUTB16) {
    float ps = 0.f, pd = 0.f;
#pragma unroll
    for (int hh = 0; hh < NH; ++hh) {
      int d = hh * 512 + d0;
      bf16x8 hp8;
#pragma unroll
      for (int k = 0; k < 8; ++k) {
        float v = fmaxf(acc[hh][k] + bias[d + k], 0.f);
        hp8[k] = (short)bf16_of(v);
        if constexpr (SCORENEXT) {
          ps += v * wvnS[d + k];
          pd += v * wvnD[d + k];
        }
      }
      *(bf16x8*)&outH[(ll)node * DOUT + d] = hp8;
    }
    if constexpr (SCORENEXT) {
#pragma unroll
      for (int o = 32; o > 0; o >>= 1) {
        ps += __shfl_xor(ps, o, 64);
        pd += __shfl_xor(pd, o, 64);
      }
      if (lane == 0) { oSs[node] = ps; oSd[node] = pd; }
    }
  } else if constexpr (LOGSM) {
    float v0 = acc[0][0] + bias[d0 + 0];
    float v1 = acc[0][1] + bias[d0 + 1];
    float mx = fmaxf(v0, v1);
#pragma unroll
    for (int o = 32; o > 0; o >>= 1) mx = fmaxf(mx, __shfl_xor(mx, o, 64));
    float s = __expf(v0 - mx) + __expf(v1 - mx);
#pragma unroll
    for (int o = 32; o > 0; o >>= 1) s += __shfl_xor(s, o, 64);
    float ls = logf(s);
    outF[(ll)node * DOUT + d0 + 0] = v0 - mx - ls;
    outF[(ll)node * DOUT + d0 + 1] = v1 - mx - ls;
  } else {
#pragma unroll
    for (int k = 0; k < DPL; ++k)
      outF[(ll)node * DOUT + d0 + k] = acc[0][k] + bias[d0 + k];
  }
}

// ---------------- launch ----------------
extern "C" void kernel_launch(void* const* d_in, const int* in_sizes, int n_in,
                              void* d_out, int out_size, void* d_ws, size_t ws_size,
                              hipStream_t stream) {
  const float* x = (const float*)d_in[0];
  const int* ew = (const int*)d_in[1];
  int N = in_sizes[0] / 256;
  int E = in_sizes[1] / 2;

  const float* W[4]   = {(const float*)d_in[2],  (const float*)d_in[6],
                         (const float*)d_in[10], (const float*)d_in[14]};
  const float* Asv[4] = {(const float*)d_in[3],  (const float*)d_in[7],
                         (const float*)d_in[11], (const float*)d_in[15]};
  const float* Adv[4] = {(const float*)d_in[4],  (const float*)d_in[8],
                         (const float*)d_in[12], (const float*)d_in[16]};
  const float* Bv[4]  = {(const float*)d_in[5],  (const float*)d_in[9],
                         (const float*)d_in[13], (const float*)d_in[17]};
  const int din[4]  = {256, 1024, 1024, 512};
  const int dout[4] = {1024, 1024, 512, 128};

  char* ws = (char*)d_ws;
  size_t off = 0;
  auto alloc = [&](size_t bytes) {
    void* p = ws + off;
    off += (bytes + 255) & ~(size_t)255;
    return p;
  };
  unsigned short* hB = (unsigned short*)alloc((size_t)N * 1024 * 2);  // bf16 h (layers 2-3)
  float* hF   = (float*)alloc((size_t)N * 128 * 4);                   // fp32 h (layer 4)
  short* bufP = (short*)alloc((size_t)N * 512 * 2);   // xagg split [hi|lo]
  short* bufQ = (short*)alloc((size_t)N * 1024 * 2);  // inter-layer bf16 act
  short* bufR = (short*)alloc((size_t)N * 1024 * 2);
  float* s_src  = (float*)alloc((size_t)N * 4);
  float* s_dst  = (float*)alloc((size_t)N * 4);
  float* s_src2 = (float*)alloc((size_t)N * 4);
  float* s_dst2 = (float*)alloc((size_t)N * 4);
  float* partS = (float*)alloc((size_t)16 * N * 4);
  float* partD = (float*)alloc((size_t)16 * N * 4);
  float* wvS  = (float*)alloc((size_t)2048 * 4);  // l0@0, l2@256, l3@1280
  float* wvD  = (float*)alloc((size_t)2048 * 4);
  int* deg    = (int*)alloc((size_t)(N + 1) * 4);
  int* rowptr = (int*)alloc((size_t)(N + 1) * 4);
  int* cursor = (int*)alloc((size_t)(N + 1) * 4);
  int* csr    = (int*)alloc((size_t)(E + N) * 4);
  int* flag   = (int*)alloc(256);
  short* Bt[4];
  for (int l = 0; l < 4; ++l) Bt[l] = (short*)alloc((size_t)dout[l] * din[l] * 2);

  detect_int64_kernel<<<1, 256, 0, stream>>>((const unsigned int*)ew, E, flag);
  hipMemsetAsync(deg, 0, (size_t)(N + 1) * 4, stream);
  count_deg_kernel<<<(E + 255) / 256, 256, 0, stream>>>(ew, E, deg, flag);
  scan_kernel<<<1, 1024, 0, stream>>>(deg, rowptr, cursor, N);
  fill_kernel<<<(E + N + 255) / 256, 256, 0, stream>>>(ew, E, N, cursor, csr, flag);

  {
    dim3 cg(32, 32, 4);
    convert_w_all_kernel<<<cg, 256, 0, stream>>>(W[0], W[1], W[2], W[3],
                                                 Bt[0], Bt[1], Bt[2], Bt[3]);
  }
  {
    dim3 wg(256, 3);
    wvec_all_kernel<<<wg, 256, 0, stream>>>(W[0], Asv[0], Adv[0],
                                            W[2], Asv[2], Adv[2],
                                            W[3], Asv[3], Adv[3], wvS, wvD);
  }

  int ngrp = (N + 3) / 4;
  int mgrp = (N + 63) / 64;
  // layer 1: GEMV scores -> input-side aggregation -> split GEMM (bias+relu fused)
  {
    score_gemv_kernel<<<ngrp, 256, 0, stream>>>(x, wvS, wvD, s_src, s_dst, N);
    agg_x_kernel<<<ngrp, 256, 0, stream>>>(x, s_src, s_dst, rowptr, csr, bufP, N);
    dim3 gg(dout[0] / 128, mgrp);
    gemm_mfma_kernel<1, 1, 1, 0><<<gg, 256, 0, stream>>>(
        bufP, Bt[0], bufQ, nullptr, nullptr, Bv[0], nullptr, nullptr, N, dout[0], din[0]);
  }
  // layer 2: GEMM (h2 + fused score partials) -> reduce -> agg (emits layer-3 scores)
  {
    dim3 gg(dout[1] / 128, mgrp);
    gemm_mfma_kernel<1, 0, 0, 1><<<gg, 256, 0, stream>>>(
        bufQ, Bt[1], hB, Asv[1], Adv[1], nullptr, partS, partD, N, dout[1], din[1]);
    score_reduce_kernel<<<(N + 255) / 256, 256, 0, stream>>>(partS, partD, s_src, s_dst,
                                                             N, (dout[1] / 128) * 2);
    agg_wave_kernel<1024, 1, 1, 0, 1><<<ngrp, 256, 0, stream>>>(
        hB, s_src, s_dst, rowptr, csr, Bv[1], nullptr, bufR,
        wvS + 256, wvD + 256, s_src2, s_dst2, N);
  }
  // layer 3: pure GEMM -> agg (emits layer-4 scores)
  {
    dim3 gg(dout[2] / 128, mgrp);
    gemm_mfma_kernel<1, 0, 0, 0><<<gg, 256, 0, stream>>>(
        bufR, Bt[2], hB, nullptr, nullptr, nullptr, nullptr, nullptr, N, dout[2], din[2]);
    agg_wave_kernel<512, 1, 1, 0, 1><<<ngrp, 256, 0, stream>>>(
        hB, s_src2, s_dst2, rowptr, csr, Bv[2], nullptr, bufQ,
        wvS + 1280, wvD + 1280, s_src, s_dst, N);
  }
  // layer 4: pure GEMM (fp32 h) -> agg + fused log_softmax
  {
    dim3 gg(dout[3] / 128, mgrp);
    gemm_mfma_kernel<0, 0, 0, 0><<<gg, 256, 0, stream>>>(
        bufQ, Bt[3], hF, nullptr, nullptr, nullptr, nullptr, nullptr, N, dout[3], din[3]);
    agg_wave_kernel<128, 0, 0, 1, 0><<<ngrp, 256, 0, stream>>>(
        hF, s_src, s_dst, rowptr, csr, Bv[3], (float*)d_out, nullptr,
        nullptr, nullptr, nullptr, nullptr, N);
  }
}

// Round 14
// 262.575 us; speedup vs baseline: 1.6703x; 1.0333x over previous
//
#include <hip/hip_runtime.h>
#include <math.h>

#define NEG_SLOPE 0.2f
#define EPS_F 1e-16f
typedef long long ll;

typedef __attribute__((ext_vector_type(4))) float f32x4;
typedef __attribute__((ext_vector_type(8))) short bf16x8;

// ---------------- bf16 helpers (bit-level, RTN-even) ----------------
__device__ __forceinline__ unsigned short bf16_of(float f) {
  unsigned u = __float_as_uint(f);
  u += 0x7fffu + ((u >> 16) & 1u);
  return (unsigned short)(u >> 16);
}
__device__ __forceinline__ float bf16_back(unsigned short s) {
  return __uint_as_float((unsigned)s << 16);
}

__device__ __forceinline__ void gload16(const void* g, void* l) {
  __builtin_amdgcn_global_load_lds((const __attribute__((address_space(1))) void*)g,
                                   (__attribute__((address_space(3))) void*)l, 16, 0, 0);
}

// ---------------- edge dtype detection (int64 vs int32) ----------------
__global__ void detect_int64_kernel(const unsigned int* __restrict__ w, int E,
                                    int* __restrict__ flag) {
  __shared__ int nz;
  if (threadIdx.x == 0) nz = 0;
  __syncthreads();
  int cnt = E < 2048 ? E : 2048;
  int local = 0;
  for (int i = threadIdx.x; i < cnt; i += blockDim.x)
    if (w[2 * i + 1] != 0u) local++;
  if (local) atomicAdd(&nz, local);
  __syncthreads();
  if (threadIdx.x == 0) *flag = (nz == 0) ? 1 : 0;  // 1 => int64 layout
}

__device__ __forceinline__ void edge_at(const int* __restrict__ ew, int E, int e,
                                        int is64, int& s, int& d) {
  if (is64) { s = ew[2 * e]; d = ew[2 * E + 2 * e]; }
  else      { s = ew[e];     d = ew[E + e]; }
}

// ---------------- CSR build (deg = edge-count; +1 self-loop folded in scan) ----
__global__ void count_deg_kernel(const int* __restrict__ ew, int E, int* deg,
                                 const int* __restrict__ flag) {
  int is64 = *flag;
  int e = blockIdx.x * blockDim.x + threadIdx.x;
  if (e < E) {
    int s, d;
    edge_at(ew, E, e, is64, s, d);
    atomicAdd(&deg[d], 1);
  }
}

__global__ void scan_kernel(const int* __restrict__ deg, int* rowptr, int* cursor, int N) {
  __shared__ int sums[1024];
  int tid = threadIdx.x;
  int chunk = (N + 1023) >> 10;
  int start = tid * chunk;
  int end = start + chunk; if (end > N) end = N;
  int s = 0;
  for (int i = start; i < end; ++i) s += deg[i] + 1;  // +1 = self loop
  sums[tid] = s;
  __syncthreads();
  for (int off = 1; off < 1024; off <<= 1) {
    int v = (tid >= off) ? sums[tid - off] : 0;
    __syncthreads();
    sums[tid] += v;
    __syncthreads();
  }
  int run = (tid == 0) ? 0 : sums[tid - 1];
  for (int i = start; i < end; ++i) {
    rowptr[i] = run; cursor[i] = run;
    run += deg[i] + 1;
  }
  if (tid == 1023) rowptr[N] = sums[1023];
}

__global__ void fill_kernel(const int* __restrict__ ew, int E, int N, int* cursor,
                            int* csr, const int* __restrict__ flag) {
  int is64 = *flag;
  int i = blockIdx.x * blockDim.x + threadIdx.x;
  if (i < E) {
    int s, d;
    edge_at(ew, E, i, is64, s, d);
    int pos = atomicAdd(&cursor[d], 1);
    csr[pos] = s;
  } else if (i < E + N) {
    int n = i - E;
    int pos = atomicAdd(&cursor[n], 1);
    csr[pos] = n;
  }
}

// ---------------- weight conversions ----------------
__global__ __launch_bounds__(256) void convert_w_all_kernel(
    const float* __restrict__ W0, const float* __restrict__ W1,
    const float* __restrict__ W2, const float* __restrict__ W3,
    short* __restrict__ B0, short* __restrict__ B1,
    short* __restrict__ B2, short* __restrict__ B3) {
  const int Ks[4]  = {256, 1024, 1024, 512};
  const int Ncs[4] = {1024, 1024, 512, 128};
  int z = blockIdx.z;
  int K = Ks[z], Nc = Ncs[z];
  int k0 = blockIdx.x * 32, n0 = blockIdx.y * 32;
  if (k0 >= K || n0 >= Nc) return;
  const float* W = z == 0 ? W0 : (z == 1 ? W1 : (z == 2 ? W2 : W3));
  short* Bt = z == 0 ? B0 : (z == 1 ? B1 : (z == 2 ? B2 : B3));
  __shared__ float t[32][33];
  int r = threadIdx.x >> 3;          // 0..31
  int c4 = (threadIdx.x & 7) * 4;    // 0..28
  float4 v = *(const float4*)&W[(ll)(k0 + r) * Nc + n0 + c4];
  t[r][c4] = v.x; t[r][c4 + 1] = v.y; t[r][c4 + 2] = v.z; t[r][c4 + 3] = v.w;
  __syncthreads();
  float f0 = t[c4 + 0][r], f1 = t[c4 + 1][r], f2 = t[c4 + 2][r], f3 = t[c4 + 3][r];
  short4 hp = make_short4((short)bf16_of(f0), (short)bf16_of(f1),
                          (short)bf16_of(f2), (short)bf16_of(f3));
  *(short4*)&Bt[(ll)(n0 + r) * K + k0 + c4] = hp;
}

// wvec for layers 0,2,3: wv[k] = sum_j W[k][j]*a[j]; offsets {0,256,1280}
__global__ void wvec_all_kernel(
    const float* __restrict__ W0, const float* __restrict__ as0, const float* __restrict__ ad0,
    const float* __restrict__ W2, const float* __restrict__ as2, const float* __restrict__ ad2,
    const float* __restrict__ W3, const float* __restrict__ as3, const float* __restrict__ ad3,
    float* __restrict__ wvS, float* __restrict__ wvD) {
  const int Ks[3]   = {256, 1024, 512};
  const int Ncs[3]  = {1024, 512, 128};
  const int offs[3] = {0, 256, 1280};
  int zi = blockIdx.y;
  int K = Ks[zi], Nc = Ncs[zi];
  int wid = threadIdx.x >> 6, lane = threadIdx.x & 63;
  int k = blockIdx.x * 4 + wid;
  if (k >= K) return;
  const float* W  = zi == 0 ? W0 : (zi == 1 ? W2 : W3);
  const float* as = zi == 0 ? as0 : (zi == 1 ? as2 : as3);
  const float* ad = zi == 0 ? ad0 : (zi == 1 ? ad2 : ad3);
  const float* row = W + (ll)k * Nc;
  float a = 0.f, b = 0.f;
  for (int j = lane; j < Nc; j += 64) {
    float w = row[j];
    a += w * as[j];
    b += w * ad[j];
  }
#pragma unroll
  for (int o = 32; o > 0; o >>= 1) {
    a += __shfl_xor(a, o, 64);
    b += __shfl_xor(b, o, 64);
  }
  if (lane == 0) { wvS[offs[zi] + k] = a; wvD[offs[zi] + k] = b; }
}

// layer-1 scores by GEMV (din=256)
__global__ void score_gemv_kernel(const float* __restrict__ x, const float* __restrict__ ws,
                                  const float* __restrict__ wd, float* __restrict__ s_src,
                                  float* __restrict__ s_dst, int N) {
  int wid = threadIdx.x >> 6, lane = threadIdx.x & 63;
  int n = blockIdx.x * 4 + wid;
  if (n >= N) return;
  float4 xv = *(const float4*)&x[(ll)n * 256 + lane * 4];
  float4 wsv = *(const float4*)&ws[lane * 4];
  float4 wdv = *(const float4*)&wd[lane * 4];
  float a = xv.x * wsv.x + xv.y * wsv.y + xv.z * wsv.z + xv.w * wsv.w;
  float b = xv.x * wdv.x + xv.y * wdv.y + xv.z * wdv.z + xv.w * wdv.w;
#pragma unroll
  for (int o = 32; o > 0; o >>= 1) {
    a += __shfl_xor(a, o, 64);
    b += __shfl_xor(b, o, 64);
  }
  if (lane == 0) { s_src[n] = a; s_dst[n] = b; }
}

// ---------------- layer-1 input-side aggregation -----------------
__global__ __launch_bounds__(256) void agg_x_kernel(
    const float* __restrict__ x, const float* __restrict__ ssrc,
    const float* __restrict__ sdst, const int* __restrict__ rowptr,
    const int* __restrict__ csr, short* __restrict__ outH, int N) {
  int wid = threadIdx.x >> 6, lane = threadIdx.x & 63;
  int node = blockIdx.x * 4 + wid;
  if (node >= N) return;
  int rs = rowptr[node];
  int nd = rowptr[node + 1] - rs;
  float sd = sdst[node];
  int d0 = lane * 4;

  float a0 = 0.f, a1 = 0.f, a2 = 0.f, a3 = 0.f;
  auto accum = [&](int s, float w) {
    float4 xv = *(const float4*)&x[(ll)s * 256 + d0];
    a0 += w * xv.x; a1 += w * xv.y; a2 += w * xv.z; a3 += w * xv.w;
  };

  if (nd <= 64) {
    int srcl = 0;
    float e = -1e30f;
    if (lane < nd) {
      srcl = csr[rs + lane];
      float t = ssrc[srcl] + sd;
      e = t > 0.f ? t : NEG_SLOPE * t;
    }
    float m = e;
#pragma unroll
    for (int o = 32; o > 0; o >>= 1) m = fmaxf(m, __shfl_xor(m, o, 64));
    float ex = (lane < nd) ? __expf(e - m) : 0.f;
    float den = ex;
#pragma unroll
    for (int o = 32; o > 0; o >>= 1) den += __shfl_xor(den, o, 64);
    float al = ex / (den + EPS_F);
    int i = 0;
    for (; i + 4 <= nd; i += 4) {
      int s0 = __shfl(srcl, i, 64), s1 = __shfl(srcl, i + 1, 64);
      int s2 = __shfl(srcl, i + 2, 64), s3 = __shfl(srcl, i + 3, 64);
      float w0 = __shfl(al, i, 64), w1 = __shfl(al, i + 1, 64);
      float w2 = __shfl(al, i + 2, 64), w3 = __shfl(al, i + 3, 64);
      accum(s0, w0); accum(s1, w1); accum(s2, w2); accum(s3, w3);
    }
    for (; i < nd; ++i) accum(__shfl(srcl, i, 64), __shfl(al, i, 64));
  } else {
    float m = -1e30f;
    for (int i = lane; i < nd; i += 64) {
      float t = ssrc[csr[rs + i]] + sd;
      t = t > 0.f ? t : NEG_SLOPE * t;
      m = fmaxf(m, t);
    }
#pragma unroll
    for (int o = 32; o > 0; o >>= 1) m = fmaxf(m, __shfl_xor(m, o, 64));
    float den = 0.f;
    for (int i = lane; i < nd; i += 64) {
      float t = ssrc[csr[rs + i]] + sd;
      t = t > 0.f ? t : NEG_SLOPE * t;
      den += __expf(t - m);
    }
#pragma unroll
    for (int o = 32; o > 0; o >>= 1) den += __shfl_xor(den, o, 64);
    float inv = 1.f / (den + EPS_F);
    for (int i = 0; i < nd; ++i) {
      int s = csr[rs + i];
      float t = ssrc[s] + sd;
      t = t > 0.f ? t : NEG_SLOPE * t;
      accum(s, __expf(t - m) * inv);
    }
  }

  unsigned short h0 = bf16_of(a0), h1 = bf16_of(a1), h2 = bf16_of(a2), h3 = bf16_of(a3);
  short4 hp = make_short4((short)h0, (short)h1, (short)h2, (short)h3);
  short4 lp = make_short4((short)bf16_of(a0 - bf16_back(h0)),
                          (short)bf16_of(a1 - bf16_back(h1)),
                          (short)bf16_of(a2 - bf16_back(h2)),
                          (short)bf16_of(a3 - bf16_back(h3)));
  ll base = (ll)node * 512 + d0;
  *(short4*)&outH[base] = hp;
  *(short4*)&outH[base + 256] = lp;
}

// ---------------- MFMA GEMM (64x128 tile) + optional fused epilogues --------
template <int HBF16, int SPLIT, int BIASRELU, int SCORES>
__global__ __launch_bounds__(256) void gemm_mfma_kernel(
    const short* __restrict__ A, const short* __restrict__ Bt,
    void* __restrict__ Cv, const float* __restrict__ a_src,
    const float* __restrict__ a_dst, const float* __restrict__ bias,
    float* __restrict__ partS, float* __restrict__ partD, int M, int Nc, int K) {
  __shared__ char Ah[SPLIT ? 8192 : 4096];
  __shared__ char Bs[8192];
  char* Al = Ah + 4096;  // valid only when SPLIT
  int tid = threadIdx.x;

  int nwg = gridDim.x * gridDim.y;
  int hb = blockIdx.y * gridDim.x + blockIdx.x;
  int xcd = hb & 7, q = nwg >> 3, r = nwg & 7;
  int lg = (xcd < r ? xcd * (q + 1) : r * (q + 1) + (xcd - r) * q) + (hb >> 3);
  int bx = lg % gridDim.x, by = lg / gridDim.x;
  int bm = by * 64, bn = bx * 128;

  int lane = tid & 63, wid = tid >> 6;
  int wr = wid >> 1, wc = wid & 1;
  int AS = SPLIT ? 2 * K : K;  // A row stride

  f32x4 acc[2][4];
#pragma unroll
  for (int m = 0; m < 2; ++m)
#pragma unroll
    for (int n = 0; n < 4; ++n) acc[m][n] = (f32x4){0.f, 0.f, 0.f, 0.f};

  int srow = tid >> 2;                 // 0..63
  int cphys = tid & 3;                 // LDS chunk slot this thread fills
  int swz = (srow >> 1) & 3;
  int clog = (cphys ^ swz) * 8;        // bf16 k-offset actually fetched
  int ra = bm + srow; if (ra > M - 1) ra = M - 1;
  const short* aP0 = A + (ll)ra * AS + clog;
  const short* bP0 = Bt + (ll)(bn + srow) * K + clog;
  const short* bP1 = Bt + (ll)(bn + srow + 64) * K + clog;
  int dstOff = tid * 16;

  int lrow = lane & 15;
  int lchunk = ((lane >> 4) ^ ((lrow >> 1) & 3)) * 16;
  int fOffA = (wr * 32 + lrow) * 64 + lchunk;
  int fOffB = (wc * 64 + lrow) * 64 + lchunk;

  for (int kt = 0; kt < K; kt += 32) {
    gload16(aP0 + kt, Ah + dstOff);
    if constexpr (SPLIT) gload16(aP0 + K + kt, Al + dstOff);
    gload16(bP0 + kt, Bs + dstOff);
    gload16(bP1 + kt, Bs + 4096 + dstOff);
    __syncthreads();
    bf16x8 ah[2], al[2], bfr[4];
#pragma unroll
    for (int m = 0; m < 2; ++m) {
      ah[m] = *(const bf16x8*)(Ah + fOffA + m * 1024);
      if constexpr (SPLIT) al[m] = *(const bf16x8*)(Al + fOffA + m * 1024);
    }
#pragma unroll
    for (int n = 0; n < 4; ++n) bfr[n] = *(const bf16x8*)(Bs + fOffB + n * 1024);
#pragma unroll
    for (int m = 0; m < 2; ++m)
#pragma unroll
      for (int n = 0; n < 4; ++n) {
        acc[m][n] = __builtin_amdgcn_mfma_f32_16x16x32_bf16(ah[m], bfr[n], acc[m][n], 0, 0, 0);
        if constexpr (SPLIT)
          acc[m][n] = __builtin_amdgcn_mfma_f32_16x16x32_bf16(al[m], bfr[n], acc[m][n], 0, 0, 0);
      }
    __syncthreads();
  }

  int crow0 = bm + wr * 32 + (lane >> 4) * 4;
  int ccol0 = bn + wc * 64 + (lane & 15);
  float bv4[4];
  if constexpr (BIASRELU) {
#pragma unroll
    for (int n = 0; n < 4; ++n) bv4[n] = bias[ccol0 + n * 16];
  }
#pragma unroll
  for (int m = 0; m < 2; ++m) {
#pragma unroll
    for (int j = 0; j < 4; ++j) {
      int row = crow0 + m * 16 + j;
      if (row < M) {
#pragma unroll
        for (int n = 0; n < 4; ++n) {
          float v = acc[m][n][j];
          if constexpr (BIASRELU) v = fmaxf(v + bv4[n], 0.f);
          if (HBF16) ((unsigned short*)Cv)[(ll)row * Nc + ccol0 + n * 16] = bf16_of(v);
          else       ((float*)Cv)[(ll)row * Nc + ccol0 + n * 16] = v;
        }
      }
    }
  }

  if constexpr (SCORES) {
    float as4[4], ad4[4];
#pragma unroll
    for (int n = 0; n < 4; ++n) {
      as4[n] = a_src[ccol0 + n * 16];
      ad4[n] = a_dst[ccol0 + n * 16];
    }
    int p = bx * 2 + wc;
#pragma unroll
    for (int m = 0; m < 2; ++m) {
#pragma unroll
      for (int j = 0; j < 4; ++j) {
        float ps = acc[m][0][j] * as4[0] + acc[m][1][j] * as4[1] +
                   acc[m][2][j] * as4[2] + acc[m][3][j] * as4[3];
        float pd = acc[m][0][j] * ad4[0] + acc[m][1][j] * ad4[1] +
                   acc[m][2][j] * ad4[2] + acc[m][3][j] * ad4[3];
#pragma unroll
        for (int o = 1; o < 16; o <<= 1) {
          ps += __shfl_xor(ps, o, 64);
          pd += __shfl_xor(pd, o, 64);
        }
        int row = crow0 + m * 16 + j;
        if ((lane & 15) == 0 && row < M) {
          partS[(ll)p * M + row] = ps;
          partD[(ll)p * M + row] = pd;
        }
      }
    }
  }
}

// sum the per-(col-block,wc) partials -> s_src/s_dst
__global__ void score_reduce_kernel(const float* __restrict__ partS,
                                    const float* __restrict__ partD,
                                    float* __restrict__ s_src, float* __restrict__ s_dst,
                                    int N, int NP) {
  int i = blockIdx.x * blockDim.x + threadIdx.x;
  if (i >= N) return;
  float a = 0.f, b = 0.f;
  for (int p = 0; p < NP; ++p) {
    a += partS[(ll)p * N + i];
    b += partD[(ll)p * N + i];
  }
  s_src[i] = a;
  s_dst[i] = b;
}

// ---------------- wave-per-node fused softmax + weighted aggregation --------
// SCORENEXT: compute next layer's scores from the fp32 output row in regs
// (s = out . wvec_next), write to oSs/oSd (ping-pong buffers vs ssrc/sdst).
template <int DOUT, int HIN_BF16, int OUTB16, int LOGSM, int SCORENEXT>
__global__ __launch_bounds__(256) void agg_wave_kernel(
    const void* __restrict__ hv, const float* __restrict__ ssrc,
    const float* __restrict__ sdst, const int* __restrict__ rowptr,
    const int* __restrict__ csr, const float* __restrict__ bias,
    float* __restrict__ outF, short* __restrict__ outH,
    const float* __restrict__ wvnS, const float* __restrict__ wvnD,
    float* __restrict__ oSs, float* __restrict__ oSd, int N) {
  constexpr int NH = (DOUT >= 512) ? DOUT / 512 : 1;   // row halves of 512 dims
  constexpr int DPL = (DOUT >= 512) ? 8 : DOUT / 64;   // dims/lane per half
  int wid = threadIdx.x >> 6, lane = threadIdx.x & 63;
  int node = blockIdx.x * 4 + wid;
  if (node >= N) return;
  int rs = rowptr[node];
  int nd = rowptr[node + 1] - rs;
  float sd = sdst[node];
  int d0 = lane * DPL;

  float acc[NH][DPL];
#pragma unroll
  for (int hh = 0; hh < NH; ++hh)
#pragma unroll
    for (int k = 0; k < DPL; ++k) acc[hh][k] = 0.f;

  auto accum = [&](int s, float w) {
    if constexpr (HIN_BF16) {
      const unsigned short* hp = (const unsigned short*)hv + (ll)s * DOUT + d0;
#pragma unroll
      for (int hh = 0; hh < NH; ++hh) {
        bf16x8 qv = *(const bf16x8*)(hp + hh * 512);
#pragma unroll
        for (int k = 0; k < 8; ++k)
          acc[hh][k] += w * bf16_back((unsigned short)qv[k]);
      }
    } else {
      const float* hp = (const float*)hv + (ll)s * DOUT + d0;
#pragma unroll
      for (int k = 0; k < DPL; ++k) acc[0][k] += w * hp[k];
    }
  };

  if (nd <= 64) {
    int srcl = 0;
    float e = -1e30f;
    if (lane < nd) {
      srcl = csr[rs + lane];
      float t = ssrc[srcl] + sd;
      e = t > 0.f ? t : NEG_SLOPE * t;
    }
    float m = e;
#pragma unroll
    for (int o = 32; o > 0; o >>= 1) m = fmaxf(m, __shfl_xor(m, o, 64));
    float ex = (lane < nd) ? __expf(e - m) : 0.f;
    float den = ex;
#pragma unroll
    for (int o = 32; o > 0; o >>= 1) den += __shfl_xor(den, o, 64);
    float al = ex / (den + EPS_F);

    int i = 0;
    for (; i + 4 <= nd; i += 4) {
      int s0 = __shfl(srcl, i, 64), s1 = __shfl(srcl, i + 1, 64);
      int s2 = __shfl(srcl, i + 2, 64), s3 = __shfl(srcl, i + 3, 64);
      float w0 = __shfl(al, i, 64), w1 = __shfl(al, i + 1, 64);
      float w2 = __shfl(al, i + 2, 64), w3 = __shfl(al, i + 3, 64);
      accum(s0, w0); accum(s1, w1); accum(s2, w2); accum(s3, w3);
    }
    for (; i < nd; ++i) accum(__shfl(srcl, i, 64), __shfl(al, i, 64));
  } else {
    float m = -1e30f;
    for (int i = lane; i < nd; i += 64) {
      float t = ssrc[csr[rs + i]] + sd;
      t = t > 0.f ? t : NEG_SLOPE * t;
      m = fmaxf(m, t);
    }
#pragma unroll
    for (int o = 32; o > 0; o >>= 1) m = fmaxf(m, __shfl_xor(m, o, 64));
    float den = 0.f;
    for (int i = lane; i < nd; i += 64) {
      float t = ssrc[csr[rs + i]] + sd;
      t = t > 0.f ? t : NEG_SLOPE * t;
      den += __expf(t - m);
    }
#pragma unroll
    for (int o = 32; o > 0; o >>= 1) den += __shfl_xor(den, o, 64);
    float inv = 1.f / (den + EPS_F);
    for (int i = 0; i < nd; ++i) {
      int s = csr[rs + i];  // wave-uniform broadcast load
      float t = ssrc[s] + sd;
      t = t > 0.f ? t : NEG_SLOPE * t;
      accum(s, __expf(t - m) * inv);
    }
  }

  if constexpr (OUTB16) {
    float ps = 0.f, pd = 0.f;
#pragma unroll
    for (int hh = 0; hh < NH; ++hh) {
      int d = hh * 512 + d0;
      bf16x8 hp8;
#pragma unroll
      for (int k = 0; k < 8; ++k) {
        float v = fmaxf(acc[hh][k] + bias[d + k], 0.f);
        hp8[k] = (short)bf16_of(v);
        if constexpr (SCORENEXT) {
          ps += v * wvnS[d + k];
          pd += v * wvnD[d + k];
        }
      }
      *(bf16x8*)&outH[(ll)node * DOUT + d] = hp8;
    }
    if constexpr (SCORENEXT) {
#pragma unroll
      for (int o = 32; o > 0; o >>= 1) {
        ps += __shfl_xor(ps, o, 64);
        pd += __shfl_xor(pd, o, 64);
      }
      if (lane == 0) { oSs[node] = ps; oSd[node] = pd; }
    }
  } else if constexpr (LOGSM) {
    float v0 = acc[0][0] + bias[d0 + 0];
    float v1 = acc[0][1] + bias[d0 + 1];
    float mx = fmaxf(v0, v1);
#pragma unroll
    for (int o = 32; o > 0; o >>= 1) mx = fmaxf(mx, __shfl_xor(mx, o, 64));
    float s = __expf(v0 - mx) + __expf(v1 - mx);
#pragma unroll
    for (int o = 32; o > 0; o >>= 1) s += __shfl_xor(s, o, 64);
    float ls = logf(s);
    outF[(ll)node * DOUT + d0 + 0] = v0 - mx - ls;
    outF[(ll)node * DOUT + d0 + 1] = v1 - mx - ls;
  } else {
#pragma unroll
    for (int k = 0; k < DPL; ++k)
      outF[(ll)node * DOUT + d0 + k] = acc[0][k] + bias[d0 + k];
  }
}

// ---------------- launch ----------------
extern "C" void kernel_launch(void* const* d_in, const int* in_sizes, int n_in,
                              void* d_out, int out_size, void* d_ws, size_t ws_size,
                              hipStream_t stream) {
  const float* x = (const float*)d_in[0];
  const int* ew = (const int*)d_in[1];
  int N = in_sizes[0] / 256;
  int E = in_sizes[1] / 2;

  const float* W[4]   = {(const float*)d_in[2],  (const float*)d_in[6],
                         (const float*)d_in[10], (const float*)d_in[14]};
  const float* Asv[4] = {(const float*)d_in[3],  (const float*)d_in[7],
                         (const float*)d_in[11], (const float*)d_in[15]};
  const float* Adv[4] = {(const float*)d_in[4],  (const float*)d_in[8],
                         (const float*)d_in[12], (const float*)d_in[16]};
  const float* Bv[4]  = {(const float*)d_in[5],  (const float*)d_in[9],
                         (const float*)d_in[13], (const float*)d_in[17]};
  const int din[4]  = {256, 1024, 1024, 512};
  const int dout[4] = {1024, 1024, 512, 128};

  char* ws = (char*)d_ws;
  size_t off = 0;
  auto alloc = [&](size_t bytes) {
    void* p = ws + off;
    off += (bytes + 255) & ~(size_t)255;
    return p;
  };
  unsigned short* hB = (unsigned short*)alloc((size_t)N * 1024 * 2);  // bf16 h (layers 2-3)
  float* hF   = (float*)alloc((size_t)N * 128 * 4);                   // fp32 h (layer 4)
  short* bufP = (short*)alloc((size_t)N * 512 * 2);   // xagg split [hi|lo]
  short* bufQ = (short*)alloc((size_t)N * 1024 * 2);  // inter-layer bf16 act
  short* bufR = (short*)alloc((size_t)N * 1024 * 2);
  float* s_src  = (float*)alloc((size_t)N * 4);
  float* s_dst  = (float*)alloc((size_t)N * 4);
  float* s_src2 = (float*)alloc((size_t)N * 4);
  float* s_dst2 = (float*)alloc((size_t)N * 4);
  float* partS = (float*)alloc((size_t)16 * N * 4);
  float* partD = (float*)alloc((size_t)16 * N * 4);
  float* wvS  = (float*)alloc((size_t)2048 * 4);  // l0@0, l2@256, l3@1280
  float* wvD  = (float*)alloc((size_t)2048 * 4);
  int* deg    = (int*)alloc((size_t)(N + 1) * 4);
  int* rowptr = (int*)alloc((size_t)(N + 1) * 4);
  int* cursor = (int*)alloc((size_t)(N + 1) * 4);
  int* csr    = (int*)alloc((size_t)(E + N) * 4);
  int* flag   = (int*)alloc(256);
  short* Bt[4];
  for (int l = 0; l < 4; ++l) Bt[l] = (short*)alloc((size_t)dout[l] * din[l] * 2);

  detect_int64_kernel<<<1, 256, 0, stream>>>((const unsigned int*)ew, E, flag);
  hipMemsetAsync(deg, 0, (size_t)(N + 1) * 4, stream);
  count_deg_kernel<<<(E + 255) / 256, 256, 0, stream>>>(ew, E, deg, flag);
  scan_kernel<<<1, 1024, 0, stream>>>(deg, rowptr, cursor, N);
  fill_kernel<<<(E + N + 255) / 256, 256, 0, stream>>>(ew, E, N, cursor, csr, flag);

  {
    dim3 cg(32, 32, 4);
    convert_w_all_kernel<<<cg, 256, 0, stream>>>(W[0], W[1], W[2], W[3],
                                                 Bt[0], Bt[1], Bt[2], Bt[3]);
  }
  {
    dim3 wg(256, 3);
    wvec_all_kernel<<<wg, 256, 0, stream>>>(W[0], Asv[0], Adv[0],
                                            W[2], Asv[2], Adv[2],
                                            W[3], Asv[3], Adv[3], wvS, wvD);
  }

  int ngrp = (N + 3) / 4;
  int mgrp = (N + 63) / 64;
  // layer 1: GEMV scores -> input-side aggregation -> split GEMM (bias+relu fused)
  {
    score_gemv_kernel<<<ngrp, 256, 0, stream>>>(x, wvS, wvD, s_src, s_dst, N);
    agg_x_kernel<<<ngrp, 256, 0, stream>>>(x, s_src, s_dst, rowptr, csr, bufP, N);
    dim3 gg(dout[0] / 128, mgrp);
    gemm_mfma_kernel<1, 1, 1, 0><<<gg, 256, 0, stream>>>(
        bufP, Bt[0], bufQ, nullptr, nullptr, Bv[0], nullptr, nullptr, N, dout[0], din[0]);
  }
  // layer 2: GEMM (h2 + fused score partials) -> reduce -> agg (emits layer-3 scores)
  {
    dim3 gg(dout[1] / 128, mgrp);
    gemm_mfma_kernel<1, 0, 0, 1><<<gg, 256, 0, stream>>>(
        bufQ, Bt[1], hB, Asv[1], Adv[1], nullptr, partS, partD, N, dout[1], din[1]);
    score_reduce_kernel<<<(N + 255) / 256, 256, 0, stream>>>(partS, partD, s_src, s_dst,
                                                             N, (dout[1] / 128) * 2);
    agg_wave_kernel<1024, 1, 1, 0, 1><<<ngrp, 256, 0, stream>>>(
        hB, s_src, s_dst, rowptr, csr, Bv[1], nullptr, bufR,
        wvS + 256, wvD + 256, s_src2, s_dst2, N);
  }
  // layer 3: pure GEMM -> agg (emits layer-4 scores)
  {
    dim3 gg(dout[2] / 128, mgrp);
    gemm_mfma_kernel<1, 0, 0, 0><<<gg, 256, 0, stream>>>(
        bufR, Bt[2], hB, nullptr, nullptr, nullptr, nullptr, nullptr, N, dout[2], din[2]);
    agg_wave_kernel<512, 1, 1, 0, 1><<<ngrp, 256, 0, stream>>>(
        hB, s_src2, s_dst2, rowptr, csr, Bv[2], nullptr, bufQ,
        wvS + 1280, wvD + 1280, s_src, s_dst, N);
  }
  // layer 4: pure GEMM (fp32 h) -> agg + fused log_softmax
  {
    dim3 gg(dout[3] / 128, mgrp);
    gemm_mfma_kernel<0, 0, 0, 0><<<gg, 256, 0, stream>>>(
        bufQ, Bt[3], hF, nullptr, nullptr, nullptr, nullptr, nullptr, N, dout[3], din[3]);
    agg_wave_kernel<128, 0, 0, 1, 0><<<ngrp, 256, 0, stream>>>(
        hF, s_src, s_dst, rowptr, csr, Bv[3], (float*)d_out, nullptr,
        nullptr, nullptr, nullptr, nullptr, N);
  }
}

// Round 15
// 259.388 us; speedup vs baseline: 1.6909x; 1.0123x over previous
//
#include <hip/hip_runtime.h>
#include <math.h>

#define NEG_SLOPE 0.2f
#define EPS_F 1e-16f
typedef long long ll;

typedef __attribute__((ext_vector_type(4))) float f32x4;
typedef __attribute__((ext_vector_type(8))) short bf16x8;

// ---------------- bf16 helpers (bit-level, RTN-even) ----------------
__device__ __forceinline__ unsigned short bf16_of(float f) {
  unsigned u = __float_as_uint(f);
  u += 0x7fffu + ((u >> 16) & 1u);
  return (unsigned short)(u >> 16);
}
__device__ __forceinline__ float bf16_back(unsigned short s) {
  return __uint_as_float((unsigned)s << 16);
}

__device__ __forceinline__ void gload16(const void* g, void* l) {
  __builtin_amdgcn_global_load_lds((const __attribute__((address_space(1))) void*)g,
                                   (__attribute__((address_space(3))) void*)l, 16, 0, 0);
}

// ---------------- edge dtype detection (int64 vs int32) ----------------
__global__ void detect_int64_kernel(const unsigned int* __restrict__ w, int E,
                                    int* __restrict__ flag) {
  __shared__ int nz;
  if (threadIdx.x == 0) nz = 0;
  __syncthreads();
  int cnt = E < 2048 ? E : 2048;
  int local = 0;
  for (int i = threadIdx.x; i < cnt; i += blockDim.x)
    if (w[2 * i + 1] != 0u) local++;
  if (local) atomicAdd(&nz, local);
  __syncthreads();
  if (threadIdx.x == 0) *flag = (nz == 0) ? 1 : 0;  // 1 => int64 layout
}

__device__ __forceinline__ void edge_at(const int* __restrict__ ew, int E, int e,
                                        int is64, int& s, int& d) {
  if (is64) { s = ew[2 * e]; d = ew[2 * E + 2 * e]; }
  else      { s = ew[e];     d = ew[E + e]; }
}

// ---------------- CSR build (deg = edge-count; +1 self-loop folded in scan) ----
__global__ void count_deg_kernel(const int* __restrict__ ew, int E, int* deg,
                                 const int* __restrict__ flag) {
  int is64 = *flag;
  int e = blockIdx.x * blockDim.x + threadIdx.x;
  if (e < E) {
    int s, d;
    edge_at(ew, E, e, is64, s, d);
    atomicAdd(&deg[d], 1);
  }
}

__global__ void scan_kernel(const int* __restrict__ deg, int* rowptr, int* cursor, int N) {
  __shared__ int sums[1024];
  int tid = threadIdx.x;
  int chunk = (N + 1023) >> 10;
  int start = tid * chunk;
  int end = start + chunk; if (end > N) end = N;
  int s = 0;
  for (int i = start; i < end; ++i) s += deg[i] + 1;  // +1 = self loop
  sums[tid] = s;
  __syncthreads();
  for (int off = 1; off < 1024; off <<= 1) {
    int v = (tid >= off) ? sums[tid - off] : 0;
    __syncthreads();
    sums[tid] += v;
    __syncthreads();
  }
  int run = (tid == 0) ? 0 : sums[tid - 1];
  for (int i = start; i < end; ++i) {
    rowptr[i] = run; cursor[i] = run;
    run += deg[i] + 1;
  }
  if (tid == 1023) rowptr[N] = sums[1023];
}

__global__ void fill_kernel(const int* __restrict__ ew, int E, int N, int* cursor,
                            int* csr, const int* __restrict__ flag) {
  int is64 = *flag;
  int i = blockIdx.x * blockDim.x + threadIdx.x;
  if (i < E) {
    int s, d;
    edge_at(ew, E, i, is64, s, d);
    int pos = atomicAdd(&cursor[d], 1);
    csr[pos] = s;
  } else if (i < E + N) {
    int n = i - E;
    int pos = atomicAdd(&cursor[n], 1);
    csr[pos] = n;
  }
}

// ---------------- weight conversions ----------------
__global__ __launch_bounds__(256) void convert_w_all_kernel(
    const float* __restrict__ W0, const float* __restrict__ W1,
    const float* __restrict__ W2, const float* __restrict__ W3,
    short* __restrict__ B0, short* __restrict__ B1,
    short* __restrict__ B2, short* __restrict__ B3) {
  const int Ks[4]  = {256, 1024, 1024, 512};
  const int Ncs[4] = {1024, 1024, 512, 128};
  int z = blockIdx.z;
  int K = Ks[z], Nc = Ncs[z];
  int k0 = blockIdx.x * 32, n0 = blockIdx.y * 32;
  if (k0 >= K || n0 >= Nc) return;
  const float* W = z == 0 ? W0 : (z == 1 ? W1 : (z == 2 ? W2 : W3));
  short* Bt = z == 0 ? B0 : (z == 1 ? B1 : (z == 2 ? B2 : B3));
  __shared__ float t[32][33];
  int r = threadIdx.x >> 3;          // 0..31
  int c4 = (threadIdx.x & 7) * 4;    // 0..28
  float4 v = *(const float4*)&W[(ll)(k0 + r) * Nc + n0 + c4];
  t[r][c4] = v.x; t[r][c4 + 1] = v.y; t[r][c4 + 2] = v.z; t[r][c4 + 3] = v.w;
  __syncthreads();
  float f0 = t[c4 + 0][r], f1 = t[c4 + 1][r], f2 = t[c4 + 2][r], f3 = t[c4 + 3][r];
  short4 hp = make_short4((short)bf16_of(f0), (short)bf16_of(f1),
                          (short)bf16_of(f2), (short)bf16_of(f3));
  *(short4*)&Bt[(ll)(n0 + r) * K + k0 + c4] = hp;
}

// wvec for layers 0,2,3: wv[k] = sum_j W[k][j]*a[j]; offsets {0,256,1280}
__global__ void wvec_all_kernel(
    const float* __restrict__ W0, const float* __restrict__ as0, const float* __restrict__ ad0,
    const float* __restrict__ W2, const float* __restrict__ as2, const float* __restrict__ ad2,
    const float* __restrict__ W3, const float* __restrict__ as3, const float* __restrict__ ad3,
    float* __restrict__ wvS, float* __restrict__ wvD) {
  const int Ks[3]   = {256, 1024, 512};
  const int Ncs[3]  = {1024, 512, 128};
  const int offs[3] = {0, 256, 1280};
  int zi = blockIdx.y;
  int K = Ks[zi], Nc = Ncs[zi];
  int wid = threadIdx.x >> 6, lane = threadIdx.x & 63;
  int k = blockIdx.x * 4 + wid;
  if (k >= K) return;
  const float* W  = zi == 0 ? W0 : (zi == 1 ? W2 : W3);
  const float* as = zi == 0 ? as0 : (zi == 1 ? as2 : as3);
  const float* ad = zi == 0 ? ad0 : (zi == 1 ? ad2 : ad3);
  const float* row = W + (ll)k * Nc;
  float a = 0.f, b = 0.f;
  for (int j = lane; j < Nc; j += 64) {
    float w = row[j];
    a += w * as[j];
    b += w * ad[j];
  }
#pragma unroll
  for (int o = 32; o > 0; o >>= 1) {
    a += __shfl_xor(a, o, 64);
    b += __shfl_xor(b, o, 64);
  }
  if (lane == 0) { wvS[offs[zi] + k] = a; wvD[offs[zi] + k] = b; }
}

// layer-1 scores by GEMV (din=256)
__global__ void score_gemv_kernel(const float* __restrict__ x, const float* __restrict__ ws,
                                  const float* __restrict__ wd, float* __restrict__ s_src,
                                  float* __restrict__ s_dst, int N) {
  int wid = threadIdx.x >> 6, lane = threadIdx.x & 63;
  int n = blockIdx.x * 4 + wid;
  if (n >= N) return;
  float4 xv = *(const float4*)&x[(ll)n * 256 + lane * 4];
  float4 wsv = *(const float4*)&ws[lane * 4];
  float4 wdv = *(const float4*)&wd[lane * 4];
  float a = xv.x * wsv.x + xv.y * wsv.y + xv.z * wsv.z + xv.w * wsv.w;
  float b = xv.x * wdv.x + xv.y * wdv.y + xv.z * wdv.z + xv.w * wdv.w;
#pragma unroll
  for (int o = 32; o > 0; o >>= 1) {
    a += __shfl_xor(a, o, 64);
    b += __shfl_xor(b, o, 64);
  }
  if (lane == 0) { s_src[n] = a; s_dst[n] = b; }
}

// ---------------- layer-1 input-side aggregation -----------------
__global__ __launch_bounds__(256) void agg_x_kernel(
    const float* __restrict__ x, const float* __restrict__ ssrc,
    const float* __restrict__ sdst, const int* __restrict__ rowptr,
    const int* __restrict__ csr, short* __restrict__ outH, int N) {
  int wid = threadIdx.x >> 6, lane = threadIdx.x & 63;
  int node = blockIdx.x * 4 + wid;
  if (node >= N) return;
  int rs = rowptr[node];
  int nd = rowptr[node + 1] - rs;
  float sd = sdst[node];
  int d0 = lane * 4;

  float a0 = 0.f, a1 = 0.f, a2 = 0.f, a3 = 0.f;
  auto accum = [&](int s, float w) {
    float4 xv = *(const float4*)&x[(ll)s * 256 + d0];
    a0 += w * xv.x; a1 += w * xv.y; a2 += w * xv.z; a3 += w * xv.w;
  };

  if (nd <= 64) {
    int srcl = 0;
    float e = -1e30f;
    if (lane < nd) {
      srcl = csr[rs + lane];
      float t = ssrc[srcl] + sd;
      e = t > 0.f ? t : NEG_SLOPE * t;
    }
    float m = e;
#pragma unroll
    for (int o = 32; o > 0; o >>= 1) m = fmaxf(m, __shfl_xor(m, o, 64));
    float ex = (lane < nd) ? __expf(e - m) : 0.f;
    float den = ex;
#pragma unroll
    for (int o = 32; o > 0; o >>= 1) den += __shfl_xor(den, o, 64);
    float al = ex / (den + EPS_F);
    int i = 0;
    for (; i + 4 <= nd; i += 4) {
      int s0 = __shfl(srcl, i, 64), s1 = __shfl(srcl, i + 1, 64);
      int s2 = __shfl(srcl, i + 2, 64), s3 = __shfl(srcl, i + 3, 64);
      float w0 = __shfl(al, i, 64), w1 = __shfl(al, i + 1, 64);
      float w2 = __shfl(al, i + 2, 64), w3 = __shfl(al, i + 3, 64);
      accum(s0, w0); accum(s1, w1); accum(s2, w2); accum(s3, w3);
    }
    for (; i < nd; ++i) accum(__shfl(srcl, i, 64), __shfl(al, i, 64));
  } else {
    float m = -1e30f;
    for (int i = lane; i < nd; i += 64) {
      float t = ssrc[csr[rs + i]] + sd;
      t = t > 0.f ? t : NEG_SLOPE * t;
      m = fmaxf(m, t);
    }
#pragma unroll
    for (int o = 32; o > 0; o >>= 1) m = fmaxf(m, __shfl_xor(m, o, 64));
    float den = 0.f;
    for (int i = lane; i < nd; i += 64) {
      float t = ssrc[csr[rs + i]] + sd;
      t = t > 0.f ? t : NEG_SLOPE * t;
      den += __expf(t - m);
    }
#pragma unroll
    for (int o = 32; o > 0; o >>= 1) den += __shfl_xor(den, o, 64);
    float inv = 1.f / (den + EPS_F);
    for (int i = 0; i < nd; ++i) {
      int s = csr[rs + i];
      float t = ssrc[s] + sd;
      t = t > 0.f ? t : NEG_SLOPE * t;
      accum(s, __expf(t - m) * inv);
    }
  }

  unsigned short h0 = bf16_of(a0), h1 = bf16_of(a1), h2 = bf16_of(a2), h3 = bf16_of(a3);
  short4 hp = make_short4((short)h0, (short)h1, (short)h2, (short)h3);
  short4 lp = make_short4((short)bf16_of(a0 - bf16_back(h0)),
                          (short)bf16_of(a1 - bf16_back(h1)),
                          (short)bf16_of(a2 - bf16_back(h2)),
                          (short)bf16_of(a3 - bf16_back(h3)));
  ll base = (ll)node * 512 + d0;
  *(short4*)&outH[base] = hp;
  *(short4*)&outH[base + 256] = lp;
}

// ---------------- MFMA GEMM (64x128 tile, BK=64) + optional fused epilogues --
// BK=64: 8 chunks of 16B per row; chunk XOR-swizzled phys = log ^ (row&7)
// (each 16-lane fragment group hits every bank-quad exactly 2x = free).
// Staging: LDS linear (slot*16), GLOBAL source permuted (gc = p ^ (row&7),
// constant per thread across gloads since row strides by 32). Halved barrier
// count vs BK=32. XCD-chunked bijective block swizzle for L2 locality.
template <int HBF16, int SPLIT, int BIASRELU, int SCORES>
__global__ __launch_bounds__(256) void gemm_mfma_kernel(
    const short* __restrict__ A, const short* __restrict__ Bt,
    void* __restrict__ Cv, const float* __restrict__ a_src,
    const float* __restrict__ a_dst, const float* __restrict__ bias,
    float* __restrict__ partS, float* __restrict__ partD, int M, int Nc, int K) {
  __shared__ char Ah[SPLIT ? 16384 : 8192];  // 64 rows x 128B (+ lo plane)
  __shared__ char Bs[16384];                 // 128 rows x 128B
  char* Al = Ah + 8192;  // valid only when SPLIT
  int tid = threadIdx.x;

  int nwg = gridDim.x * gridDim.y;
  int hb = blockIdx.y * gridDim.x + blockIdx.x;
  int xcd = hb & 7, q = nwg >> 3, r = nwg & 7;
  int lg = (xcd < r ? xcd * (q + 1) : r * (q + 1) + (xcd - r) * q) + (hb >> 3);
  int bx = lg % gridDim.x, by = lg / gridDim.x;
  int bm = by * 64, bn = bx * 128;

  int lane = tid & 63, wid = tid >> 6;
  int wr = wid >> 1, wc = wid & 1;
  int AS = SPLIT ? 2 * K : K;  // A row stride

  f32x4 acc[2][4];
#pragma unroll
  for (int m = 0; m < 2; ++m)
#pragma unroll
    for (int n = 0; n < 4; ++n) acc[m][n] = (f32x4){0.f, 0.f, 0.f, 0.f};

  // staging: slot g*256+tid -> row = 32*g + (tid>>3), phys chunk p = tid&7,
  // global chunk gc = p ^ (row&7) (row&7 invariant across g).
  int srow = tid >> 3;                  // 0..31
  int gc = (tid & 7) ^ (srow & 7);      // global 16B-chunk fetched
  int raA0 = bm + srow;      if (raA0 > M - 1) raA0 = M - 1;
  int raA1 = bm + srow + 32; if (raA1 > M - 1) raA1 = M - 1;
  const short* aSrc0 = A + (ll)raA0 * AS + gc * 8;
  const short* aSrc1 = A + (ll)raA1 * AS + gc * 8;
  const short* bSrc0 = Bt + (ll)(bn + srow) * K + gc * 8;
  const short* bSrc1 = Bt + (ll)(bn + srow + 32) * K + gc * 8;
  const short* bSrc2 = Bt + (ll)(bn + srow + 64) * K + gc * 8;
  const short* bSrc3 = Bt + (ll)(bn + srow + 96) * K + gc * 8;
  int dstOff = tid * 16;

  // fragment read offsets: row_local*128 + (((lane>>4)+kk*4) ^ (lrow&7))*16
  int lrow = lane & 15;
  int swzr = lrow & 7;
  int c0 = lane >> 4;  // 0..3
  int offA[2][2], offB[4][2];
#pragma unroll
  for (int m = 0; m < 2; ++m)
#pragma unroll
    for (int kk = 0; kk < 2; ++kk)
      offA[m][kk] = ((wr * 32 + m * 16 + lrow) * 8 + ((c0 + kk * 4) ^ swzr)) * 16;
#pragma unroll
  for (int n = 0; n < 4; ++n)
#pragma unroll
    for (int kk = 0; kk < 2; ++kk)
      offB[n][kk] = ((wc * 64 + n * 16 + lrow) * 8 + ((c0 + kk * 4) ^ swzr)) * 16;

  for (int kt = 0; kt < K; kt += 64) {
    gload16(aSrc0 + kt, Ah + dstOff);
    gload16(aSrc1 + kt, Ah + 4096 + dstOff);
    if constexpr (SPLIT) {
      gload16(aSrc0 + K + kt, Al + dstOff);
      gload16(aSrc1 + K + kt, Al + 4096 + dstOff);
    }
    gload16(bSrc0 + kt, Bs + dstOff);
    gload16(bSrc1 + kt, Bs + 4096 + dstOff);
    gload16(bSrc2 + kt, Bs + 8192 + dstOff);
    gload16(bSrc3 + kt, Bs + 12288 + dstOff);
    __syncthreads();
    bf16x8 ah[2][2], al[2][2], bfr[4][2];
#pragma unroll
    for (int m = 0; m < 2; ++m)
#pragma unroll
      for (int kk = 0; kk < 2; ++kk) {
        ah[m][kk] = *(const bf16x8*)(Ah + offA[m][kk]);
        if constexpr (SPLIT) al[m][kk] = *(const bf16x8*)(Al + offA[m][kk]);
      }
#pragma unroll
    for (int n = 0; n < 4; ++n)
#pragma unroll
      for (int kk = 0; kk < 2; ++kk)
        bfr[n][kk] = *(const bf16x8*)(Bs + offB[n][kk]);
#pragma unroll
    for (int kk = 0; kk < 2; ++kk)
#pragma unroll
      for (int m = 0; m < 2; ++m)
#pragma unroll
        for (int n = 0; n < 4; ++n) {
          acc[m][n] = __builtin_amdgcn_mfma_f32_16x16x32_bf16(ah[m][kk], bfr[n][kk],
                                                              acc[m][n], 0, 0, 0);
          if constexpr (SPLIT)
            acc[m][n] = __builtin_amdgcn_mfma_f32_16x16x32_bf16(al[m][kk], bfr[n][kk],
                                                                acc[m][n], 0, 0, 0);
        }
    __syncthreads();
  }

  int crow0 = bm + wr * 32 + (lane >> 4) * 4;
  int ccol0 = bn + wc * 64 + (lane & 15);
  float bv4[4];
  if constexpr (BIASRELU) {
#pragma unroll
    for (int n = 0; n < 4; ++n) bv4[n] = bias[ccol0 + n * 16];
  }
#pragma unroll
  for (int m = 0; m < 2; ++m) {
#pragma unroll
    for (int j = 0; j < 4; ++j) {
      int row = crow0 + m * 16 + j;
      if (row < M) {
#pragma unroll
        for (int n = 0; n < 4; ++n) {
          float v = acc[m][n][j];
          if constexpr (BIASRELU) v = fmaxf(v + bv4[n], 0.f);
          if (HBF16) ((unsigned short*)Cv)[(ll)row * Nc + ccol0 + n * 16] = bf16_of(v);
          else       ((float*)Cv)[(ll)row * Nc + ccol0 + n * 16] = v;
        }
      }
    }
  }

  if constexpr (SCORES) {
    float as4[4], ad4[4];
#pragma unroll
    for (int n = 0; n < 4; ++n) {
      as4[n] = a_src[ccol0 + n * 16];
      ad4[n] = a_dst[ccol0 + n * 16];
    }
    int p = bx * 2 + wc;
#pragma unroll
    for (int m = 0; m < 2; ++m) {
#pragma unroll
      for (int j = 0; j < 4; ++j) {
        float ps = acc[m][0][j] * as4[0] + acc[m][1][j] * as4[1] +
                   acc[m][2][j] * as4[2] + acc[m][3][j] * as4[3];
        float pd = acc[m][0][j] * ad4[0] + acc[m][1][j] * ad4[1] +
                   acc[m][2][j] * ad4[2] + acc[m][3][j] * ad4[3];
#pragma unroll
        for (int o = 1; o < 16; o <<= 1) {
          ps += __shfl_xor(ps, o, 64);
          pd += __shfl_xor(pd, o, 64);
        }
        int row = crow0 + m * 16 + j;
        if ((lane & 15) == 0 && row < M) {
          partS[(ll)p * M + row] = ps;
          partD[(ll)p * M + row] = pd;
        }
      }
    }
  }
}

// sum the per-(col-block,wc) partials -> s_src/s_dst
__global__ void score_reduce_kernel(const float* __restrict__ partS,
                                    const float* __restrict__ partD,
                                    float* __restrict__ s_src, float* __restrict__ s_dst,
                                    int N, int NP) {
  int i = blockIdx.x * blockDim.x + threadIdx.x;
  if (i >= N) return;
  float a = 0.f, b = 0.f;
  for (int p = 0; p < NP; ++p) {
    a += partS[(ll)p * N + i];
    b += partD[(ll)p * N + i];
  }
  s_src[i] = a;
  s_dst[i] = b;
}

// ---------------- wave-per-node fused softmax + weighted aggregation --------
// SCORENEXT: compute next layer's scores from the fp32 output row in regs
// (s = out . wvec_next), write to oSs/oSd (ping-pong buffers vs ssrc/sdst).
template <int DOUT, int HIN_BF16, int OUTB16, int LOGSM, int SCORENEXT>
__global__ __launch_bounds__(256) void agg_wave_kernel(
    const void* __restrict__ hv, const float* __restrict__ ssrc,
    const float* __restrict__ sdst, const int* __restrict__ rowptr,
    const int* __restrict__ csr, const float* __restrict__ bias,
    float* __restrict__ outF, short* __restrict__ outH,
    const float* __restrict__ wvnS, const float* __restrict__ wvnD,
    float* __restrict__ oSs, float* __restrict__ oSd, int N) {
  constexpr int NH = (DOUT >= 512) ? DOUT / 512 : 1;   // row halves of 512 dims
  constexpr int DPL = (DOUT >= 512) ? 8 : DOUT / 64;   // dims/lane per half
  int wid = threadIdx.x >> 6, lane = threadIdx.x & 63;
  int node = blockIdx.x * 4 + wid;
  if (node >= N) return;
  int rs = rowptr[node];
  int nd = rowptr[node + 1] - rs;
  float sd = sdst[node];
  int d0 = lane * DPL;

  float acc[NH][DPL];
#pragma unroll
  for (int hh = 0; hh < NH; ++hh)
#pragma unroll
    for (int k = 0; k < DPL; ++k) acc[hh][k] = 0.f;

  auto accum = [&](int s, float w) {
    if constexpr (HIN_BF16) {
      const unsigned short* hp = (const unsigned short*)hv + (ll)s * DOUT + d0;
#pragma unroll
      for (int hh = 0; hh < NH; ++hh) {
        bf16x8 qv = *(const bf16x8*)(hp + hh * 512);
#pragma unroll
        for (int k = 0; k < 8; ++k)
          acc[hh][k] += w * bf16_back((unsigned short)qv[k]);
      }
    } else {
      const float* hp = (const float*)hv + (ll)s * DOUT + d0;
#pragma unroll
      for (int k = 0; k < DPL; ++k) acc[0][k] += w * hp[k];
    }
  };

  if (nd <= 64) {
    int srcl = 0;
    float e = -1e30f;
    if (lane < nd) {
      srcl = csr[rs + lane];
      float t = ssrc[srcl] + sd;
      e = t > 0.f ? t : NEG_SLOPE * t;
    }
    float m = e;
#pragma unroll
    for (int o = 32; o > 0; o >>= 1) m = fmaxf(m, __shfl_xor(m, o, 64));
    float ex = (lane < nd) ? __expf(e - m) : 0.f;
    float den = ex;
#pragma unroll
    for (int o = 32; o > 0; o >>= 1) den += __shfl_xor(den, o, 64);
    float al = ex / (den + EPS_F);

    int i = 0;
    for (; i + 4 <= nd; i += 4) {
      int s0 = __shfl(srcl, i, 64), s1 = __shfl(srcl, i + 1, 64);
      int s2 = __shfl(srcl, i + 2, 64), s3 = __shfl(srcl, i + 3, 64);
      float w0 = __shfl(al, i, 64), w1 = __shfl(al, i + 1, 64);
      float w2 = __shfl(al, i + 2, 64), w3 = __shfl(al, i + 3, 64);
      accum(s0, w0); accum(s1, w1); accum(s2, w2); accum(s3, w3);
    }
    for (; i < nd; ++i) accum(__shfl(srcl, i, 64), __shfl(al, i, 64));
  } else {
    float m = -1e30f;
    for (int i = lane; i < nd; i += 64) {
      float t = ssrc[csr[rs + i]] + sd;
      t = t > 0.f ? t : NEG_SLOPE * t;
      m = fmaxf(m, t);
    }
#pragma unroll
    for (int o = 32; o > 0; o >>= 1) m = fmaxf(m, __shfl_xor(m, o, 64));
    float den = 0.f;
    for (int i = lane; i < nd; i += 64) {
      float t = ssrc[csr[rs + i]] + sd;
      t = t > 0.f ? t : NEG_SLOPE * t;
      den += __expf(t - m);
    }
#pragma unroll
    for (int o = 32; o > 0; o >>= 1) den += __shfl_xor(den, o, 64);
    float inv = 1.f / (den + EPS_F);
    for (int i = 0; i < nd; ++i) {
      int s = csr[rs + i];  // wave-uniform broadcast load
      float t = ssrc[s] + sd;
      t = t > 0.f ? t : NEG_SLOPE * t;
      accum(s, __expf(t - m) * inv);
    }
  }

  if constexpr (OUTB16) {
    float ps = 0.f, pd = 0.f;
#pragma unroll
    for (int hh = 0; hh < NH; ++hh) {
      int d = hh * 512 + d0;
      bf16x8 hp8;
#pragma unroll
      for (int k = 0; k < 8; ++k) {
        float v = fmaxf(acc[hh][k] + bias[d + k], 0.f);
        hp8[k] = (short)bf16_of(v);
        if constexpr (SCORENEXT) {
          ps += v * wvnS[d + k];
          pd += v * wvnD[d + k];
        }
      }
      *(bf16x8*)&outH[(ll)node * DOUT + d] = hp8;
    }
    if constexpr (SCORENEXT) {
#pragma unroll
      for (int o = 32; o > 0; o >>= 1) {
        ps += __shfl_xor(ps, o, 64);
        pd += __shfl_xor(pd, o, 64);
      }
      if (lane == 0) { oSs[node] = ps; oSd[node] = pd; }
    }
  } else if constexpr (LOGSM) {
    float v0 = acc[0][0] + bias[d0 + 0];
    float v1 = acc[0][1] + bias[d0 + 1];
    float mx = fmaxf(v0, v1);
#pragma unroll
    for (int o = 32; o > 0; o >>= 1) mx = fmaxf(mx, __shfl_xor(mx, o, 64));
    float s = __expf(v0 - mx) + __expf(v1 - mx);
#pragma unroll
    for (int o = 32; o > 0; o >>= 1) s += __shfl_xor(s, o, 64);
    float ls = logf(s);
    outF[(ll)node * DOUT + d0 + 0] = v0 - mx - ls;
    outF[(ll)node * DOUT + d0 + 1] = v1 - mx - ls;
  } else {
#pragma unroll
    for (int k = 0; k < DPL; ++k)
      outF[(ll)node * DOUT + d0 + k] = acc[0][k] + bias[d0 + k];
  }
}

// ---------------- launch ----------------
extern "C" void kernel_launch(void* const* d_in, const int* in_sizes, int n_in,
                              void* d_out, int out_size, void* d_ws, size_t ws_size,
                              hipStream_t stream) {
  const float* x = (const float*)d_in[0];
  const int* ew = (const int*)d_in[1];
  int N = in_sizes[0] / 256;
  int E = in_sizes[1] / 2;

  const float* W[4]   = {(const float*)d_in[2],  (const float*)d_in[6],
                         (const float*)d_in[10], (const float*)d_in[14]};
  const float* Asv[4] = {(const float*)d_in[3],  (const float*)d_in[7],
                         (const float*)d_in[11], (const float*)d_in[15]};
  const float* Adv[4] = {(const float*)d_in[4],  (const float*)d_in[8],
                         (const float*)d_in[12], (const float*)d_in[16]};
  const float* Bv[4]  = {(const float*)d_in[5],  (const float*)d_in[9],
                         (const float*)d_in[13], (const float*)d_in[17]};
  const int din[4]  = {256, 1024, 1024, 512};
  const int dout[4] = {1024, 1024, 512, 128};

  char* ws = (char*)d_ws;
  size_t off = 0;
  auto alloc = [&](size_t bytes) {
    void* p = ws + off;
    off += (bytes + 255) & ~(size_t)255;
    return p;
  };
  unsigned short* hB = (unsigned short*)alloc((size_t)N * 1024 * 2);  // bf16 h (layers 2-3)
  float* hF   = (float*)alloc((size_t)N * 128 * 4);                   // fp32 h (layer 4)
  short* bufP = (short*)alloc((size_t)N * 512 * 2);   // xagg split [hi|lo]
  short* bufQ = (short*)alloc((size_t)N * 1024 * 2);  // inter-layer bf16 act
  short* bufR = (short*)alloc((size_t)N * 1024 * 2);
  float* s_src  = (float*)alloc((size_t)N * 4);
  float* s_dst  = (float*)alloc((size_t)N * 4);
  float* s_src2 = (float*)alloc((size_t)N * 4);
  float* s_dst2 = (float*)alloc((size_t)N * 4);
  float* partS = (float*)alloc((size_t)16 * N * 4);
  float* partD = (float*)alloc((size_t)16 * N * 4);
  float* wvS  = (float*)alloc((size_t)2048 * 4);  // l0@0, l2@256, l3@1280
  float* wvD  = (float*)alloc((size_t)2048 * 4);
  int* deg    = (int*)alloc((size_t)(N + 1) * 4);
  int* rowptr = (int*)alloc((size_t)(N + 1) * 4);
  int* cursor = (int*)alloc((size_t)(N + 1) * 4);
  int* csr    = (int*)alloc((size_t)(E + N) * 4);
  int* flag   = (int*)alloc(256);
  short* Bt[4];
  for (int l = 0; l < 4; ++l) Bt[l] = (short*)alloc((size_t)dout[l] * din[l] * 2);

  detect_int64_kernel<<<1, 256, 0, stream>>>((const unsigned int*)ew, E, flag);
  hipMemsetAsync(deg, 0, (size_t)(N + 1) * 4, stream);
  count_deg_kernel<<<(E + 255) / 256, 256, 0, stream>>>(ew, E, deg, flag);
  scan_kernel<<<1, 1024, 0, stream>>>(deg, rowptr, cursor, N);
  fill_kernel<<<(E + N + 255) / 256, 256, 0, stream>>>(ew, E, N, cursor, csr, flag);

  {
    dim3 cg(32, 32, 4);
    convert_w_all_kernel<<<cg, 256, 0, stream>>>(W[0], W[1], W[2], W[3],
                                                 Bt[0], Bt[1], Bt[2], Bt[3]);
  }
  {
    dim3 wg(256, 3);
    wvec_all_kernel<<<wg, 256, 0, stream>>>(W[0], Asv[0], Adv[0],
                                            W[2], Asv[2], Adv[2],
                                            W[3], Asv[3], Adv[3], wvS, wvD);
  }

  int ngrp = (N + 3) / 4;
  int mgrp = (N + 63) / 64;
  // layer 1: GEMV scores -> input-side aggregation -> split GEMM (bias+relu fused)
  {
    score_gemv_kernel<<<ngrp, 256, 0, stream>>>(x, wvS, wvD, s_src, s_dst, N);
    agg_x_kernel<<<ngrp, 256, 0, stream>>>(x, s_src, s_dst, rowptr, csr, bufP, N);
    dim3 gg(dout[0] / 128, mgrp);
    gemm_mfma_kernel<1, 1, 1, 0><<<gg, 256, 0, stream>>>(
        bufP, Bt[0], bufQ, nullptr, nullptr, Bv[0], nullptr, nullptr, N, dout[0], din[0]);
  }
  // layer 2: GEMM (h2 + fused score partials) -> reduce -> agg (emits layer-3 scores)
  {
    dim3 gg(dout[1] / 128, mgrp);
    gemm_mfma_kernel<1, 0, 0, 1><<<gg, 256, 0, stream>>>(
        bufQ, Bt[1], hB, Asv[1], Adv[1], nullptr, partS, partD, N, dout[1], din[1]);
    score_reduce_kernel<<<(N + 255) / 256, 256, 0, stream>>>(partS, partD, s_src, s_dst,
                                                             N, (dout[1] / 128) * 2);
    agg_wave_kernel<1024, 1, 1, 0, 1><<<ngrp, 256, 0, stream>>>(
        hB, s_src, s_dst, rowptr, csr, Bv[1], nullptr, bufR,
        wvS + 256, wvD + 256, s_src2, s_dst2, N);
  }
  // layer 3: pure GEMM -> agg (emits layer-4 scores)
  {
    dim3 gg(dout[2] / 128, mgrp);
    gemm_mfma_kernel<1, 0, 0, 0><<<gg, 256, 0, stream>>>(
        bufR, Bt[2], hB, nullptr, nullptr, nullptr, nullptr, nullptr, N, dout[2], din[2]);
    agg_wave_kernel<512, 1, 1, 0, 1><<<ngrp, 256, 0, stream>>>(
        hB, s_src2, s_dst2, rowptr, csr, Bv[2], nullptr, bufQ,
        wvS + 1280, wvD + 1280, s_src, s_dst, N);
  }
  // layer 4: pure GEMM (fp32 h) -> agg + fused log_softmax
  {
    dim3 gg(dout[3] / 128, mgrp);
    gemm_mfma_kernel<0, 0, 0, 0><<<gg, 256, 0, stream>>>(
        bufQ, Bt[3], hF, nullptr, nullptr, nullptr, nullptr, nullptr, N, dout[3], din[3]);
    agg_wave_kernel<128, 0, 0, 1, 0><<<ngrp, 256, 0, stream>>>(
        hF, s_src, s_dst, rowptr, csr, Bv[3], (float*)d_out, nullptr,
        nullptr, nullptr, nullptr, nullptr, N);
  }
}

// Round 16
// 254.183 us; speedup vs baseline: 1.7255x; 1.0205x over previous
//
#include <hip/hip_runtime.h>
#include <math.h>

#define NEG_SLOPE 0.2f
#define EPS_F 1e-16f
typedef long long ll;

typedef __attribute__((ext_vector_type(4))) float f32x4;
typedef __attribute__((ext_vector_type(8))) short bf16x8;

// ---------------- bf16 helpers (bit-level, RTN-even) ----------------
__device__ __forceinline__ unsigned short bf16_of(float f) {
  unsigned u = __float_as_uint(f);
  u += 0x7fffu + ((u >> 16) & 1u);
  return (unsigned short)(u >> 16);
}
__device__ __forceinline__ float bf16_back(unsigned short s) {
  return __uint_as_float((unsigned)s << 16);
}

__device__ __forceinline__ void gload16(const void* g, void* l) {
  __builtin_amdgcn_global_load_lds((const __attribute__((address_space(1))) void*)g,
                                   (__attribute__((address_space(3))) void*)l, 16, 0, 0);
}

// block-uniform int64-layout detection from a fixed window (deterministic)
__device__ __forceinline__ int detect64_block(const int* __restrict__ ew, int E) {
  __shared__ int nzs;
  if (threadIdx.x == 0) nzs = 0;
  __syncthreads();
  const unsigned* w = (const unsigned*)ew;
  int cnt = E < 2048 ? E : 2048;
  int local = 0;
  for (int i = threadIdx.x; i < cnt; i += blockDim.x)
    if (w[2 * i + 1] != 0u) local++;
  if (local) atomicAdd(&nzs, local);
  __syncthreads();
  return nzs == 0;  // all high words zero => int64 layout
}

__device__ __forceinline__ void edge_at(const int* __restrict__ ew, int E, int e,
                                        int is64, int& s, int& d) {
  if (is64) { s = ew[2 * e]; d = ew[2 * E + 2 * e]; }
  else      { s = ew[e];     d = ew[E + e]; }
}

// ---------------- CSR build (deg = edge-count; +1 self-loop folded in scan) ----
__global__ void count_deg_kernel(const int* __restrict__ ew, int E, int* deg) {
  int is64 = detect64_block(ew, E);
  int e = blockIdx.x * blockDim.x + threadIdx.x;
  if (e < E) {
    int s, d;
    edge_at(ew, E, e, is64, s, d);
    atomicAdd(&deg[d], 1);
  }
}

__global__ void scan_kernel(const int* __restrict__ deg, int* rowptr, int* cursor, int N) {
  __shared__ int sums[1024];
  int tid = threadIdx.x;
  int chunk = (N + 1023) >> 10;
  int start = tid * chunk;
  int end = start + chunk; if (end > N) end = N;
  int s = 0;
  for (int i = start; i < end; ++i) s += deg[i] + 1;  // +1 = self loop
  sums[tid] = s;
  __syncthreads();
  for (int off = 1; off < 1024; off <<= 1) {
    int v = (tid >= off) ? sums[tid - off] : 0;
    __syncthreads();
    sums[tid] += v;
    __syncthreads();
  }
  int run = (tid == 0) ? 0 : sums[tid - 1];
  for (int i = start; i < end; ++i) {
    rowptr[i] = run; cursor[i] = run;
    run += deg[i] + 1;
  }
  if (tid == 1023) rowptr[N] = sums[1023];
}

__global__ void fill_kernel(const int* __restrict__ ew, int E, int N, int* cursor,
                            int* csr) {
  int is64 = detect64_block(ew, E);
  int i = blockIdx.x * blockDim.x + threadIdx.x;
  if (i < E) {
    int s, d;
    edge_at(ew, E, i, is64, s, d);
    int pos = atomicAdd(&cursor[d], 1);
    csr[pos] = s;
  } else if (i < E + N) {
    int n = i - E;
    int pos = atomicAdd(&cursor[n], 1);
    csr[pos] = n;
  }
}

// ---------------- weight conversions + wvec (one dispatch) ----------------
// z<4: W[z] [K,Nc] fp32 -> Bt[z] [Nc,K] bf16 (W_hi^T).
// z==4: wvec for layers 0,2,3: wv[k] = sum_j W[k][j]*a[j]; offsets {0,256,1280}.
__global__ __launch_bounds__(256) void convert_w_wvec_kernel(
    const float* __restrict__ W0, const float* __restrict__ W1,
    const float* __restrict__ W2, const float* __restrict__ W3,
    short* __restrict__ B0, short* __restrict__ B1,
    short* __restrict__ B2, short* __restrict__ B3,
    const float* __restrict__ as0, const float* __restrict__ ad0,
    const float* __restrict__ as2, const float* __restrict__ ad2,
    const float* __restrict__ as3, const float* __restrict__ ad3,
    float* __restrict__ wvS, float* __restrict__ wvD) {
  int z = blockIdx.z;
  if (z < 4) {
    const int Ks[4]  = {256, 1024, 1024, 512};
    const int Ncs[4] = {1024, 1024, 512, 128};
    int K = Ks[z], Nc = Ncs[z];
    int k0 = blockIdx.x * 32, n0 = blockIdx.y * 32;
    if (k0 >= K || n0 >= Nc) return;
    const float* W = z == 0 ? W0 : (z == 1 ? W1 : (z == 2 ? W2 : W3));
    short* Bt = z == 0 ? B0 : (z == 1 ? B1 : (z == 2 ? B2 : B3));
    __shared__ float t[32][33];
    int r = threadIdx.x >> 3;          // 0..31
    int c4 = (threadIdx.x & 7) * 4;    // 0..28
    float4 v = *(const float4*)&W[(ll)(k0 + r) * Nc + n0 + c4];
    t[r][c4] = v.x; t[r][c4 + 1] = v.y; t[r][c4 + 2] = v.z; t[r][c4 + 3] = v.w;
    __syncthreads();
    float f0 = t[c4 + 0][r], f1 = t[c4 + 1][r], f2 = t[c4 + 2][r], f3 = t[c4 + 3][r];
    short4 hp = make_short4((short)bf16_of(f0), (short)bf16_of(f1),
                            (short)bf16_of(f2), (short)bf16_of(f3));
    *(short4*)&Bt[(ll)(n0 + r) * K + k0 + c4] = hp;
  } else {
    const int Ks[3]   = {256, 1024, 512};
    const int Ncs[3]  = {1024, 512, 128};
    const int offs[3] = {0, 256, 1280};
    int id = blockIdx.y * 32 + blockIdx.x;  // 0..1023
    if (id >= 768) return;
    int zi = id >> 8, kg = id & 255;
    int K = Ks[zi], Nc = Ncs[zi];
    int wid = threadIdx.x >> 6, lane = threadIdx.x & 63;
    int k = kg * 4 + wid;
    if (k >= K) return;
    const float* W  = zi == 0 ? W0 : (zi == 1 ? W2 : W3);
    const float* as = zi == 0 ? as0 : (zi == 1 ? as2 : as3);
    const float* ad = zi == 0 ? ad0 : (zi == 1 ? ad2 : ad3);
    const float* row = W + (ll)k * Nc;
    float a = 0.f, b = 0.f;
    for (int j = lane; j < Nc; j += 64) {
      float w = row[j];
      a += w * as[j];
      b += w * ad[j];
    }
#pragma unroll
    for (int o = 32; o > 0; o >>= 1) {
      a += __shfl_xor(a, o, 64);
      b += __shfl_xor(b, o, 64);
    }
    if (lane == 0) { wvS[offs[zi] + k] = a; wvD[offs[zi] + k] = b; }
  }
}

// layer-1 scores by GEMV (din=256)
__global__ void score_gemv_kernel(const float* __restrict__ x, const float* __restrict__ ws,
                                  const float* __restrict__ wd, float* __restrict__ s_src,
                                  float* __restrict__ s_dst, int N) {
  int wid = threadIdx.x >> 6, lane = threadIdx.x & 63;
  int n = blockIdx.x * 4 + wid;
  if (n >= N) return;
  float4 xv = *(const float4*)&x[(ll)n * 256 + lane * 4];
  float4 wsv = *(const float4*)&ws[lane * 4];
  float4 wdv = *(const float4*)&wd[lane * 4];
  float a = xv.x * wsv.x + xv.y * wsv.y + xv.z * wsv.z + xv.w * wsv.w;
  float b = xv.x * wdv.x + xv.y * wdv.y + xv.z * wdv.z + xv.w * wdv.w;
#pragma unroll
  for (int o = 32; o > 0; o >>= 1) {
    a += __shfl_xor(a, o, 64);
    b += __shfl_xor(b, o, 64);
  }
  if (lane == 0) { s_src[n] = a; s_dst[n] = b; }
}

// ---------------- layer-1 input-side aggregation (plain bf16 out) -----------
__global__ __launch_bounds__(256) void agg_x_kernel(
    const float* __restrict__ x, const float* __restrict__ ssrc,
    const float* __restrict__ sdst, const int* __restrict__ rowptr,
    const int* __restrict__ csr, short* __restrict__ outH, int N) {
  int wid = threadIdx.x >> 6, lane = threadIdx.x & 63;
  int node = blockIdx.x * 4 + wid;
  if (node >= N) return;
  int rs = rowptr[node];
  int nd = rowptr[node + 1] - rs;
  float sd = sdst[node];
  int d0 = lane * 4;

  float a0 = 0.f, a1 = 0.f, a2 = 0.f, a3 = 0.f;
  auto accum = [&](int s, float w) {
    float4 xv = *(const float4*)&x[(ll)s * 256 + d0];
    a0 += w * xv.x; a1 += w * xv.y; a2 += w * xv.z; a3 += w * xv.w;
  };

  if (nd <= 64) {
    int srcl = 0;
    float e = -1e30f;
    if (lane < nd) {
      srcl = csr[rs + lane];
      float t = ssrc[srcl] + sd;
      e = t > 0.f ? t : NEG_SLOPE * t;
    }
    float m = e;
#pragma unroll
    for (int o = 32; o > 0; o >>= 1) m = fmaxf(m, __shfl_xor(m, o, 64));
    float ex = (lane < nd) ? __expf(e - m) : 0.f;
    float den = ex;
#pragma unroll
    for (int o = 32; o > 0; o >>= 1) den += __shfl_xor(den, o, 64);
    float al = ex / (den + EPS_F);
    int i = 0;
    for (; i + 4 <= nd; i += 4) {
      int s0 = __shfl(srcl, i, 64), s1 = __shfl(srcl, i + 1, 64);
      int s2 = __shfl(srcl, i + 2, 64), s3 = __shfl(srcl, i + 3, 64);
      float w0 = __shfl(al, i, 64), w1 = __shfl(al, i + 1, 64);
      float w2 = __shfl(al, i + 2, 64), w3 = __shfl(al, i + 3, 64);
      accum(s0, w0); accum(s1, w1); accum(s2, w2); accum(s3, w3);
    }
    for (; i < nd; ++i) accum(__shfl(srcl, i, 64), __shfl(al, i, 64));
  } else {
    float m = -1e30f;
    for (int i = lane; i < nd; i += 64) {
      float t = ssrc[csr[rs + i]] + sd;
      t = t > 0.f ? t : NEG_SLOPE * t;
      m = fmaxf(m, t);
    }
#pragma unroll
    for (int o = 32; o > 0; o >>= 1) m = fmaxf(m, __shfl_xor(m, o, 64));
    float den = 0.f;
    for (int i = lane; i < nd; i += 64) {
      float t = ssrc[csr[rs + i]] + sd;
      t = t > 0.f ? t : NEG_SLOPE * t;
      den += __expf(t - m);
    }
#pragma unroll
    for (int o = 32; o > 0; o >>= 1) den += __shfl_xor(den, o, 64);
    float inv = 1.f / (den + EPS_F);
    for (int i = 0; i < nd; ++i) {
      int s = csr[rs + i];
      float t = ssrc[s] + sd;
      t = t > 0.f ? t : NEG_SLOPE * t;
      accum(s, __expf(t - m) * inv);
    }
  }

  short4 hp = make_short4((short)bf16_of(a0), (short)bf16_of(a1),
                          (short)bf16_of(a2), (short)bf16_of(a3));
  *(short4*)&outH[(ll)node * 256 + d0] = hp;
}

// ---------------- MFMA GEMM (64x128 tile, BK=64) + optional fused epilogues --
// Chunk XOR-swizzle phys = log ^ (row&7); LDS linear, global source permuted.
// XCD-chunked bijective block swizzle for L2 locality.
template <int HBF16, int BIASRELU, int SCORES>
__global__ __launch_bounds__(256) void gemm_mfma_kernel(
    const short* __restrict__ A, const short* __restrict__ Bt,
    void* __restrict__ Cv, const float* __restrict__ a_src,
    const float* __restrict__ a_dst, const float* __restrict__ bias,
    float* __restrict__ partS, float* __restrict__ partD, int M, int Nc, int K) {
  __shared__ char Ah[8192];   // 64 rows x 128B
  __shared__ char Bs[16384];  // 128 rows x 128B
  int tid = threadIdx.x;

  int nwg = gridDim.x * gridDim.y;
  int hb = blockIdx.y * gridDim.x + blockIdx.x;
  int xcd = hb & 7, q = nwg >> 3, r = nwg & 7;
  int lg = (xcd < r ? xcd * (q + 1) : r * (q + 1) + (xcd - r) * q) + (hb >> 3);
  int bx = lg % gridDim.x, by = lg / gridDim.x;
  int bm = by * 64, bn = bx * 128;

  int lane = tid & 63, wid = tid >> 6;
  int wr = wid >> 1, wc = wid & 1;

  f32x4 acc[2][4];
#pragma unroll
  for (int m = 0; m < 2; ++m)
#pragma unroll
    for (int n = 0; n < 4; ++n) acc[m][n] = (f32x4){0.f, 0.f, 0.f, 0.f};

  int srow = tid >> 3;                  // 0..31
  int gc = (tid & 7) ^ (srow & 7);      // global 16B-chunk fetched
  int raA0 = bm + srow;      if (raA0 > M - 1) raA0 = M - 1;
  int raA1 = bm + srow + 32; if (raA1 > M - 1) raA1 = M - 1;
  const short* aSrc0 = A + (ll)raA0 * K + gc * 8;
  const short* aSrc1 = A + (ll)raA1 * K + gc * 8;
  const short* bSrc0 = Bt + (ll)(bn + srow) * K + gc * 8;
  const short* bSrc1 = Bt + (ll)(bn + srow + 32) * K + gc * 8;
  const short* bSrc2 = Bt + (ll)(bn + srow + 64) * K + gc * 8;
  const short* bSrc3 = Bt + (ll)(bn + srow + 96) * K + gc * 8;
  int dstOff = tid * 16;

  int lrow = lane & 15;
  int swzr = lrow & 7;
  int c0 = lane >> 4;  // 0..3
  int offA[2][2], offB[4][2];
#pragma unroll
  for (int m = 0; m < 2; ++m)
#pragma unroll
    for (int kk = 0; kk < 2; ++kk)
      offA[m][kk] = ((wr * 32 + m * 16 + lrow) * 8 + ((c0 + kk * 4) ^ swzr)) * 16;
#pragma unroll
  for (int n = 0; n < 4; ++n)
#pragma unroll
    for (int kk = 0; kk < 2; ++kk)
      offB[n][kk] = ((wc * 64 + n * 16 + lrow) * 8 + ((c0 + kk * 4) ^ swzr)) * 16;

  for (int kt = 0; kt < K; kt += 64) {
    gload16(aSrc0 + kt, Ah + dstOff);
    gload16(aSrc1 + kt, Ah + 4096 + dstOff);
    gload16(bSrc0 + kt, Bs + dstOff);
    gload16(bSrc1 + kt, Bs + 4096 + dstOff);
    gload16(bSrc2 + kt, Bs + 8192 + dstOff);
    gload16(bSrc3 + kt, Bs + 12288 + dstOff);
    __syncthreads();
    bf16x8 ah[2][2], bfr[4][2];
#pragma unroll
    for (int m = 0; m < 2; ++m)
#pragma unroll
      for (int kk = 0; kk < 2; ++kk)
        ah[m][kk] = *(const bf16x8*)(Ah + offA[m][kk]);
#pragma unroll
    for (int n = 0; n < 4; ++n)
#pragma unroll
      for (int kk = 0; kk < 2; ++kk)
        bfr[n][kk] = *(const bf16x8*)(Bs + offB[n][kk]);
#pragma unroll
    for (int kk = 0; kk < 2; ++kk)
#pragma unroll
      for (int m = 0; m < 2; ++m)
#pragma unroll
        for (int n = 0; n < 4; ++n)
          acc[m][n] = __builtin_amdgcn_mfma_f32_16x16x32_bf16(ah[m][kk], bfr[n][kk],
                                                              acc[m][n], 0, 0, 0);
    __syncthreads();
  }

  int crow0 = bm + wr * 32 + (lane >> 4) * 4;
  int ccol0 = bn + wc * 64 + (lane & 15);
  float bv4[4];
  if constexpr (BIASRELU) {
#pragma unroll
    for (int n = 0; n < 4; ++n) bv4[n] = bias[ccol0 + n * 16];
  }
#pragma unroll
  for (int m = 0; m < 2; ++m) {
#pragma unroll
    for (int j = 0; j < 4; ++j) {
      int row = crow0 + m * 16 + j;
      if (row < M) {
#pragma unroll
        for (int n = 0; n < 4; ++n) {
          float v = acc[m][n][j];
          if constexpr (BIASRELU) v = fmaxf(v + bv4[n], 0.f);
          if (HBF16) ((unsigned short*)Cv)[(ll)row * Nc + ccol0 + n * 16] = bf16_of(v);
          else       ((float*)Cv)[(ll)row * Nc + ccol0 + n * 16] = v;
        }
      }
    }
  }

  if constexpr (SCORES) {
    float as4[4], ad4[4];
#pragma unroll
    for (int n = 0; n < 4; ++n) {
      as4[n] = a_src[ccol0 + n * 16];
      ad4[n] = a_dst[ccol0 + n * 16];
    }
    int p = bx * 2 + wc;
#pragma unroll
    for (int m = 0; m < 2; ++m) {
#pragma unroll
      for (int j = 0; j < 4; ++j) {
        float ps = acc[m][0][j] * as4[0] + acc[m][1][j] * as4[1] +
                   acc[m][2][j] * as4[2] + acc[m][3][j] * as4[3];
        float pd = acc[m][0][j] * ad4[0] + acc[m][1][j] * ad4[1] +
                   acc[m][2][j] * ad4[2] + acc[m][3][j] * ad4[3];
#pragma unroll
        for (int o = 1; o < 16; o <<= 1) {
          ps += __shfl_xor(ps, o, 64);
          pd += __shfl_xor(pd, o, 64);
        }
        int row = crow0 + m * 16 + j;
        if ((lane & 15) == 0 && row < M) {
          partS[(ll)p * M + row] = ps;
          partD[(ll)p * M + row] = pd;
        }
      }
    }
  }
}

// sum the per-(col-block,wc) partials -> s_src/s_dst
__global__ void score_reduce_kernel(const float* __restrict__ partS,
                                    const float* __restrict__ partD,
                                    float* __restrict__ s_src, float* __restrict__ s_dst,
                                    int N, int NP) {
  int i = blockIdx.x * blockDim.x + threadIdx.x;
  if (i >= N) return;
  float a = 0.f, b = 0.f;
  for (int p = 0; p < NP; ++p) {
    a += partS[(ll)p * N + i];
    b += partD[(ll)p * N + i];
  }
  s_src[i] = a;
  s_dst[i] = b;
}

// ---------------- wave-per-node fused softmax + weighted aggregation --------
// SCORENEXT: compute next layer's scores from the fp32 output row in regs.
template <int DOUT, int HIN_BF16, int OUTB16, int LOGSM, int SCORENEXT>
__global__ __launch_bounds__(256) void agg_wave_kernel(
    const void* __restrict__ hv, const float* __restrict__ ssrc,
    const float* __restrict__ sdst, const int* __restrict__ rowptr,
    const int* __restrict__ csr, const float* __restrict__ bias,
    float* __restrict__ outF, short* __restrict__ outH,
    const float* __restrict__ wvnS, const float* __restrict__ wvnD,
    float* __restrict__ oSs, float* __restrict__ oSd, int N) {
  constexpr int NH = (DOUT >= 512) ? DOUT / 512 : 1;   // row halves of 512 dims
  constexpr int DPL = (DOUT >= 512) ? 8 : DOUT / 64;   // dims/lane per half
  int wid = threadIdx.x >> 6, lane = threadIdx.x & 63;
  int node = blockIdx.x * 4 + wid;
  if (node >= N) return;
  int rs = rowptr[node];
  int nd = rowptr[node + 1] - rs;
  float sd = sdst[node];
  int d0 = lane * DPL;

  float acc[NH][DPL];
#pragma unroll
  for (int hh = 0; hh < NH; ++hh)
#pragma unroll
    for (int k = 0; k < DPL; ++k) acc[hh][k] = 0.f;

  auto accum = [&](int s, float w) {
    if constexpr (HIN_BF16) {
      const unsigned short* hp = (const unsigned short*)hv + (ll)s * DOUT + d0;
#pragma unroll
      for (int hh = 0; hh < NH; ++hh) {
        bf16x8 qv = *(const bf16x8*)(hp + hh * 512);
#pragma unroll
        for (int k = 0; k < 8; ++k)
          acc[hh][k] += w * bf16_back((unsigned short)qv[k]);
      }
    } else {
      const float* hp = (const float*)hv + (ll)s * DOUT + d0;
#pragma unroll
      for (int k = 0; k < DPL; ++k) acc[0][k] += w * hp[k];
    }
  };

  if (nd <= 64) {
    int srcl = 0;
    float e = -1e30f;
    if (lane < nd) {
      srcl = csr[rs + lane];
      float t = ssrc[srcl] + sd;
      e = t > 0.f ? t : NEG_SLOPE * t;
    }
    float m = e;
#pragma unroll
    for (int o = 32; o > 0; o >>= 1) m = fmaxf(m, __shfl_xor(m, o, 64));
    float ex = (lane < nd) ? __expf(e - m) : 0.f;
    float den = ex;
#pragma unroll
    for (int o = 32; o > 0; o >>= 1) den += __shfl_xor(den, o, 64);
    float al = ex / (den + EPS_F);

    int i = 0;
    for (; i + 4 <= nd; i += 4) {
      int s0 = __shfl(srcl, i, 64), s1 = __shfl(srcl, i + 1, 64);
      int s2 = __shfl(srcl, i + 2, 64), s3 = __shfl(srcl, i + 3, 64);
      float w0 = __shfl(al, i, 64), w1 = __shfl(al, i + 1, 64);
      float w2 = __shfl(al, i + 2, 64), w3 = __shfl(al, i + 3, 64);
      accum(s0, w0); accum(s1, w1); accum(s2, w2); accum(s3, w3);
    }
    for (; i < nd; ++i) accum(__shfl(srcl, i, 64), __shfl(al, i, 64));
  } else {
    float m = -1e30f;
    for (int i = lane; i < nd; i += 64) {
      float t = ssrc[csr[rs + i]] + sd;
      t = t > 0.f ? t : NEG_SLOPE * t;
      m = fmaxf(m, t);
    }
#pragma unroll
    for (int o = 32; o > 0; o >>= 1) m = fmaxf(m, __shfl_xor(m, o, 64));
    float den = 0.f;
    for (int i = lane; i < nd; i += 64) {
      float t = ssrc[csr[rs + i]] + sd;
      t = t > 0.f ? t : NEG_SLOPE * t;
      den += __expf(t - m);
    }
#pragma unroll
    for (int o = 32; o > 0; o >>= 1) den += __shfl_xor(den, o, 64);
    float inv = 1.f / (den + EPS_F);
    for (int i = 0; i < nd; ++i) {
      int s = csr[rs + i];  // wave-uniform broadcast load
      float t = ssrc[s] + sd;
      t = t > 0.f ? t : NEG_SLOPE * t;
      accum(s, __expf(t - m) * inv);
    }
  }

  if constexpr (OUTB16) {
    float ps = 0.f, pd = 0.f;
#pragma unroll
    for (int hh = 0; hh < NH; ++hh) {
      int d = hh * 512 + d0;
      bf16x8 hp8;
#pragma unroll
      for (int k = 0; k < 8; ++k) {
        float v = fmaxf(acc[hh][k] + bias[d + k], 0.f);
        hp8[k] = (short)bf16_of(v);
        if constexpr (SCORENEXT) {
          ps += v * wvnS[d + k];
          pd += v * wvnD[d + k];
        }
      }
      *(bf16x8*)&outH[(ll)node * DOUT + d] = hp8;
    }
    if constexpr (SCORENEXT) {
#pragma unroll
      for (int o = 32; o > 0; o >>= 1) {
        ps += __shfl_xor(ps, o, 64);
        pd += __shfl_xor(pd, o, 64);
      }
      if (lane == 0) { oSs[node] = ps; oSd[node] = pd; }
    }
  } else if constexpr (LOGSM) {
    float v0 = acc[0][0] + bias[d0 + 0];
    float v1 = acc[0][1] + bias[d0 + 1];
    float mx = fmaxf(v0, v1);
#pragma unroll
    for (int o = 32; o > 0; o >>= 1) mx = fmaxf(mx, __shfl_xor(mx, o, 64));
    float s = __expf(v0 - mx) + __expf(v1 - mx);
#pragma unroll
    for (int o = 32; o > 0; o >>= 1) s += __shfl_xor(s, o, 64);
    float ls = logf(s);
    outF[(ll)node * DOUT + d0 + 0] = v0 - mx - ls;
    outF[(ll)node * DOUT + d0 + 1] = v1 - mx - ls;
  } else {
#pragma unroll
    for (int k = 0; k < DPL; ++k)
      outF[(ll)node * DOUT + d0 + k] = acc[0][k] + bias[d0 + k];
  }
}

// ---------------- launch ----------------
extern "C" void kernel_launch(void* const* d_in, const int* in_sizes, int n_in,
                              void* d_out, int out_size, void* d_ws, size_t ws_size,
                              hipStream_t stream) {
  const float* x = (const float*)d_in[0];
  const int* ew = (const int*)d_in[1];
  int N = in_sizes[0] / 256;
  int E = in_sizes[1] / 2;

  const float* W[4]   = {(const float*)d_in[2],  (const float*)d_in[6],
                         (const float*)d_in[10], (const float*)d_in[14]};
  const float* Asv[4] = {(const float*)d_in[3],  (const float*)d_in[7],
                         (const float*)d_in[11], (const float*)d_in[15]};
  const float* Adv[4] = {(const float*)d_in[4],  (const float*)d_in[8],
                         (const float*)d_in[12], (const float*)d_in[16]};
  const float* Bv[4]  = {(const float*)d_in[5],  (const float*)d_in[9],
                         (const float*)d_in[13], (const float*)d_in[17]};
  const int din[4]  = {256, 1024, 1024, 512};
  const int dout[4] = {1024, 1024, 512, 128};

  char* ws = (char*)d_ws;
  size_t off = 0;
  auto alloc = [&](size_t bytes) {
    void* p = ws + off;
    off += (bytes + 255) & ~(size_t)255;
    return p;
  };
  unsigned short* hB = (unsigned short*)alloc((size_t)N * 1024 * 2);  // bf16 h (layers 2-3)
  float* hF   = (float*)alloc((size_t)N * 128 * 4);                   // fp32 h (layer 4)
  short* bufP = (short*)alloc((size_t)N * 256 * 2);   // xagg bf16
  short* bufQ = (short*)alloc((size_t)N * 1024 * 2);  // inter-layer bf16 act
  short* bufR = (short*)alloc((size_t)N * 1024 * 2);
  float* s_src  = (float*)alloc((size_t)N * 4);
  float* s_dst  = (float*)alloc((size_t)N * 4);
  float* s_src2 = (float*)alloc((size_t)N * 4);
  float* s_dst2 = (float*)alloc((size_t)N * 4);
  float* partS = (float*)alloc((size_t)16 * N * 4);
  float* partD = (float*)alloc((size_t)16 * N * 4);
  float* wvS  = (float*)alloc((size_t)2048 * 4);  // l0@0, l2@256, l3@1280
  float* wvD  = (float*)alloc((size_t)2048 * 4);
  int* deg    = (int*)alloc((size_t)(N + 1) * 4);
  int* rowptr = (int*)alloc((size_t)(N + 1) * 4);
  int* cursor = (int*)alloc((size_t)(N + 1) * 4);
  int* csr    = (int*)alloc((size_t)(E + N) * 4);
  short* Bt[4];
  for (int l = 0; l < 4; ++l) Bt[l] = (short*)alloc((size_t)dout[l] * din[l] * 2);

  hipMemsetAsync(deg, 0, (size_t)(N + 1) * 4, stream);
  count_deg_kernel<<<(E + 255) / 256, 256, 0, stream>>>(ew, E, deg);
  scan_kernel<<<1, 1024, 0, stream>>>(deg, rowptr, cursor, N);
  fill_kernel<<<(E + N + 255) / 256, 256, 0, stream>>>(ew, E, N, cursor, csr);

  {
    dim3 cg(32, 32, 5);
    convert_w_wvec_kernel<<<cg, 256, 0, stream>>>(
        W[0], W[1], W[2], W[3], Bt[0], Bt[1], Bt[2], Bt[3],
        Asv[0], Adv[0], Asv[2], Adv[2], Asv[3], Adv[3], wvS, wvD);
  }

  int ngrp = (N + 3) / 4;
  int mgrp = (N + 63) / 64;
  // layer 1: GEMV scores -> input-side aggregation (bf16) -> GEMM (bias+relu)
  {
    score_gemv_kernel<<<ngrp, 256, 0, stream>>>(x, wvS, wvD, s_src, s_dst, N);
    agg_x_kernel<<<ngrp, 256, 0, stream>>>(x, s_src, s_dst, rowptr, csr, bufP, N);
    dim3 gg(dout[0] / 128, mgrp);
    gemm_mfma_kernel<1, 1, 0><<<gg, 256, 0, stream>>>(
        bufP, Bt[0], bufQ, nullptr, nullptr, Bv[0], nullptr, nullptr, N, dout[0], din[0]);
  }
  // layer 2: GEMM (h2 + fused score partials) -> reduce -> agg (emits layer-3 scores)
  {
    dim3 gg(dout[1] / 128, mgrp);
    gemm_mfma_kernel<1, 0, 1><<<gg, 256, 0, stream>>>(
        bufQ, Bt[1], hB, Asv[1], Adv[1], nullptr, partS, partD, N, dout[1], din[1]);
    score_reduce_kernel<<<(N + 255) / 256, 256, 0, stream>>>(partS, partD, s_src, s_dst,
                                                             N, (dout[1] / 128) * 2);
    agg_wave_kernel<1024, 1, 1, 0, 1><<<ngrp, 256, 0, stream>>>(
        hB, s_src, s_dst, rowptr, csr, Bv[1], nullptr, bufR,
        wvS + 256, wvD + 256, s_src2, s_dst2, N);
  }
  // layer 3: pure GEMM -> agg (emits layer-4 scores)
  {
    dim3 gg(dout[2] / 128, mgrp);
    gemm_mfma_kernel<1, 0, 0><<<gg, 256, 0, stream>>>(
        bufR, Bt[2], hB, nullptr, nullptr, nullptr, nullptr, nullptr, N, dout[2], din[2]);
    agg_wave_kernel<512, 1, 1, 0, 1><<<ngrp, 256, 0, stream>>>(
        hB, s_src2, s_dst2, rowptr, csr, Bv[2], nullptr, bufQ,
        wvS + 1280, wvD + 1280, s_src, s_dst, N);
  }
  // layer 4: pure GEMM (fp32 h) -> agg + fused log_softmax
  {
    dim3 gg(dout[3] / 128, mgrp);
    gemm_mfma_kernel<0, 0, 0><<<gg, 256, 0, stream>>>(
        bufQ, Bt[3], hF, nullptr, nullptr, nullptr, nullptr, nullptr, N, dout[3], din[3]);
    agg_wave_kernel<128, 0, 0, 1, 0><<<ngrp, 256, 0, stream>>>(
        hF, s_src, s_dst, rowptr, csr, Bv[3], (float*)d_out, nullptr,
        nullptr, nullptr, nullptr, nullptr, N);
  }
}

// Round 17
// 250.433 us; speedup vs baseline: 1.7513x; 1.0150x over previous
//
#include <hip/hip_runtime.h>
#include <math.h>

#define NEG_SLOPE 0.2f
#define EPS_F 1e-16f
typedef long long ll;

typedef __attribute__((ext_vector_type(4))) float f32x4;
typedef __attribute__((ext_vector_type(8))) short bf16x8;

// ---------------- bf16 helpers (bit-level, RTN-even) ----------------
__device__ __forceinline__ unsigned short bf16_of(float f) {
  unsigned u = __float_as_uint(f);
  u += 0x7fffu + ((u >> 16) & 1u);
  return (unsigned short)(u >> 16);
}
__device__ __forceinline__ float bf16_back(unsigned short s) {
  return __uint_as_float((unsigned)s << 16);
}

__device__ __forceinline__ void gload16(const void* g, void* l) {
  __builtin_amdgcn_global_load_lds((const __attribute__((address_space(1))) void*)g,
                                   (__attribute__((address_space(3))) void*)l, 16, 0, 0);
}

// block-uniform int64-layout detection from a fixed window (deterministic)
__device__ __forceinline__ int detect64_block(const int* __restrict__ ew, int E) {
  __shared__ int nzs;
  if (threadIdx.x == 0) nzs = 0;
  __syncthreads();
  const unsigned* w = (const unsigned*)ew;
  int cnt = E < 2048 ? E : 2048;
  int local = 0;
  for (int i = threadIdx.x; i < cnt; i += blockDim.x)
    if (w[2 * i + 1] != 0u) local++;
  if (local) atomicAdd(&nzs, local);
  __syncthreads();
  return nzs == 0;  // all high words zero => int64 layout
}

__device__ __forceinline__ void edge_at(const int* __restrict__ ew, int E, int e,
                                        int is64, int& s, int& d) {
  if (is64) { s = ew[2 * e]; d = ew[2 * E + 2 * e]; }
  else      { s = ew[e];     d = ew[E + e]; }
}

// ---------------- CSR build (deg = edge-count; +1 self-loop folded in scan) ----
__global__ void count_deg_kernel(const int* __restrict__ ew, int E, int* deg) {
  int is64 = detect64_block(ew, E);
  int e = blockIdx.x * blockDim.x + threadIdx.x;
  if (e < E) {
    int s, d;
    edge_at(ew, E, e, is64, s, d);
    atomicAdd(&deg[d], 1);
  }
}

__global__ void scan_kernel(const int* __restrict__ deg, int* rowptr, int* cursor, int N) {
  __shared__ int sums[1024];
  int tid = threadIdx.x;
  int chunk = (N + 1023) >> 10;
  int start = tid * chunk;
  int end = start + chunk; if (end > N) end = N;
  int s = 0;
  for (int i = start; i < end; ++i) s += deg[i] + 1;  // +1 = self loop
  sums[tid] = s;
  __syncthreads();
  for (int off = 1; off < 1024; off <<= 1) {
    int v = (tid >= off) ? sums[tid - off] : 0;
    __syncthreads();
    sums[tid] += v;
    __syncthreads();
  }
  int run = (tid == 0) ? 0 : sums[tid - 1];
  for (int i = start; i < end; ++i) {
    rowptr[i] = run; cursor[i] = run;
    run += deg[i] + 1;
  }
  if (tid == 1023) rowptr[N] = sums[1023];
}

__global__ void fill_kernel(const int* __restrict__ ew, int E, int N, int* cursor,
                            int* csr) {
  int is64 = detect64_block(ew, E);
  int i = blockIdx.x * blockDim.x + threadIdx.x;
  if (i < E) {
    int s, d;
    edge_at(ew, E, i, is64, s, d);
    int pos = atomicAdd(&cursor[d], 1);
    csr[pos] = s;
  } else if (i < E + N) {
    int n = i - E;
    int pos = atomicAdd(&cursor[n], 1);
    csr[pos] = n;
  }
}

// ---------------- weight conversions + wvec (one dispatch) ----------------
// z<4: W[z] [K,Nc] fp32 -> Bt[z] [Nc,K] bf16 (W_hi^T).
// z==4: wvec for all 4 layers: wv_l[k] = sum_j W_l[k][j]*a_l[j];
//       offsets {0,256,1280,2304}, lengths {256,1024,1024,512}.
__global__ __launch_bounds__(256) void convert_w_wvec_kernel(
    const float* __restrict__ W0, const float* __restrict__ W1,
    const float* __restrict__ W2, const float* __restrict__ W3,
    short* __restrict__ B0, short* __restrict__ B1,
    short* __restrict__ B2, short* __restrict__ B3,
    const float* __restrict__ as0, const float* __restrict__ ad0,
    const float* __restrict__ as1, const float* __restrict__ ad1,
    const float* __restrict__ as2, const float* __restrict__ ad2,
    const float* __restrict__ as3, const float* __restrict__ ad3,
    float* __restrict__ wvS, float* __restrict__ wvD) {
  int z = blockIdx.z;
  if (z < 4) {
    const int Ks[4]  = {256, 1024, 1024, 512};
    const int Ncs[4] = {1024, 1024, 512, 128};
    int K = Ks[z], Nc = Ncs[z];
    int k0 = blockIdx.x * 32, n0 = blockIdx.y * 32;
    if (k0 >= K || n0 >= Nc) return;
    const float* W = z == 0 ? W0 : (z == 1 ? W1 : (z == 2 ? W2 : W3));
    short* Bt = z == 0 ? B0 : (z == 1 ? B1 : (z == 2 ? B2 : B3));
    __shared__ float t[32][33];
    int r = threadIdx.x >> 3;          // 0..31
    int c4 = (threadIdx.x & 7) * 4;    // 0..28
    float4 v = *(const float4*)&W[(ll)(k0 + r) * Nc + n0 + c4];
    t[r][c4] = v.x; t[r][c4 + 1] = v.y; t[r][c4 + 2] = v.z; t[r][c4 + 3] = v.w;
    __syncthreads();
    float f0 = t[c4 + 0][r], f1 = t[c4 + 1][r], f2 = t[c4 + 2][r], f3 = t[c4 + 3][r];
    short4 hp = make_short4((short)bf16_of(f0), (short)bf16_of(f1),
                            (short)bf16_of(f2), (short)bf16_of(f3));
    *(short4*)&Bt[(ll)(n0 + r) * K + k0 + c4] = hp;
  } else {
    const int Ks[4]   = {256, 1024, 1024, 512};
    const int Ncs[4]  = {1024, 1024, 512, 128};
    const int offs[4] = {0, 256, 1280, 2304};
    int id = blockIdx.y * 32 + blockIdx.x;  // 0..1023; need 64+256+256+128=704
    int zi, kg;
    if (id < 64) { zi = 0; kg = id; }
    else if (id < 320) { zi = 1; kg = id - 64; }
    else if (id < 576) { zi = 2; kg = id - 320; }
    else if (id < 704) { zi = 3; kg = id - 576; }
    else return;
    int K = Ks[zi], Nc = Ncs[zi];
    int wid = threadIdx.x >> 6, lane = threadIdx.x & 63;
    int k = kg * 4 + wid;
    if (k >= K) return;
    const float* W  = zi == 0 ? W0 : (zi == 1 ? W1 : (zi == 2 ? W2 : W3));
    const float* as = zi == 0 ? as0 : (zi == 1 ? as1 : (zi == 2 ? as2 : as3));
    const float* ad = zi == 0 ? ad0 : (zi == 1 ? ad1 : (zi == 2 ? ad2 : ad3));
    const float* row = W + (ll)k * Nc;
    float a = 0.f, b = 0.f;
    for (int j = lane; j < Nc; j += 64) {
      float w = row[j];
      a += w * as[j];
      b += w * ad[j];
    }
#pragma unroll
    for (int o = 32; o > 0; o >>= 1) {
      a += __shfl_xor(a, o, 64);
      b += __shfl_xor(b, o, 64);
    }
    if (lane == 0) { wvS[offs[zi] + k] = a; wvD[offs[zi] + k] = b; }
  }
}

// layer-1 scores by GEMV (fp32 x, din=256)
__global__ void score_gemv_kernel(const float* __restrict__ x, const float* __restrict__ ws,
                                  const float* __restrict__ wd, float* __restrict__ s_src,
                                  float* __restrict__ s_dst, int N) {
  int wid = threadIdx.x >> 6, lane = threadIdx.x & 63;
  int n = blockIdx.x * 4 + wid;
  if (n >= N) return;
  float4 xv = *(const float4*)&x[(ll)n * 256 + lane * 4];
  float4 wsv = *(const float4*)&ws[lane * 4];
  float4 wdv = *(const float4*)&wd[lane * 4];
  float a = xv.x * wsv.x + xv.y * wsv.y + xv.z * wsv.z + xv.w * wsv.w;
  float b = xv.x * wdv.x + xv.y * wdv.y + xv.z * wdv.z + xv.w * wdv.w;
#pragma unroll
  for (int o = 32; o > 0; o >>= 1) {
    a += __shfl_xor(a, o, 64);
    b += __shfl_xor(b, o, 64);
  }
  if (lane == 0) { s_src[n] = a; s_dst[n] = b; }
}

// layer-2 scores by GEMV on bf16 activations (din=1024; 16 dims/lane)
__global__ void score_gemv_b16_kernel(const unsigned short* __restrict__ act,
                                      const float* __restrict__ ws,
                                      const float* __restrict__ wd,
                                      float* __restrict__ s_src,
                                      float* __restrict__ s_dst, int N) {
  int wid = threadIdx.x >> 6, lane = threadIdx.x & 63;
  int n = blockIdx.x * 4 + wid;
  if (n >= N) return;
  const unsigned short* row = act + (ll)n * 1024 + lane * 16;
  float a = 0.f, b = 0.f;
#pragma unroll
  for (int h = 0; h < 2; ++h) {
    bf16x8 q = *(const bf16x8*)(row + h * 8);
#pragma unroll
    for (int k = 0; k < 8; ++k) {
      float v = bf16_back((unsigned short)q[k]);
      int d = lane * 16 + h * 8 + k;
      a += v * ws[d];
      b += v * wd[d];
    }
  }
#pragma unroll
  for (int o = 32; o > 0; o >>= 1) {
    a += __shfl_xor(a, o, 64);
    b += __shfl_xor(b, o, 64);
  }
  if (lane == 0) { s_src[n] = a; s_dst[n] = b; }
}

// ---------------- layer-1 input-side aggregation (plain bf16 out) -----------
__global__ __launch_bounds__(256) void agg_x_kernel(
    const float* __restrict__ x, const float* __restrict__ ssrc,
    const float* __restrict__ sdst, const int* __restrict__ rowptr,
    const int* __restrict__ csr, short* __restrict__ outH, int N) {
  int wid = threadIdx.x >> 6, lane = threadIdx.x & 63;
  int node = blockIdx.x * 4 + wid;
  if (node >= N) return;
  int rs = rowptr[node];
  int nd = rowptr[node + 1] - rs;
  float sd = sdst[node];
  int d0 = lane * 4;

  float a0 = 0.f, a1 = 0.f, a2 = 0.f, a3 = 0.f;
  auto accum = [&](int s, float w) {
    float4 xv = *(const float4*)&x[(ll)s * 256 + d0];
    a0 += w * xv.x; a1 += w * xv.y; a2 += w * xv.z; a3 += w * xv.w;
  };

  if (nd <= 64) {
    int srcl = 0;
    float e = -1e30f;
    if (lane < nd) {
      srcl = csr[rs + lane];
      float t = ssrc[srcl] + sd;
      e = t > 0.f ? t : NEG_SLOPE * t;
    }
    float m = e;
#pragma unroll
    for (int o = 32; o > 0; o >>= 1) m = fmaxf(m, __shfl_xor(m, o, 64));
    float ex = (lane < nd) ? __expf(e - m) : 0.f;
    float den = ex;
#pragma unroll
    for (int o = 32; o > 0; o >>= 1) den += __shfl_xor(den, o, 64);
    float al = ex / (den + EPS_F);
    int i = 0;
    for (; i + 4 <= nd; i += 4) {
      int s0 = __shfl(srcl, i, 64), s1 = __shfl(srcl, i + 1, 64);
      int s2 = __shfl(srcl, i + 2, 64), s3 = __shfl(srcl, i + 3, 64);
      float w0 = __shfl(al, i, 64), w1 = __shfl(al, i + 1, 64);
      float w2 = __shfl(al, i + 2, 64), w3 = __shfl(al, i + 3, 64);
      accum(s0, w0); accum(s1, w1); accum(s2, w2); accum(s3, w3);
    }
    for (; i < nd; ++i) accum(__shfl(srcl, i, 64), __shfl(al, i, 64));
  } else {
    float m = -1e30f;
    for (int i = lane; i < nd; i += 64) {
      float t = ssrc[csr[rs + i]] + sd;
      t = t > 0.f ? t : NEG_SLOPE * t;
      m = fmaxf(m, t);
    }
#pragma unroll
    for (int o = 32; o > 0; o >>= 1) m = fmaxf(m, __shfl_xor(m, o, 64));
    float den = 0.f;
    for (int i = lane; i < nd; i += 64) {
      float t = ssrc[csr[rs + i]] + sd;
      t = t > 0.f ? t : NEG_SLOPE * t;
      den += __expf(t - m);
    }
#pragma unroll
    for (int o = 32; o > 0; o >>= 1) den += __shfl_xor(den, o, 64);
    float inv = 1.f / (den + EPS_F);
    for (int i = 0; i < nd; ++i) {
      int s = csr[rs + i];
      float t = ssrc[s] + sd;
      t = t > 0.f ? t : NEG_SLOPE * t;
      accum(s, __expf(t - m) * inv);
    }
  }

  short4 hp = make_short4((short)bf16_of(a0), (short)bf16_of(a1),
                          (short)bf16_of(a2), (short)bf16_of(a3));
  *(short4*)&outH[(ll)node * 256 + d0] = hp;
}

// ---------------- MFMA GEMM (64x128 tile, BK=64) ----------------
// Chunk XOR-swizzle phys = log ^ (row&7); LDS linear, global source permuted.
// XCD-chunked bijective block swizzle for L2 locality. BIASRELU fuses epilogue.
template <int HBF16, int BIASRELU>
__global__ __launch_bounds__(256) void gemm_mfma_kernel(
    const short* __restrict__ A, const short* __restrict__ Bt,
    void* __restrict__ Cv, const float* __restrict__ bias, int M, int Nc, int K) {
  __shared__ char Ah[8192];   // 64 rows x 128B
  __shared__ char Bs[16384];  // 128 rows x 128B
  int tid = threadIdx.x;

  int nwg = gridDim.x * gridDim.y;
  int hb = blockIdx.y * gridDim.x + blockIdx.x;
  int xcd = hb & 7, q = nwg >> 3, r = nwg & 7;
  int lg = (xcd < r ? xcd * (q + 1) : r * (q + 1) + (xcd - r) * q) + (hb >> 3);
  int bx = lg % gridDim.x, by = lg / gridDim.x;
  int bm = by * 64, bn = bx * 128;

  int lane = tid & 63, wid = tid >> 6;
  int wr = wid >> 1, wc = wid & 1;

  f32x4 acc[2][4];
#pragma unroll
  for (int m = 0; m < 2; ++m)
#pragma unroll
    for (int n = 0; n < 4; ++n) acc[m][n] = (f32x4){0.f, 0.f, 0.f, 0.f};

  int srow = tid >> 3;                  // 0..31
  int gc = (tid & 7) ^ (srow & 7);      // global 16B-chunk fetched
  int raA0 = bm + srow;      if (raA0 > M - 1) raA0 = M - 1;
  int raA1 = bm + srow + 32; if (raA1 > M - 1) raA1 = M - 1;
  const short* aSrc0 = A + (ll)raA0 * K + gc * 8;
  const short* aSrc1 = A + (ll)raA1 * K + gc * 8;
  const short* bSrc0 = Bt + (ll)(bn + srow) * K + gc * 8;
  const short* bSrc1 = Bt + (ll)(bn + srow + 32) * K + gc * 8;
  const short* bSrc2 = Bt + (ll)(bn + srow + 64) * K + gc * 8;
  const short* bSrc3 = Bt + (ll)(bn + srow + 96) * K + gc * 8;
  int dstOff = tid * 16;

  int lrow = lane & 15;
  int swzr = lrow & 7;
  int c0 = lane >> 4;  // 0..3
  int offA[2][2], offB[4][2];
#pragma unroll
  for (int m = 0; m < 2; ++m)
#pragma unroll
    for (int kk = 0; kk < 2; ++kk)
      offA[m][kk] = ((wr * 32 + m * 16 + lrow) * 8 + ((c0 + kk * 4) ^ swzr)) * 16;
#pragma unroll
  for (int n = 0; n < 4; ++n)
#pragma unroll
    for (int kk = 0; kk < 2; ++kk)
      offB[n][kk] = ((wc * 64 + n * 16 + lrow) * 8 + ((c0 + kk * 4) ^ swzr)) * 16;

  for (int kt = 0; kt < K; kt += 64) {
    gload16(aSrc0 + kt, Ah + dstOff);
    gload16(aSrc1 + kt, Ah + 4096 + dstOff);
    gload16(bSrc0 + kt, Bs + dstOff);
    gload16(bSrc1 + kt, Bs + 4096 + dstOff);
    gload16(bSrc2 + kt, Bs + 8192 + dstOff);
    gload16(bSrc3 + kt, Bs + 12288 + dstOff);
    __syncthreads();
    bf16x8 ah[2][2], bfr[4][2];
#pragma unroll
    for (int m = 0; m < 2; ++m)
#pragma unroll
      for (int kk = 0; kk < 2; ++kk)
        ah[m][kk] = *(const bf16x8*)(Ah + offA[m][kk]);
#pragma unroll
    for (int n = 0; n < 4; ++n)
#pragma unroll
      for (int kk = 0; kk < 2; ++kk)
        bfr[n][kk] = *(const bf16x8*)(Bs + offB[n][kk]);
#pragma unroll
    for (int kk = 0; kk < 2; ++kk)
#pragma unroll
      for (int m = 0; m < 2; ++m)
#pragma unroll
        for (int n = 0; n < 4; ++n)
          acc[m][n] = __builtin_amdgcn_mfma_f32_16x16x32_bf16(ah[m][kk], bfr[n][kk],
                                                              acc[m][n], 0, 0, 0);
    __syncthreads();
  }

  int crow0 = bm + wr * 32 + (lane >> 4) * 4;
  int ccol0 = bn + wc * 64 + (lane & 15);
  float bv4[4];
  if constexpr (BIASRELU) {
#pragma unroll
    for (int n = 0; n < 4; ++n) bv4[n] = bias[ccol0 + n * 16];
  }
#pragma unroll
  for (int m = 0; m < 2; ++m) {
#pragma unroll
    for (int j = 0; j < 4; ++j) {
      int row = crow0 + m * 16 + j;
      if (row < M) {
#pragma unroll
        for (int n = 0; n < 4; ++n) {
          float v = acc[m][n][j];
          if constexpr (BIASRELU) v = fmaxf(v + bv4[n], 0.f);
          if (HBF16) ((unsigned short*)Cv)[(ll)row * Nc + ccol0 + n * 16] = bf16_of(v);
          else       ((float*)Cv)[(ll)row * Nc + ccol0 + n * 16] = v;
        }
      }
    }
  }
}

// ---------------- wave-per-node fused softmax + weighted aggregation --------
// SCORENEXT: compute next layer's scores from the fp32 output row in regs.
template <int DOUT, int HIN_BF16, int OUTB16, int LOGSM, int SCORENEXT>
__global__ __launch_bounds__(256) void agg_wave_kernel(
    const void* __restrict__ hv, const float* __restrict__ ssrc,
    const float* __restrict__ sdst, const int* __restrict__ rowptr,
    const int* __restrict__ csr, const float* __restrict__ bias,
    float* __restrict__ outF, short* __restrict__ outH,
    const float* __restrict__ wvnS, const float* __restrict__ wvnD,
    float* __restrict__ oSs, float* __restrict__ oSd, int N) {
  constexpr int NH = (DOUT >= 512) ? DOUT / 512 : 1;   // row halves of 512 dims
  constexpr int DPL = (DOUT >= 512) ? 8 : DOUT / 64;   // dims/lane per half
  int wid = threadIdx.x >> 6, lane = threadIdx.x & 63;
  int node = blockIdx.x * 4 + wid;
  if (node >= N) return;
  int rs = rowptr[node];
  int nd = rowptr[node + 1] - rs;
  float sd = sdst[node];
  int d0 = lane * DPL;

  float acc[NH][DPL];
#pragma unroll
  for (int hh = 0; hh < NH; ++hh)
#pragma unroll
    for (int k = 0; k < DPL; ++k) acc[hh][k] = 0.f;

  auto accum = [&](int s, float w) {
    if constexpr (HIN_BF16) {
      const unsigned short* hp = (const unsigned short*)hv + (ll)s * DOUT + d0;
#pragma unroll
      for (int hh = 0; hh < NH; ++hh) {
        bf16x8 qv = *(const bf16x8*)(hp + hh * 512);
#pragma unroll
        for (int k = 0; k < 8; ++k)
          acc[hh][k] += w * bf16_back((unsigned short)qv[k]);
      }
    } else {
      const float* hp = (const float*)hv + (ll)s * DOUT + d0;
#pragma unroll
      for (int k = 0; k < DPL; ++k) acc[0][k] += w * hp[k];
    }
  };

  if (nd <= 64) {
    int srcl = 0;
    float e = -1e30f;
    if (lane < nd) {
      srcl = csr[rs + lane];
      float t = ssrc[srcl] + sd;
      e = t > 0.f ? t : NEG_SLOPE * t;
    }
    float m = e;
#pragma unroll
    for (int o = 32; o > 0; o >>= 1) m = fmaxf(m, __shfl_xor(m, o, 64));
    float ex = (lane < nd) ? __expf(e - m) : 0.f;
    float den = ex;
#pragma unroll
    for (int o = 32; o > 0; o >>= 1) den += __shfl_xor(den, o, 64);
    float al = ex / (den + EPS_F);

    int i = 0;
    for (; i + 4 <= nd; i += 4) {
      int s0 = __shfl(srcl, i, 64), s1 = __shfl(srcl, i + 1, 64);
      int s2 = __shfl(srcl, i + 2, 64), s3 = __shfl(srcl, i + 3, 64);
      float w0 = __shfl(al, i, 64), w1 = __shfl(al, i + 1, 64);
      float w2 = __shfl(al, i + 2, 64), w3 = __shfl(al, i + 3, 64);
      accum(s0, w0); accum(s1, w1); accum(s2, w2); accum(s3, w3);
    }
    for (; i < nd; ++i) accum(__shfl(srcl, i, 64), __shfl(al, i, 64));
  } else {
    float m = -1e30f;
    for (int i = lane; i < nd; i += 64) {
      float t = ssrc[csr[rs + i]] + sd;
      t = t > 0.f ? t : NEG_SLOPE * t;
      m = fmaxf(m, t);
    }
#pragma unroll
    for (int o = 32; o > 0; o >>= 1) m = fmaxf(m, __shfl_xor(m, o, 64));
    float den = 0.f;
    for (int i = lane; i < nd; i += 64) {
      float t = ssrc[csr[rs + i]] + sd;
      t = t > 0.f ? t : NEG_SLOPE * t;
      den += __expf(t - m);
    }
#pragma unroll
    for (int o = 32; o > 0; o >>= 1) den += __shfl_xor(den, o, 64);
    float inv = 1.f / (den + EPS_F);
    for (int i = 0; i < nd; ++i) {
      int s = csr[rs + i];  // wave-uniform broadcast load
      float t = ssrc[s] + sd;
      t = t > 0.f ? t : NEG_SLOPE * t;
      accum(s, __expf(t - m) * inv);
    }
  }

  if constexpr (OUTB16) {
    float ps = 0.f, pd = 0.f;
#pragma unroll
    for (int hh = 0; hh < NH; ++hh) {
      int d = hh * 512 + d0;
      bf16x8 hp8;
#pragma unroll
      for (int k = 0; k < 8; ++k) {
        float v = fmaxf(acc[hh][k] + bias[d + k], 0.f);
        hp8[k] = (short)bf16_of(v);
        if constexpr (SCORENEXT) {
          ps += v * wvnS[d + k];
          pd += v * wvnD[d + k];
        }
      }
      *(bf16x8*)&outH[(ll)node * DOUT + d] = hp8;
    }
    if constexpr (SCORENEXT) {
#pragma unroll
      for (int o = 32; o > 0; o >>= 1) {
        ps += __shfl_xor(ps, o, 64);
        pd += __shfl_xor(pd, o, 64);
      }
      if (lane == 0) { oSs[node] = ps; oSd[node] = pd; }
    }
  } else if constexpr (LOGSM) {
    float v0 = acc[0][0] + bias[d0 + 0];
    float v1 = acc[0][1] + bias[d0 + 1];
    float mx = fmaxf(v0, v1);
#pragma unroll
    for (int o = 32; o > 0; o >>= 1) mx = fmaxf(mx, __shfl_xor(mx, o, 64));
    float s = __expf(v0 - mx) + __expf(v1 - mx);
#pragma unroll
    for (int o = 32; o > 0; o >>= 1) s += __shfl_xor(s, o, 64);
    float ls = logf(s);
    outF[(ll)node * DOUT + d0 + 0] = v0 - mx - ls;
    outF[(ll)node * DOUT + d0 + 1] = v1 - mx - ls;
  } else {
#pragma unroll
    for (int k = 0; k < DPL; ++k)
      outF[(ll)node * DOUT + d0 + k] = acc[0][k] + bias[d0 + k];
  }
}

// ---------------- launch ----------------
extern "C" void kernel_launch(void* const* d_in, const int* in_sizes, int n_in,
                              void* d_out, int out_size, void* d_ws, size_t ws_size,
                              hipStream_t stream) {
  const float* x = (const float*)d_in[0];
  const int* ew = (const int*)d_in[1];
  int N = in_sizes[0] / 256;
  int E = in_sizes[1] / 2;

  const float* W[4]   = {(const float*)d_in[2],  (const float*)d_in[6],
                         (const float*)d_in[10], (const float*)d_in[14]};
  const float* Asv[4] = {(const float*)d_in[3],  (const float*)d_in[7],
                         (const float*)d_in[11], (const float*)d_in[15]};
  const float* Adv[4] = {(const float*)d_in[4],  (const float*)d_in[8],
                         (const float*)d_in[12], (const float*)d_in[16]};
  const float* Bv[4]  = {(const float*)d_in[5],  (const float*)d_in[9],
                         (const float*)d_in[13], (const float*)d_in[17]};
  const int din[4]  = {256, 1024, 1024, 512};
  const int dout[4] = {1024, 1024, 512, 128};

  char* ws = (char*)d_ws;
  size_t off = 0;
  auto alloc = [&](size_t bytes) {
    void* p = ws + off;
    off += (bytes + 255) & ~(size_t)255;
    return p;
  };
  unsigned short* hB = (unsigned short*)alloc((size_t)N * 1024 * 2);  // bf16 h (layers 2-3)
  float* hF   = (float*)alloc((size_t)N * 128 * 4);                   // fp32 h (layer 4)
  short* bufP = (short*)alloc((size_t)N * 256 * 2);   // xagg bf16
  short* bufQ = (short*)alloc((size_t)N * 1024 * 2);  // inter-layer bf16 act
  short* bufR = (short*)alloc((size_t)N * 1024 * 2);
  float* s_src  = (float*)alloc((size_t)N * 4);
  float* s_dst  = (float*)alloc((size_t)N * 4);
  float* s_src2 = (float*)alloc((size_t)N * 4);
  float* s_dst2 = (float*)alloc((size_t)N * 4);
  float* wvS  = (float*)alloc((size_t)4096 * 4);  // l1@0, l2@256, l3@1280, l4@2304
  float* wvD  = (float*)alloc((size_t)4096 * 4);
  int* deg    = (int*)alloc((size_t)(N + 1) * 4);
  int* rowptr = (int*)alloc((size_t)(N + 1) * 4);
  int* cursor = (int*)alloc((size_t)(N + 1) * 4);
  int* csr    = (int*)alloc((size_t)(E + N) * 4);
  short* Bt[4];
  for (int l = 0; l < 4; ++l) Bt[l] = (short*)alloc((size_t)dout[l] * din[l] * 2);

  hipMemsetAsync(deg, 0, (size_t)(N + 1) * 4, stream);
  count_deg_kernel<<<(E + 255) / 256, 256, 0, stream>>>(ew, E, deg);
  scan_kernel<<<1, 1024, 0, stream>>>(deg, rowptr, cursor, N);
  fill_kernel<<<(E + N + 255) / 256, 256, 0, stream>>>(ew, E, N, cursor, csr);

  {
    dim3 cg(32, 32, 5);
    convert_w_wvec_kernel<<<cg, 256, 0, stream>>>(
        W[0], W[1], W[2], W[3], Bt[0], Bt[1], Bt[2], Bt[3],
        Asv[0], Adv[0], Asv[1], Adv[1], Asv[2], Adv[2], Asv[3], Adv[3], wvS, wvD);
  }

  int ngrp = (N + 3) / 4;
  int mgrp = (N + 63) / 64;
  // layer 1: GEMV scores -> input-side aggregation (bf16) -> GEMM (bias+relu)
  {
    score_gemv_kernel<<<ngrp, 256, 0, stream>>>(x, wvS, wvD, s_src, s_dst, N);
    agg_x_kernel<<<ngrp, 256, 0, stream>>>(x, s_src, s_dst, rowptr, csr, bufP, N);
    dim3 gg(dout[0] / 128, mgrp);
    gemm_mfma_kernel<1, 1><<<gg, 256, 0, stream>>>(bufP, Bt[0], bufQ, Bv[0],
                                                   N, dout[0], din[0]);
  }
  // layer 2: GEMV scores (s2 = act1 . wv2) -> GEMM h2 -> agg (emits layer-3 scores)
  {
    score_gemv_b16_kernel<<<ngrp, 256, 0, stream>>>((const unsigned short*)bufQ,
                                                    wvS + 256, wvD + 256,
                                                    s_src, s_dst, N);
    dim3 gg(dout[1] / 128, mgrp);
    gemm_mfma_kernel<1, 0><<<gg, 256, 0, stream>>>(bufQ, Bt[1], hB, nullptr,
                                                   N, dout[1], din[1]);
    agg_wave_kernel<1024, 1, 1, 0, 1><<<ngrp, 256, 0, stream>>>(
        hB, s_src, s_dst, rowptr, csr, Bv[1], nullptr, bufR,
        wvS + 1280, wvD + 1280, s_src2, s_dst2, N);
  }
  // layer 3: pure GEMM -> agg (emits layer-4 scores via wv4)
  {
    dim3 gg(dout[2] / 128, mgrp);
    gemm_mfma_kernel<1, 0><<<gg, 256, 0, stream>>>(bufR, Bt[2], hB, nullptr,
                                                   N, dout[2], din[2]);
    agg_wave_kernel<512, 1, 1, 0, 1><<<ngrp, 256, 0, stream>>>(
        hB, s_src2, s_dst2, rowptr, csr, Bv[2], nullptr, bufQ,
        wvS + 2304, wvD + 2304, s_src, s_dst, N);
  }
  // layer 4: pure GEMM (fp32 h) -> agg + fused log_softmax
  {
    dim3 gg(dout[3] / 128, mgrp);
    gemm_mfma_kernel<0, 0><<<gg, 256, 0, stream>>>(bufQ, Bt[3], hF, nullptr,
                                                   N, dout[3], din[3]);
    agg_wave_kernel<128, 0, 0, 1, 0><<<ngrp, 256, 0, stream>>>(
        hF, s_src, s_dst, rowptr, csr, Bv[3], (float*)d_out, nullptr,
        nullptr, nullptr, nullptr, nullptr, N);
  }
}